// Round 7
// baseline (685.300 us; speedup 1.0000x reference)
//
#include <hip/hip_runtime.h>

#define EPSV 1e-5f

// Problem constants: B=4, N=8, B2=32, C=128, H=W=64, HW=4096, KS=3
// Workspace (floats): k2d@0 (16777216), v@16777216 (16777216), wd@33554432 (12582912),
// stats@46137344: gnsum[1024] gnsq[1024] gap[512] gnmean[1024] gnrstd[1024] attn[1024]

__device__ __forceinline__ void block_sum_atomic(float val, float* dst) {
    __shared__ float sm[4];
    #pragma unroll
    for (int off = 32; off; off >>= 1) val += __shfl_down(val, off, 64);
    int lane = threadIdx.x & 63, wid = threadIdx.x >> 6;
    if (lane == 0) sm[wid] = val;
    __syncthreads();
    if (threadIdx.x == 0) atomicAdd(dst, sm[0] + sm[1] + sm[2] + sm[3]);
}

__device__ __forceinline__ unsigned bfbits(float f) {   // RNE f32->bf16 bits
    unsigned u = __float_as_uint(f);
    u += 0x7fff + ((u >> 16) & 1);
    return u >> 16;
}

// ---- kA: key_embed = ReLU(BN(grouped temporal conv3d)) + gap partial ----
__global__ __launch_bounds__(256, 4) void kA_key(
    const float* __restrict__ x, const float* __restrict__ wk,
    const float* __restrict__ g, const float* __restrict__ bb,
    const float* __restrict__ m, const float* __restrict__ vr,
    float* __restrict__ k2d, float* __restrict__ gap)
{
    int blk   = blockIdx.x;
    int strip = blk & 3;
    int half  = (blk >> 2) & 1;
    int grp   = (blk >> 3) & 3;
    int b2    = blk >> 5;
    int px0   = strip * 1024 + threadIdx.x * 4;
    int bi = b2 >> 3, ni = b2 & 7;
    int gch = grp * 32;
    int ob  = gch + half * 16;

    float acc[16][4];
    #pragma unroll
    for (int j = 0; j < 16; ++j)
        acc[j][0] = acc[j][1] = acc[j][2] = acc[j][3] = 0.f;

    #pragma unroll
    for (int dk = 0; dk < 3; ++dk) {
        int nf = ni + dk - 1;
        if (nf >= 0 && nf < 8) {
            const float* xp  = x + ((bi * 8 + nf) * 128 + gch) * 4096 + px0;
            const float* wkp = wk + ob * 96 + dk;
            #pragma unroll 4
            for (int ci = 0; ci < 32; ++ci) {
                const float4 xv = *(const float4*)(xp + ci * 4096);
                #pragma unroll
                for (int j = 0; j < 16; ++j) {
                    float wv = wkp[j * 96 + ci * 3];
                    acc[j][0] = fmaf(xv.x, wv, acc[j][0]);
                    acc[j][1] = fmaf(xv.y, wv, acc[j][1]);
                    acc[j][2] = fmaf(xv.z, wv, acc[j][2]);
                    acc[j][3] = fmaf(xv.w, wv, acc[j][3]);
                }
            }
        }
    }

    int lane = threadIdx.x & 63, wid = threadIdx.x >> 6;
    __shared__ float ssum[16][4];
    #pragma unroll
    for (int j = 0; j < 16; ++j) {
        int o = ob + j;
        float s = g[o] * rsqrtf(vr[o] + EPSV);
        float t = bb[o] - m[o] * s;
        float4 r;
        r.x = fmaxf(fmaf(acc[j][0], s, t), 0.f);
        r.y = fmaxf(fmaf(acc[j][1], s, t), 0.f);
        r.z = fmaxf(fmaf(acc[j][2], s, t), 0.f);
        r.w = fmaxf(fmaf(acc[j][3], s, t), 0.f);
        *(float4*)(k2d + (b2 * 128 + o) * 4096 + px0) = r;
        float lsum = r.x + r.y + r.z + r.w;
        #pragma unroll
        for (int off = 32; off; off >>= 1) lsum += __shfl_down(lsum, off, 64);
        if (lane == 0) ssum[j][wid] = lsum;
    }
    __syncthreads();
    if (threadIdx.x < 16) {
        float* sr = ssum[threadIdx.x];
        atomicAdd(&gap[bi * 128 + ob + threadIdx.x], sr[0] + sr[1] + sr[2] + sr[3]);
    }
}

// ---- kB: v = BN(x @ w_1x1); 16 oc x 1024-px strip; thread = 4 px ----
__global__ __launch_bounds__(256, 4) void kB_val(
    const float* __restrict__ x, const float* __restrict__ w,
    const float* __restrict__ g, const float* __restrict__ bb,
    const float* __restrict__ m, const float* __restrict__ vr,
    float* __restrict__ vout)
{
    int blk   = blockIdx.x;
    int ocg   = blk & 7;
    int strip = (blk >> 3) & 3;
    int b2    = blk >> 5;
    int px0   = strip * 1024 + threadIdx.x * 4;
    const float* xp = x + b2 * 128 * 4096 + px0;
    const float* wp = w + ocg * 16 * 128;

    float acc[16][4];
    #pragma unroll
    for (int j = 0; j < 16; ++j)
        acc[j][0] = acc[j][1] = acc[j][2] = acc[j][3] = 0.f;

    #pragma unroll 4
    for (int c = 0; c < 128; ++c) {
        const float4 xv = *(const float4*)(xp + c * 4096);
        #pragma unroll
        for (int j = 0; j < 16; ++j) {
            float wv = wp[j * 128 + c];
            acc[j][0] = fmaf(xv.x, wv, acc[j][0]);
            acc[j][1] = fmaf(xv.y, wv, acc[j][1]);
            acc[j][2] = fmaf(xv.z, wv, acc[j][2]);
            acc[j][3] = fmaf(xv.w, wv, acc[j][3]);
        }
    }
    #pragma unroll
    for (int j = 0; j < 16; ++j) {
        int o = ocg * 16 + j;
        float s = g[o] * rsqrtf(vr[o] + EPSV);
        float t = bb[o] - m[o] * s;
        float4 r;
        r.x = fmaf(acc[j][0], s, t);
        r.y = fmaf(acc[j][1], s, t);
        r.z = fmaf(acc[j][2], s, t);
        r.w = fmaf(acc[j][3], s, t);
        *(float4*)(vout + (b2 * 128 + o) * 4096 + px0) = r;
    }
}

// ---- kC: e = ReLU(BN([x;k2d]@w_e1)), wd = e@w_e2+b, GN partials ----
// Block = 64 px; lane = (pxg<<2)|chg: thread = 4 px x 4 e-channels (acc[4][4]).
// Wave q: e-ch [16q,16q+16); stage2: wd rows [24q,24q+24), 6 rows/thread.
// Grid 2048; LDS bf16 e_s[64][64] = 8 KB.
__global__ __launch_bounds__(256, 4) void kC_wd(
    const float* __restrict__ x, const float* __restrict__ k2d,
    const float* __restrict__ we1,
    const float* __restrict__ eg, const float* __restrict__ eb,
    const float* __restrict__ em, const float* __restrict__ ev,
    const float* __restrict__ we2, const float* __restrict__ be2,
    float* __restrict__ wd, float* __restrict__ gnsum, float* __restrict__ gnsq)
{
    int tid  = threadIdx.x;
    int lane = tid & 63;
    int q    = __builtin_amdgcn_readfirstlane(tid >> 6);
    int pxg  = lane >> 2;
    int chg  = lane & 3;
    int tile = blockIdx.x & 63;
    int b2   = blockIdx.x >> 6;
    int pxl  = pxg * 4;
    int px0  = tile * 64 + pxl;

    const float* xp = x   + b2 * 128 * 4096 + px0;
    const float* kp = k2d + b2 * 128 * 4096 + px0;
    int ch0 = q * 16 + chg * 4;
    const float* w1p = we1 + ch0 * 256;

    float acc[4][4];
    #pragma unroll
    for (int j = 0; j < 4; ++j)
        acc[j][0] = acc[j][1] = acc[j][2] = acc[j][3] = 0.f;

    #pragma unroll 4
    for (int c = 0; c < 128; ++c) {
        const float4 xv = *(const float4*)(xp + c * 4096);
        #pragma unroll
        for (int j = 0; j < 4; ++j) {
            float wv = w1p[j * 256 + c];
            acc[j][0] = fmaf(xv.x, wv, acc[j][0]);
            acc[j][1] = fmaf(xv.y, wv, acc[j][1]);
            acc[j][2] = fmaf(xv.z, wv, acc[j][2]);
            acc[j][3] = fmaf(xv.w, wv, acc[j][3]);
        }
    }
    #pragma unroll 4
    for (int c = 0; c < 128; ++c) {
        const float4 xv = *(const float4*)(kp + c * 4096);
        #pragma unroll
        for (int j = 0; j < 4; ++j) {
            float wv = w1p[j * 256 + 128 + c];
            acc[j][0] = fmaf(xv.x, wv, acc[j][0]);
            acc[j][1] = fmaf(xv.y, wv, acc[j][1]);
            acc[j][2] = fmaf(xv.z, wv, acc[j][2]);
            acc[j][3] = fmaf(xv.w, wv, acc[j][3]);
        }
    }

    __shared__ __align__(8) unsigned short e_s[64][64];   // bf16 bits, 8 KB
    #pragma unroll
    for (int j = 0; j < 4; ++j) {
        int eo = ch0 + j;
        float s = eg[eo] * rsqrtf(ev[eo] + EPSV);
        float t = eb[eo] - em[eo] * s;
        float r0 = fmaxf(fmaf(acc[j][0], s, t), 0.f);
        float r1 = fmaxf(fmaf(acc[j][1], s, t), 0.f);
        float r2 = fmaxf(fmaf(acc[j][2], s, t), 0.f);
        float r3 = fmaxf(fmaf(acc[j][3], s, t), 0.f);
        uint2 pk;
        pk.x = bfbits(r0) | (bfbits(r1) << 16);
        pk.y = bfbits(r2) | (bfbits(r3) << 16);
        *(uint2*)&e_s[eo][pxl] = pk;
    }
    __syncthreads();

    // stage 2: 6 wd rows per thread: rows q*24 + chg*6 .. +5
    int row0 = q * 24 + chg * 6;
    const float* w2p = we2 + row0 * 64;
    float wa[6][4];
    #pragma unroll
    for (int j = 0; j < 6; ++j) {
        float b = be2[row0 + j];
        wa[j][0] = wa[j][1] = wa[j][2] = wa[j][3] = b;
    }
    #pragma unroll 4
    for (int c = 0; c < 64; ++c) {
        const uint2 eu = *(const uint2*)&e_s[c][pxl];
        float e0 = __uint_as_float(eu.x << 16);
        float e1 = __uint_as_float(eu.x & 0xffff0000u);
        float e2 = __uint_as_float(eu.y << 16);
        float e3 = __uint_as_float(eu.y & 0xffff0000u);
        #pragma unroll
        for (int j = 0; j < 6; ++j) {
            float wv = w2p[j * 64 + c];
            wa[j][0] = fmaf(e0, wv, wa[j][0]);
            wa[j][1] = fmaf(e1, wv, wa[j][1]);
            wa[j][2] = fmaf(e2, wv, wa[j][2]);
            wa[j][3] = fmaf(e3, wv, wa[j][3]);
        }
    }

    float* wdp = wd + (b2 * 96 + row0) * 4096 + px0;
    #pragma unroll
    for (int j = 0; j < 6; ++j) {
        float4 r; r.x = wa[j][0]; r.y = wa[j][1]; r.z = wa[j][2]; r.w = wa[j][3];
        *(float4*)(wdp + j * 4096) = r;
    }

    // GN partials: thread's 6 rows = 2 complete c1 groups (3 rows each)
    #pragma unroll
    for (int jj = 0; jj < 2; ++jj) {
        float lsum = 0.f, lsq = 0.f;
        #pragma unroll
        for (int k = 0; k < 3; ++k)
            #pragma unroll
            for (int p = 0; p < 4; ++p) {
                float vv = wa[jj * 3 + k][p];
                lsum += vv; lsq += vv * vv;
            }
        // reduce across the 16 pxg lanes (stride 4 preserves chg class)
        #pragma unroll
        for (int off = 32; off >= 4; off >>= 1) {
            lsum += __shfl_down(lsum, off, 64);
            lsq  += __shfl_down(lsq,  off, 64);
        }
        if (pxg == 0) {
            int c1 = q * 8 + chg * 2 + jj;
            atomicAdd(&gnsum[b2 * 32 + c1], lsum);
            atomicAdd(&gnsq [b2 * 32 + c1], lsq);
        }
    }
}

// ---- kC2: finalize GroupNorm stats ----
__global__ __launch_bounds__(256) void kC2_gn(
    const float* __restrict__ gnsum, const float* __restrict__ gnsq,
    float* __restrict__ gnmean, float* __restrict__ gnrstd)
{
    int idx = blockIdx.x * 256 + threadIdx.x;
    const float inv = 1.f / 12288.f;
    float mu  = gnsum[idx] * inv;
    float var = fmaf(gnsq[idx], inv, -mu * mu);
    gnmean[idx] = mu;
    gnrstd[idx] = rsqrtf(fmaxf(var, 0.f) + EPSV);
}

// ---- kD: agg = SiLU(BN2(sum_k GN(wd)*unfold(v))) -> d_out, + gap ----
// Block = (bi, c1, 512-px strip); loops all 8 frames, 4 channels of c1.
// v rolled through registers (read once); wd read once. Thread = 2 px.
__global__ __launch_bounds__(256, 8) void kD_agg(
    const float* __restrict__ wd, const float* __restrict__ v,
    const float* __restrict__ gnmean, const float* __restrict__ gnrstd,
    const float* __restrict__ gng, const float* __restrict__ gnb,
    const float* __restrict__ g, const float* __restrict__ bb,
    const float* __restrict__ m, const float* __restrict__ vr,
    float* __restrict__ out, float* __restrict__ gap)
{
    int blk   = blockIdx.x;
    int strip = blk & 7;
    int c1    = (blk >> 3) & 31;
    int bi    = blk >> 8;            // grid = 4*32*8 = 1024
    int px0   = strip * 512 + threadIdx.x * 2;

    float sch[4], tch[4], gl[4];
    #pragma unroll
    for (int ch = 0; ch < 4; ++ch) {
        int c = c1 * 4 + ch;
        float s = g[c] * rsqrtf(vr[c] + EPSV);
        sch[ch] = s; tch[ch] = bb[c] - m[c] * s; gl[ch] = 0.f;
    }
    float gg[3], gb[3];
    #pragma unroll
    for (int k = 0; k < 3; ++k) { gg[k] = gng[c1 * 3 + k]; gb[k] = gnb[c1 * 3 + k]; }

    float2 vreg[4][3];
    #pragma unroll
    for (int ch = 0; ch < 4; ++ch) {
        vreg[ch][0] = make_float2(0.f, 0.f);
        vreg[ch][1] = *(const float2*)(v + ((bi * 8 + 0) * 128 + c1 * 4 + ch) * 4096 + px0);
        vreg[ch][2] = *(const float2*)(v + ((bi * 8 + 1) * 128 + c1 * 4 + ch) * 4096 + px0);
    }

    for (int ni = 0; ni < 8; ++ni) {
        int b2 = bi * 8 + ni;
        float mu = gnmean[b2 * 32 + c1], rs = gnrstd[b2 * 32 + c1];
        float2 wn[3];
        #pragma unroll
        for (int k = 0; k < 3; ++k) {
            int nf = ni + k - 1;
            if (nf >= 0 && nf < 8) {
                const float2 wv = *(const float2*)(wd + (b2 * 96 + c1 * 3 + k) * 4096 + px0);
                wn[k].x = fmaf((wv.x - mu) * rs, gg[k], gb[k]);
                wn[k].y = fmaf((wv.y - mu) * rs, gg[k], gb[k]);
            } else {
                wn[k] = make_float2(0.f, 0.f);
            }
        }
        #pragma unroll
        for (int ch = 0; ch < 4; ++ch) {
            float a0 = 0.f, a1 = 0.f;
            #pragma unroll
            for (int k = 0; k < 3; ++k) {
                a0 = fmaf(wn[k].x, vreg[ch][k].x, a0);
                a1 = fmaf(wn[k].y, vreg[ch][k].y, a1);
            }
            float y0 = fmaf(a0, sch[ch], tch[ch]);
            float y1 = fmaf(a1, sch[ch], tch[ch]);
            float2 r;
            r.x = y0 / (1.f + __expf(-y0));
            r.y = y1 / (1.f + __expf(-y1));
            *(float2*)(out + (b2 * 128 + c1 * 4 + ch) * 4096 + px0) = r;
            gl[ch] += r.x + r.y;
        }
        if (ni < 7) {
            #pragma unroll
            for (int ch = 0; ch < 4; ++ch) {
                vreg[ch][0] = vreg[ch][1];
                vreg[ch][1] = vreg[ch][2];
                if (ni + 2 < 8)
                    vreg[ch][2] = *(const float2*)(v + ((bi * 8 + ni + 2) * 128 + c1 * 4 + ch) * 4096 + px0);
            }
        }
    }

    __shared__ float sm[4][4];
    int lane = threadIdx.x & 63, wid = threadIdx.x >> 6;
    #pragma unroll
    for (int ch = 0; ch < 4; ++ch) {
        float s = gl[ch];
        #pragma unroll
        for (int off = 32; off; off >>= 1) s += __shfl_down(s, off, 64);
        if (lane == 0) sm[ch][wid] = s;
    }
    __syncthreads();
    if (threadIdx.x < 4) {
        float* sr = sm[threadIdx.x];
        atomicAdd(&gap[bi * 128 + c1 * 4 + threadIdx.x], sr[0] + sr[1] + sr[2] + sr[3]);
    }
}

// ---- kE1: a = ReLU(BNvec(gap/32768 @ w1^T + b1)) ----
__global__ __launch_bounds__(256) void kE1_a(
    const float* __restrict__ gap,
    const float* __restrict__ w1, const float* __restrict__ b1,
    const float* __restrict__ g, const float* __restrict__ bb,
    const float* __restrict__ m, const float* __restrict__ vr,
    float* __restrict__ a_buf)
{
    int idx = blockIdx.x * 256 + threadIdx.x;
    int bi = idx >> 7, oc = idx & 127;
    float acc = b1[oc];
    const float* gp = gap + bi * 128;
    const float* wp = w1 + oc * 128;
    for (int c = 0; c < 128; c += 4) {
        const float4 w4 = *(const float4*)(wp + c);
        acc = fmaf(gp[c + 0] * (1.f / 32768.f), w4.x, acc);
        acc = fmaf(gp[c + 1] * (1.f / 32768.f), w4.y, acc);
        acc = fmaf(gp[c + 2] * (1.f / 32768.f), w4.z, acc);
        acc = fmaf(gp[c + 3] * (1.f / 32768.f), w4.w, acc);
    }
    float s = g[oc] * rsqrtf(vr[oc] + EPSV);
    a_buf[bi * 128 + oc] = fmaxf(fmaf(acc, s, bb[oc] - m[oc] * s), 0.f);
}

// ---- kE2: attn = softmax over radix-2 pairs ----
__global__ __launch_bounds__(256) void kE2_attn(
    const float* __restrict__ a_buf,
    const float* __restrict__ w2, const float* __restrict__ b2v,
    float* __restrict__ attn)
{
    int idx = blockIdx.x * 256 + threadIdx.x;
    int bi = idx >> 7, cc = idx & 127;
    float l0 = b2v[cc * 2], l1 = b2v[cc * 2 + 1];
    const float* ap  = a_buf + bi * 128;
    const float* w0p = w2 + (cc * 2) * 128;
    const float* w1p = w2 + (cc * 2 + 1) * 128;
    for (int j = 0; j < 128; j += 4) {
        const float4 wa4 = *(const float4*)(w0p + j);
        const float4 wb4 = *(const float4*)(w1p + j);
        l0 = fmaf(ap[j + 0], wa4.x, l0); l1 = fmaf(ap[j + 0], wb4.x, l1);
        l0 = fmaf(ap[j + 1], wa4.y, l0); l1 = fmaf(ap[j + 1], wb4.y, l1);
        l0 = fmaf(ap[j + 2], wa4.z, l0); l1 = fmaf(ap[j + 2], wb4.z, l1);
        l0 = fmaf(ap[j + 3], wa4.w, l0); l1 = fmaf(ap[j + 3], wb4.w, l1);
    }
    float mx = fmaxf(l0, l1);
    float e0 = __expf(l0 - mx), e1 = __expf(l1 - mx);
    float inv = 1.f / (e0 + e1);
    attn[bi * 256 + cc * 2]     = e0 * inv;
    attn[bi * 256 + cc * 2 + 1] = e1 * inv;
}

// ---- kF: out = attn0*agg + attn1*k2d; thread = 4 px ----
__global__ __launch_bounds__(256, 8) void kF_out(
    float* __restrict__ out, const float* __restrict__ k2d,
    const float* __restrict__ attn)
{
    int blk   = blockIdx.x;
    int strip = blk & 3;
    int c     = (blk >> 2) & 127;
    int b2    = blk >> 9;
    int bi    = b2 >> 3;
    float a0 = attn[bi * 256 + c * 2];
    float a1 = attn[bi * 256 + c * 2 + 1];
    int idx = (b2 * 128 + c) * 4096 + strip * 1024 + threadIdx.x * 4;
    float4 o4 = *(const float4*)(out + idx);
    float4 k4 = *(const float4*)(k2d + idx);
    float4 r;
    r.x = fmaf(a0, o4.x, a1 * k4.x);
    r.y = fmaf(a0, o4.y, a1 * k4.y);
    r.z = fmaf(a0, o4.z, a1 * k4.z);
    r.w = fmaf(a0, o4.w, a1 * k4.w);
    *(float4*)(out + idx) = r;
}

extern "C" void kernel_launch(void* const* d_in, const int* in_sizes, int n_in,
                              void* d_out, int out_size, void* d_ws, size_t ws_size,
                              hipStream_t stream)
{
    const float* x      = (const float*)d_in[0];
    const float* w_key  = (const float*)d_in[1];
    const float* bnk_g  = (const float*)d_in[2];
    const float* bnk_b  = (const float*)d_in[3];
    const float* bnk_m  = (const float*)d_in[4];
    const float* bnk_v  = (const float*)d_in[5];
    const float* w_e1   = (const float*)d_in[6];
    const float* bne_g  = (const float*)d_in[7];
    const float* bne_b  = (const float*)d_in[8];
    const float* bne_m  = (const float*)d_in[9];
    const float* bne_v  = (const float*)d_in[10];
    const float* w_e2   = (const float*)d_in[11];
    const float* b_e2   = (const float*)d_in[12];
    const float* gn_g   = (const float*)d_in[13];
    const float* gn_b   = (const float*)d_in[14];
    const float* w_1x1  = (const float*)d_in[15];
    const float* bn1_g  = (const float*)d_in[16];
    const float* bn1_b  = (const float*)d_in[17];
    const float* bn1_m  = (const float*)d_in[18];
    const float* bn1_v  = (const float*)d_in[19];
    const float* bn2_g  = (const float*)d_in[20];
    const float* bn2_b  = (const float*)d_in[21];
    const float* bn2_m  = (const float*)d_in[22];
    const float* bn2_v  = (const float*)d_in[23];
    const float* w_se1  = (const float*)d_in[24];
    const float* b_se1  = (const float*)d_in[25];
    const float* bnse_g = (const float*)d_in[26];
    const float* bnse_b = (const float*)d_in[27];
    const float* bnse_m = (const float*)d_in[28];
    const float* bnse_v = (const float*)d_in[29];
    const float* w_se2  = (const float*)d_in[30];
    const float* b_se2  = (const float*)d_in[31];

    float* ws    = (float*)d_ws;
    float* k2d   = ws;
    float* v     = ws + 16777216;
    float* wd    = ws + 33554432;
    float* st    = ws + 46137344;
    float* gnsum  = st;
    float* gnsq   = st + 1024;
    float* gap    = st + 2048;
    float* gnmean = st + 2560;
    float* gnrstd = st + 3584;
    float* attn   = st + 4608;
    float* a_buf  = st;            // aliases gnsum (dead after kC2)

    hipMemsetAsync(gnsum, 0, 2560 * sizeof(float), stream);

    kA_key<<<1024, 256, 0, stream>>>(x, w_key, bnk_g, bnk_b, bnk_m, bnk_v, k2d, gap);
    kB_val<<<1024, 256, 0, stream>>>(x, w_1x1, bn1_g, bn1_b, bn1_m, bn1_v, v);
    kC_wd<<<2048, 256, 0, stream>>>(x, k2d, w_e1, bne_g, bne_b, bne_m, bne_v,
                                    w_e2, b_e2, wd, gnsum, gnsq);
    kC2_gn<<<4, 256, 0, stream>>>(gnsum, gnsq, gnmean, gnrstd);
    kD_agg<<<1024, 256, 0, stream>>>(wd, v, gnmean, gnrstd, gn_g, gn_b,
                                     bn2_g, bn2_b, bn2_m, bn2_v,
                                     (float*)d_out, gap);
    kE1_a<<<2, 256, 0, stream>>>(gap, w_se1, b_se1, bnse_g, bnse_b, bnse_m, bnse_v, a_buf);
    kE2_attn<<<2, 256, 0, stream>>>(a_buf, w_se2, b_se2, attn);
    kF_out<<<16384, 256, 0, stream>>>((float*)d_out, k2d, attn);
}

// Round 8
// 356.880 us; speedup vs baseline: 1.9203x; 1.9203x over previous
//
#include <hip/hip_runtime.h>

#define EPSV 1e-5f

// Problem constants: B=4, N=8, B2=32, C=128, H=W=64, HW=4096, KS=3
// Workspace (floats): k2d@0 (16777216), v@16777216 (16777216), wd@33554432 (12582912),
// stats@46137344: gnsum[1024] gnsq[1024] gap[512] gnmean[1024] gnrstd[1024] attn[1024]

__device__ __forceinline__ void block_sum_atomic(float val, float* dst) {
    __shared__ float sm[4];
    #pragma unroll
    for (int off = 32; off; off >>= 1) val += __shfl_down(val, off, 64);
    int lane = threadIdx.x & 63, wid = threadIdx.x >> 6;
    if (lane == 0) sm[wid] = val;
    __syncthreads();
    if (threadIdx.x == 0) atomicAdd(dst, sm[0] + sm[1] + sm[2] + sm[3]);
}

__device__ __forceinline__ unsigned bfbits(float f) {   // RNE f32->bf16 bits
    unsigned u = __float_as_uint(f);
    u += 0x7fff + ((u >> 16) & 1);
    return u >> 16;
}

// ---- kA: key_embed = ReLU(BN(grouped temporal conv3d)) + gap partial ----
__global__ __launch_bounds__(256, 4) void kA_key(
    const float* __restrict__ x, const float* __restrict__ wk,
    const float* __restrict__ g, const float* __restrict__ bb,
    const float* __restrict__ m, const float* __restrict__ vr,
    float* __restrict__ k2d, float* __restrict__ gap)
{
    int blk   = blockIdx.x;
    int strip = blk & 3;
    int half  = (blk >> 2) & 1;
    int grp   = (blk >> 3) & 3;
    int b2    = blk >> 5;
    int px0   = strip * 1024 + threadIdx.x * 4;
    int bi = b2 >> 3, ni = b2 & 7;
    int gch = grp * 32;
    int ob  = gch + half * 16;

    float acc[16][4];
    #pragma unroll
    for (int j = 0; j < 16; ++j)
        acc[j][0] = acc[j][1] = acc[j][2] = acc[j][3] = 0.f;

    #pragma unroll
    for (int dk = 0; dk < 3; ++dk) {
        int nf = ni + dk - 1;
        if (nf >= 0 && nf < 8) {
            const float* xp  = x + ((bi * 8 + nf) * 128 + gch) * 4096 + px0;
            const float* wkp = wk + ob * 96 + dk;
            #pragma unroll 4
            for (int ci = 0; ci < 32; ++ci) {
                const float4 xv = *(const float4*)(xp + ci * 4096);
                #pragma unroll
                for (int j = 0; j < 16; ++j) {
                    float wv = wkp[j * 96 + ci * 3];
                    acc[j][0] = fmaf(xv.x, wv, acc[j][0]);
                    acc[j][1] = fmaf(xv.y, wv, acc[j][1]);
                    acc[j][2] = fmaf(xv.z, wv, acc[j][2]);
                    acc[j][3] = fmaf(xv.w, wv, acc[j][3]);
                }
            }
        }
    }

    int lane = threadIdx.x & 63, wid = threadIdx.x >> 6;
    __shared__ float ssum[16][4];
    #pragma unroll
    for (int j = 0; j < 16; ++j) {
        int o = ob + j;
        float s = g[o] * rsqrtf(vr[o] + EPSV);
        float t = bb[o] - m[o] * s;
        float4 r;
        r.x = fmaxf(fmaf(acc[j][0], s, t), 0.f);
        r.y = fmaxf(fmaf(acc[j][1], s, t), 0.f);
        r.z = fmaxf(fmaf(acc[j][2], s, t), 0.f);
        r.w = fmaxf(fmaf(acc[j][3], s, t), 0.f);
        *(float4*)(k2d + (b2 * 128 + o) * 4096 + px0) = r;
        float lsum = r.x + r.y + r.z + r.w;
        #pragma unroll
        for (int off = 32; off; off >>= 1) lsum += __shfl_down(lsum, off, 64);
        if (lane == 0) ssum[j][wid] = lsum;
    }
    __syncthreads();
    if (threadIdx.x < 16) {
        float* sr = ssum[threadIdx.x];
        atomicAdd(&gap[bi * 128 + ob + threadIdx.x], sr[0] + sr[1] + sr[2] + sr[3]);
    }
}

// ---- kB: v = BN(x @ w_1x1); 16 oc x 1024-px strip; thread = 4 px ----
__global__ __launch_bounds__(256, 4) void kB_val(
    const float* __restrict__ x, const float* __restrict__ w,
    const float* __restrict__ g, const float* __restrict__ bb,
    const float* __restrict__ m, const float* __restrict__ vr,
    float* __restrict__ vout)
{
    int blk   = blockIdx.x;
    int ocg   = blk & 7;
    int strip = (blk >> 3) & 3;
    int b2    = blk >> 5;
    int px0   = strip * 1024 + threadIdx.x * 4;
    const float* xp = x + b2 * 128 * 4096 + px0;
    const float* wp = w + ocg * 16 * 128;

    float acc[16][4];
    #pragma unroll
    for (int j = 0; j < 16; ++j)
        acc[j][0] = acc[j][1] = acc[j][2] = acc[j][3] = 0.f;

    #pragma unroll 4
    for (int c = 0; c < 128; ++c) {
        const float4 xv = *(const float4*)(xp + c * 4096);
        #pragma unroll
        for (int j = 0; j < 16; ++j) {
            float wv = wp[j * 128 + c];
            acc[j][0] = fmaf(xv.x, wv, acc[j][0]);
            acc[j][1] = fmaf(xv.y, wv, acc[j][1]);
            acc[j][2] = fmaf(xv.z, wv, acc[j][2]);
            acc[j][3] = fmaf(xv.w, wv, acc[j][3]);
        }
    }
    #pragma unroll
    for (int j = 0; j < 16; ++j) {
        int o = ocg * 16 + j;
        float s = g[o] * rsqrtf(vr[o] + EPSV);
        float t = bb[o] - m[o] * s;
        float4 r;
        r.x = fmaf(acc[j][0], s, t);
        r.y = fmaf(acc[j][1], s, t);
        r.z = fmaf(acc[j][2], s, t);
        r.w = fmaf(acc[j][3], s, t);
        *(float4*)(vout + (b2 * 128 + o) * 4096 + px0) = r;
    }
}

// ---- kC: e = ReLU(BN([x;k2d]@w_e1)), wd = e@w_e2+b, GN partials ----
// Block = 512 threads = 8 waves, covering 256 px (4 px/thread, float4).
// Wave q: stage1 e-channels [8q,8q+8) (weights wave-uniform -> scalar loads);
//         stage2 wd rows [12q,12q+12) = c1 groups [4q,4q+4).
// Grid 512; 2 blocks/CU, 16 waves/CU. LDS bf16 e_s[64][256] = 32 KB, conflict-free.
__global__ __launch_bounds__(512, 4) void kC_wd(
    const float* __restrict__ x, const float* __restrict__ k2d,
    const float* __restrict__ we1,
    const float* __restrict__ eg, const float* __restrict__ eb,
    const float* __restrict__ em, const float* __restrict__ ev,
    const float* __restrict__ we2, const float* __restrict__ be2,
    float* __restrict__ wd, float* __restrict__ gnsum, float* __restrict__ gnsq)
{
    int tid  = threadIdx.x;
    int lane = tid & 63;
    int q    = __builtin_amdgcn_readfirstlane(tid >> 6);   // 0..7, wave-uniform
    int tile = blockIdx.x & 15;
    int b2   = blockIdx.x >> 4;
    int pxl  = lane * 4;
    int px0  = tile * 256 + pxl;

    const float* xp  = x   + b2 * 128 * 4096 + px0;
    const float* kp  = k2d + b2 * 128 * 4096 + px0;
    const float* w1q = we1 + q * 8 * 256;

    float acc[8][4];
    #pragma unroll
    for (int j = 0; j < 8; ++j)
        acc[j][0] = acc[j][1] = acc[j][2] = acc[j][3] = 0.f;

    #pragma unroll 4
    for (int c = 0; c < 128; ++c) {
        const float4 xv = *(const float4*)(xp + c * 4096);
        #pragma unroll
        for (int j = 0; j < 8; ++j) {
            float wv = w1q[j * 256 + c];
            acc[j][0] = fmaf(xv.x, wv, acc[j][0]);
            acc[j][1] = fmaf(xv.y, wv, acc[j][1]);
            acc[j][2] = fmaf(xv.z, wv, acc[j][2]);
            acc[j][3] = fmaf(xv.w, wv, acc[j][3]);
        }
    }
    #pragma unroll 4
    for (int c = 0; c < 128; ++c) {
        const float4 xv = *(const float4*)(kp + c * 4096);
        #pragma unroll
        for (int j = 0; j < 8; ++j) {
            float wv = w1q[j * 256 + 128 + c];
            acc[j][0] = fmaf(xv.x, wv, acc[j][0]);
            acc[j][1] = fmaf(xv.y, wv, acc[j][1]);
            acc[j][2] = fmaf(xv.z, wv, acc[j][2]);
            acc[j][3] = fmaf(xv.w, wv, acc[j][3]);
        }
    }

    __shared__ __align__(8) unsigned short e_s[64][256];   // bf16 bits, 32 KB
    #pragma unroll
    for (int j = 0; j < 8; ++j) {
        int eo = q * 8 + j;
        float s = eg[eo] * rsqrtf(ev[eo] + EPSV);
        float t = eb[eo] - em[eo] * s;
        float r0 = fmaxf(fmaf(acc[j][0], s, t), 0.f);
        float r1 = fmaxf(fmaf(acc[j][1], s, t), 0.f);
        float r2 = fmaxf(fmaf(acc[j][2], s, t), 0.f);
        float r3 = fmaxf(fmaf(acc[j][3], s, t), 0.f);
        uint2 pk;
        pk.x = bfbits(r0) | (bfbits(r1) << 16);
        pk.y = bfbits(r2) | (bfbits(r3) << 16);
        *(uint2*)&e_s[eo][pxl] = pk;
    }
    __syncthreads();

    // stage 2: 12 wd rows per wave (wave-uniform weight rows -> scalar loads)
    int row0 = q * 12;
    const float* w2q = we2 + row0 * 64;
    float wa[12][4];
    #pragma unroll
    for (int j = 0; j < 12; ++j) {
        float b = be2[row0 + j];
        wa[j][0] = wa[j][1] = wa[j][2] = wa[j][3] = b;
    }
    #pragma unroll 4
    for (int c = 0; c < 64; ++c) {
        const uint2 eu = *(const uint2*)&e_s[c][pxl];
        float e0 = __uint_as_float(eu.x << 16);
        float e1 = __uint_as_float(eu.x & 0xffff0000u);
        float e2 = __uint_as_float(eu.y << 16);
        float e3 = __uint_as_float(eu.y & 0xffff0000u);
        #pragma unroll
        for (int j = 0; j < 12; ++j) {
            float wv = w2q[j * 64 + c];
            wa[j][0] = fmaf(e0, wv, wa[j][0]);
            wa[j][1] = fmaf(e1, wv, wa[j][1]);
            wa[j][2] = fmaf(e2, wv, wa[j][2]);
            wa[j][3] = fmaf(e3, wv, wa[j][3]);
        }
    }

    float* wdp = wd + (b2 * 96 + row0) * 4096 + px0;
    #pragma unroll
    for (int j = 0; j < 12; ++j) {
        float4 r; r.x = wa[j][0]; r.y = wa[j][1]; r.z = wa[j][2]; r.w = wa[j][3];
        *(float4*)(wdp + j * 4096) = r;
    }

    // GN partials: wave's 12 rows = 4 complete c1 groups
    #pragma unroll
    for (int jj = 0; jj < 4; ++jj) {
        float lsum = 0.f, lsq = 0.f;
        #pragma unroll
        for (int k = 0; k < 3; ++k)
            #pragma unroll
            for (int p = 0; p < 4; ++p) {
                float vv = wa[jj * 3 + k][p];
                lsum += vv; lsq += vv * vv;
            }
        #pragma unroll
        for (int off = 32; off; off >>= 1) {
            lsum += __shfl_down(lsum, off, 64);
            lsq  += __shfl_down(lsq,  off, 64);
        }
        if (lane == 0) {
            int c1 = q * 4 + jj;
            atomicAdd(&gnsum[b2 * 32 + c1], lsum);
            atomicAdd(&gnsq [b2 * 32 + c1], lsq);
        }
    }
}

// ---- kC2: finalize GroupNorm stats ----
__global__ __launch_bounds__(256) void kC2_gn(
    const float* __restrict__ gnsum, const float* __restrict__ gnsq,
    float* __restrict__ gnmean, float* __restrict__ gnrstd)
{
    int idx = blockIdx.x * 256 + threadIdx.x;
    const float inv = 1.f / 12288.f;
    float mu  = gnsum[idx] * inv;
    float var = fmaf(gnsq[idx], inv, -mu * mu);
    gnmean[idx] = mu;
    gnrstd[idx] = rsqrtf(fmaxf(var, 0.f) + EPSV);
}

// ---- kD: agg = SiLU(BN2(sum_k GN(wd)*unfold(v))) -> d_out, + gap ----
__global__ __launch_bounds__(256, 8) void kD_agg(
    const float* __restrict__ wd, const float* __restrict__ v,
    const float* __restrict__ gnmean, const float* __restrict__ gnrstd,
    const float* __restrict__ gng, const float* __restrict__ gnb,
    const float* __restrict__ g, const float* __restrict__ bb,
    const float* __restrict__ m, const float* __restrict__ vr,
    float* __restrict__ out, float* __restrict__ gap)
{
    int blk   = blockIdx.x;
    int strip = blk & 7;
    int c1    = (blk >> 3) & 31;
    int bi    = blk >> 8;            // grid = 4*32*8 = 1024
    int px0   = strip * 512 + threadIdx.x * 2;

    float sch[4], tch[4], gl[4];
    #pragma unroll
    for (int ch = 0; ch < 4; ++ch) {
        int c = c1 * 4 + ch;
        float s = g[c] * rsqrtf(vr[c] + EPSV);
        sch[ch] = s; tch[ch] = bb[c] - m[c] * s; gl[ch] = 0.f;
    }
    float gg[3], gb[3];
    #pragma unroll
    for (int k = 0; k < 3; ++k) { gg[k] = gng[c1 * 3 + k]; gb[k] = gnb[c1 * 3 + k]; }

    float2 vreg[4][3];
    #pragma unroll
    for (int ch = 0; ch < 4; ++ch) {
        vreg[ch][0] = make_float2(0.f, 0.f);
        vreg[ch][1] = *(const float2*)(v + ((bi * 8 + 0) * 128 + c1 * 4 + ch) * 4096 + px0);
        vreg[ch][2] = *(const float2*)(v + ((bi * 8 + 1) * 128 + c1 * 4 + ch) * 4096 + px0);
    }

    for (int ni = 0; ni < 8; ++ni) {
        int b2 = bi * 8 + ni;
        float mu = gnmean[b2 * 32 + c1], rs = gnrstd[b2 * 32 + c1];
        float2 wn[3];
        #pragma unroll
        for (int k = 0; k < 3; ++k) {
            int nf = ni + k - 1;
            if (nf >= 0 && nf < 8) {
                const float2 wv = *(const float2*)(wd + (b2 * 96 + c1 * 3 + k) * 4096 + px0);
                wn[k].x = fmaf((wv.x - mu) * rs, gg[k], gb[k]);
                wn[k].y = fmaf((wv.y - mu) * rs, gg[k], gb[k]);
            } else {
                wn[k] = make_float2(0.f, 0.f);
            }
        }
        #pragma unroll
        for (int ch = 0; ch < 4; ++ch) {
            float a0 = 0.f, a1 = 0.f;
            #pragma unroll
            for (int k = 0; k < 3; ++k) {
                a0 = fmaf(wn[k].x, vreg[ch][k].x, a0);
                a1 = fmaf(wn[k].y, vreg[ch][k].y, a1);
            }
            float y0 = fmaf(a0, sch[ch], tch[ch]);
            float y1 = fmaf(a1, sch[ch], tch[ch]);
            float2 r;
            r.x = y0 / (1.f + __expf(-y0));
            r.y = y1 / (1.f + __expf(-y1));
            *(float2*)(out + (b2 * 128 + c1 * 4 + ch) * 4096 + px0) = r;
            gl[ch] += r.x + r.y;
        }
        if (ni < 7) {
            #pragma unroll
            for (int ch = 0; ch < 4; ++ch) {
                vreg[ch][0] = vreg[ch][1];
                vreg[ch][1] = vreg[ch][2];
                if (ni + 2 < 8)
                    vreg[ch][2] = *(const float2*)(v + ((bi * 8 + ni + 2) * 128 + c1 * 4 + ch) * 4096 + px0);
            }
        }
    }

    __shared__ float sm[4][4];
    int lane = threadIdx.x & 63, wid = threadIdx.x >> 6;
    #pragma unroll
    for (int ch = 0; ch < 4; ++ch) {
        float s = gl[ch];
        #pragma unroll
        for (int off = 32; off; off >>= 1) s += __shfl_down(s, off, 64);
        if (lane == 0) sm[ch][wid] = s;
    }
    __syncthreads();
    if (threadIdx.x < 4) {
        float* sr = sm[threadIdx.x];
        atomicAdd(&gap[bi * 128 + c1 * 4 + threadIdx.x], sr[0] + sr[1] + sr[2] + sr[3]);
    }
}

// ---- kE1: a = ReLU(BNvec(gap/32768 @ w1^T + b1)) ----
__global__ __launch_bounds__(256) void kE1_a(
    const float* __restrict__ gap,
    const float* __restrict__ w1, const float* __restrict__ b1,
    const float* __restrict__ g, const float* __restrict__ bb,
    const float* __restrict__ m, const float* __restrict__ vr,
    float* __restrict__ a_buf)
{
    int idx = blockIdx.x * 256 + threadIdx.x;
    int bi = idx >> 7, oc = idx & 127;
    float acc = b1[oc];
    const float* gp = gap + bi * 128;
    const float* wp = w1 + oc * 128;
    for (int c = 0; c < 128; c += 4) {
        const float4 w4 = *(const float4*)(wp + c);
        acc = fmaf(gp[c + 0] * (1.f / 32768.f), w4.x, acc);
        acc = fmaf(gp[c + 1] * (1.f / 32768.f), w4.y, acc);
        acc = fmaf(gp[c + 2] * (1.f / 32768.f), w4.z, acc);
        acc = fmaf(gp[c + 3] * (1.f / 32768.f), w4.w, acc);
    }
    float s = g[oc] * rsqrtf(vr[oc] + EPSV);
    a_buf[bi * 128 + oc] = fmaxf(fmaf(acc, s, bb[oc] - m[oc] * s), 0.f);
}

// ---- kE2: attn = softmax over radix-2 pairs ----
__global__ __launch_bounds__(256) void kE2_attn(
    const float* __restrict__ a_buf,
    const float* __restrict__ w2, const float* __restrict__ b2v,
    float* __restrict__ attn)
{
    int idx = blockIdx.x * 256 + threadIdx.x;
    int bi = idx >> 7, cc = idx & 127;
    float l0 = b2v[cc * 2], l1 = b2v[cc * 2 + 1];
    const float* ap  = a_buf + bi * 128;
    const float* w0p = w2 + (cc * 2) * 128;
    const float* w1p = w2 + (cc * 2 + 1) * 128;
    for (int j = 0; j < 128; j += 4) {
        const float4 wa4 = *(const float4*)(w0p + j);
        const float4 wb4 = *(const float4*)(w1p + j);
        l0 = fmaf(ap[j + 0], wa4.x, l0); l1 = fmaf(ap[j + 0], wb4.x, l1);
        l0 = fmaf(ap[j + 1], wa4.y, l0); l1 = fmaf(ap[j + 1], wb4.y, l1);
        l0 = fmaf(ap[j + 2], wa4.z, l0); l1 = fmaf(ap[j + 2], wb4.z, l1);
        l0 = fmaf(ap[j + 3], wa4.w, l0); l1 = fmaf(ap[j + 3], wb4.w, l1);
    }
    float mx = fmaxf(l0, l1);
    float e0 = __expf(l0 - mx), e1 = __expf(l1 - mx);
    float inv = 1.f / (e0 + e1);
    attn[bi * 256 + cc * 2]     = e0 * inv;
    attn[bi * 256 + cc * 2 + 1] = e1 * inv;
}

// ---- kF: out = attn0*agg + attn1*k2d; thread = 4 px ----
__global__ __launch_bounds__(256, 8) void kF_out(
    float* __restrict__ out, const float* __restrict__ k2d,
    const float* __restrict__ attn)
{
    int blk   = blockIdx.x;
    int strip = blk & 3;
    int c     = (blk >> 2) & 127;
    int b2    = blk >> 9;
    int bi    = b2 >> 3;
    float a0 = attn[bi * 256 + c * 2];
    float a1 = attn[bi * 256 + c * 2 + 1];
    int idx = (b2 * 128 + c) * 4096 + strip * 1024 + threadIdx.x * 4;
    float4 o4 = *(const float4*)(out + idx);
    float4 k4 = *(const float4*)(k2d + idx);
    float4 r;
    r.x = fmaf(a0, o4.x, a1 * k4.x);
    r.y = fmaf(a0, o4.y, a1 * k4.y);
    r.z = fmaf(a0, o4.z, a1 * k4.z);
    r.w = fmaf(a0, o4.w, a1 * k4.w);
    *(float4*)(out + idx) = r;
}

extern "C" void kernel_launch(void* const* d_in, const int* in_sizes, int n_in,
                              void* d_out, int out_size, void* d_ws, size_t ws_size,
                              hipStream_t stream)
{
    const float* x      = (const float*)d_in[0];
    const float* w_key  = (const float*)d_in[1];
    const float* bnk_g  = (const float*)d_in[2];
    const float* bnk_b  = (const float*)d_in[3];
    const float* bnk_m  = (const float*)d_in[4];
    const float* bnk_v  = (const float*)d_in[5];
    const float* w_e1   = (const float*)d_in[6];
    const float* bne_g  = (const float*)d_in[7];
    const float* bne_b  = (const float*)d_in[8];
    const float* bne_m  = (const float*)d_in[9];
    const float* bne_v  = (const float*)d_in[10];
    const float* w_e2   = (const float*)d_in[11];
    const float* b_e2   = (const float*)d_in[12];
    const float* gn_g   = (const float*)d_in[13];
    const float* gn_b   = (const float*)d_in[14];
    const float* w_1x1  = (const float*)d_in[15];
    const float* bn1_g  = (const float*)d_in[16];
    const float* bn1_b  = (const float*)d_in[17];
    const float* bn1_m  = (const float*)d_in[18];
    const float* bn1_v  = (const float*)d_in[19];
    const float* bn2_g  = (const float*)d_in[20];
    const float* bn2_b  = (const float*)d_in[21];
    const float* bn2_m  = (const float*)d_in[22];
    const float* bn2_v  = (const float*)d_in[23];
    const float* w_se1  = (const float*)d_in[24];
    const float* b_se1  = (const float*)d_in[25];
    const float* bnse_g = (const float*)d_in[26];
    const float* bnse_b = (const float*)d_in[27];
    const float* bnse_m = (const float*)d_in[28];
    const float* bnse_v = (const float*)d_in[29];
    const float* w_se2  = (const float*)d_in[30];
    const float* b_se2  = (const float*)d_in[31];

    float* ws    = (float*)d_ws;
    float* k2d   = ws;
    float* v     = ws + 16777216;
    float* wd    = ws + 33554432;
    float* st    = ws + 46137344;
    float* gnsum  = st;
    float* gnsq   = st + 1024;
    float* gap    = st + 2048;
    float* gnmean = st + 2560;
    float* gnrstd = st + 3584;
    float* attn   = st + 4608;
    float* a_buf  = st;            // aliases gnsum (dead after kC2)

    hipMemsetAsync(gnsum, 0, 2560 * sizeof(float), stream);

    kA_key<<<1024, 256, 0, stream>>>(x, w_key, bnk_g, bnk_b, bnk_m, bnk_v, k2d, gap);
    kB_val<<<1024, 256, 0, stream>>>(x, w_1x1, bn1_g, bn1_b, bn1_m, bn1_v, v);
    kC_wd<<<512, 512, 0, stream>>>(x, k2d, w_e1, bne_g, bne_b, bne_m, bne_v,
                                   w_e2, b_e2, wd, gnsum, gnsq);
    kC2_gn<<<4, 256, 0, stream>>>(gnsum, gnsq, gnmean, gnrstd);
    kD_agg<<<1024, 256, 0, stream>>>(wd, v, gnmean, gnrstd, gn_g, gn_b,
                                     bn2_g, bn2_b, bn2_m, bn2_v,
                                     (float*)d_out, gap);
    kE1_a<<<2, 256, 0, stream>>>(gap, w_se1, b_se1, bnse_g, bnse_b, bnse_m, bnse_v, a_buf);
    kE2_attn<<<2, 256, 0, stream>>>(a_buf, w_se2, b_se2, attn);
    kF_out<<<16384, 256, 0, stream>>>((float*)d_out, k2d, attn);
}

// Round 9
// 309.992 us; speedup vs baseline: 2.2107x; 1.1513x over previous
//
#include <hip/hip_runtime.h>

#define EPSV 1e-5f
typedef unsigned short u16;
typedef unsigned int u32;

// Problem constants: B=4, N=8, B2=32, C=128, H=W=64, HW=4096, KS=3
// Workspace: k2d(bf16)@float-offset 0, v(bf16)@16777216, wd(bf16)@33554432,
// stats(fp32)@46137344: gnsum[1024] gnsq[1024] gap[512] gnmean[1024] gnrstd[1024] attn[1024]

__device__ __forceinline__ void block_sum_atomic(float val, float* dst) {
    __shared__ float sm[4];
    #pragma unroll
    for (int off = 32; off; off >>= 1) val += __shfl_down(val, off, 64);
    int lane = threadIdx.x & 63, wid = threadIdx.x >> 6;
    if (lane == 0) sm[wid] = val;
    __syncthreads();
    if (threadIdx.x == 0) atomicAdd(dst, sm[0] + sm[1] + sm[2] + sm[3]);
}

__device__ __forceinline__ u32 bfbits(float f) {   // RNE f32->bf16 bits
    u32 u = __float_as_uint(f);
    u += 0x7fff + ((u >> 16) & 1);
    return u >> 16;
}
__device__ __forceinline__ float bflo(u32 p) { return __uint_as_float(p << 16); }
__device__ __forceinline__ float bfhi(u32 p) { return __uint_as_float(p & 0xffff0000u); }

// ---- kA: key_embed = ReLU(BN(grouped temporal conv3d)) -> bf16 k2d, + gap ----
__global__ __launch_bounds__(256, 4) void kA_key(
    const float* __restrict__ x, const float* __restrict__ wk,
    const float* __restrict__ g, const float* __restrict__ bb,
    const float* __restrict__ m, const float* __restrict__ vr,
    u16* __restrict__ k2dh, float* __restrict__ gap)
{
    int blk   = blockIdx.x;
    int strip = blk & 3;
    int half  = (blk >> 2) & 1;
    int grp   = (blk >> 3) & 3;
    int b2    = blk >> 5;
    int px0   = strip * 1024 + threadIdx.x * 4;
    int bi = b2 >> 3, ni = b2 & 7;
    int gch = grp * 32;
    int ob  = gch + half * 16;

    float acc[16][4];
    #pragma unroll
    for (int j = 0; j < 16; ++j)
        acc[j][0] = acc[j][1] = acc[j][2] = acc[j][3] = 0.f;

    #pragma unroll
    for (int dk = 0; dk < 3; ++dk) {
        int nf = ni + dk - 1;
        if (nf >= 0 && nf < 8) {
            const float* xp  = x + ((bi * 8 + nf) * 128 + gch) * 4096 + px0;
            const float* wkp = wk + ob * 96 + dk;
            #pragma unroll 4
            for (int ci = 0; ci < 32; ++ci) {
                const float4 xv = *(const float4*)(xp + ci * 4096);
                #pragma unroll
                for (int j = 0; j < 16; ++j) {
                    float wv = wkp[j * 96 + ci * 3];
                    acc[j][0] = fmaf(xv.x, wv, acc[j][0]);
                    acc[j][1] = fmaf(xv.y, wv, acc[j][1]);
                    acc[j][2] = fmaf(xv.z, wv, acc[j][2]);
                    acc[j][3] = fmaf(xv.w, wv, acc[j][3]);
                }
            }
        }
    }

    int lane = threadIdx.x & 63, wid = threadIdx.x >> 6;
    __shared__ float ssum[16][4];
    #pragma unroll
    for (int j = 0; j < 16; ++j) {
        int o = ob + j;
        float s = g[o] * rsqrtf(vr[o] + EPSV);
        float t = bb[o] - m[o] * s;
        float r0 = fmaxf(fmaf(acc[j][0], s, t), 0.f);
        float r1 = fmaxf(fmaf(acc[j][1], s, t), 0.f);
        float r2 = fmaxf(fmaf(acc[j][2], s, t), 0.f);
        float r3 = fmaxf(fmaf(acc[j][3], s, t), 0.f);
        uint2 pk;
        pk.x = bfbits(r0) | (bfbits(r1) << 16);
        pk.y = bfbits(r2) | (bfbits(r3) << 16);
        *(uint2*)(k2dh + (b2 * 128 + o) * 4096 + px0) = pk;
        float lsum = r0 + r1 + r2 + r3;
        #pragma unroll
        for (int off = 32; off; off >>= 1) lsum += __shfl_down(lsum, off, 64);
        if (lane == 0) ssum[j][wid] = lsum;
    }
    __syncthreads();
    if (threadIdx.x < 16) {
        float* sr = ssum[threadIdx.x];
        atomicAdd(&gap[bi * 128 + ob + threadIdx.x], sr[0] + sr[1] + sr[2] + sr[3]);
    }
}

// ---- kB: v = BN(x @ w_1x1) -> bf16 ----
__global__ __launch_bounds__(256, 4) void kB_val(
    const float* __restrict__ x, const float* __restrict__ w,
    const float* __restrict__ g, const float* __restrict__ bb,
    const float* __restrict__ m, const float* __restrict__ vr,
    u16* __restrict__ vh)
{
    int blk   = blockIdx.x;
    int ocg   = blk & 7;
    int strip = (blk >> 3) & 3;
    int b2    = blk >> 5;
    int px0   = strip * 1024 + threadIdx.x * 4;
    const float* xp = x + b2 * 128 * 4096 + px0;
    const float* wp = w + ocg * 16 * 128;

    float acc[16][4];
    #pragma unroll
    for (int j = 0; j < 16; ++j)
        acc[j][0] = acc[j][1] = acc[j][2] = acc[j][3] = 0.f;

    #pragma unroll 4
    for (int c = 0; c < 128; ++c) {
        const float4 xv = *(const float4*)(xp + c * 4096);
        #pragma unroll
        for (int j = 0; j < 16; ++j) {
            float wv = wp[j * 128 + c];
            acc[j][0] = fmaf(xv.x, wv, acc[j][0]);
            acc[j][1] = fmaf(xv.y, wv, acc[j][1]);
            acc[j][2] = fmaf(xv.z, wv, acc[j][2]);
            acc[j][3] = fmaf(xv.w, wv, acc[j][3]);
        }
    }
    #pragma unroll
    for (int j = 0; j < 16; ++j) {
        int o = ocg * 16 + j;
        float s = g[o] * rsqrtf(vr[o] + EPSV);
        float t = bb[o] - m[o] * s;
        uint2 pk;
        pk.x = bfbits(fmaf(acc[j][0], s, t)) | (bfbits(fmaf(acc[j][1], s, t)) << 16);
        pk.y = bfbits(fmaf(acc[j][2], s, t)) | (bfbits(fmaf(acc[j][3], s, t)) << 16);
        *(uint2*)(vh + (b2 * 128 + o) * 4096 + px0) = pk;
    }
}

// ---- kC: e = ReLU(BN([x;k2d]@w_e1)), wd = e@w_e2+b -> bf16, GN partials ----
// Tile = 128 px; block = 512 threads (8 waves), wave q: e-ch [8q,8q+8),
// then wd rows [12q,12q+12). Thread = 2 px. Grid 1024 -> 4 blocks/CU.
// LDS bf16 e_s[64][128] = 16 KB.
__global__ __launch_bounds__(512, 8) void kC_wd(
    const float* __restrict__ x, const u16* __restrict__ k2dh,
    const float* __restrict__ we1,
    const float* __restrict__ eg, const float* __restrict__ eb,
    const float* __restrict__ em, const float* __restrict__ ev,
    const float* __restrict__ we2, const float* __restrict__ be2,
    u16* __restrict__ wdh, float* __restrict__ gnsum, float* __restrict__ gnsq)
{
    int tid  = threadIdx.x;
    int lane = tid & 63;
    int q    = __builtin_amdgcn_readfirstlane(tid >> 6);   // 0..7
    int tile = blockIdx.x & 31;
    int b2   = blockIdx.x >> 5;
    int pxl  = lane * 2;
    int px0  = tile * 128 + pxl;

    const float* xp  = x    + b2 * 128 * 4096 + px0;
    const u16*   kp  = k2dh + b2 * 128 * 4096 + px0;
    const float* w1q = we1 + q * 8 * 256;

    float acc[8][2];
    #pragma unroll
    for (int j = 0; j < 8; ++j) acc[j][0] = acc[j][1] = 0.f;

    #pragma unroll 4
    for (int c = 0; c < 128; ++c) {
        const float2 xv = *(const float2*)(xp + c * 4096);
        #pragma unroll
        for (int j = 0; j < 8; ++j) {
            float wv = w1q[j * 256 + c];
            acc[j][0] = fmaf(xv.x, wv, acc[j][0]);
            acc[j][1] = fmaf(xv.y, wv, acc[j][1]);
        }
    }
    #pragma unroll 4
    for (int c = 0; c < 128; ++c) {
        const u32 kv = *(const u32*)(kp + c * 4096);
        float k0 = bflo(kv), k1 = bfhi(kv);
        #pragma unroll
        for (int j = 0; j < 8; ++j) {
            float wv = w1q[j * 256 + 128 + c];
            acc[j][0] = fmaf(k0, wv, acc[j][0]);
            acc[j][1] = fmaf(k1, wv, acc[j][1]);
        }
    }

    __shared__ __align__(4) u16 e_s[64][128];   // bf16, 16 KB
    #pragma unroll
    for (int j = 0; j < 8; ++j) {
        int eo = q * 8 + j;
        float s = eg[eo] * rsqrtf(ev[eo] + EPSV);
        float t = eb[eo] - em[eo] * s;
        float r0 = fmaxf(fmaf(acc[j][0], s, t), 0.f);
        float r1 = fmaxf(fmaf(acc[j][1], s, t), 0.f);
        *(u32*)&e_s[eo][pxl] = bfbits(r0) | (bfbits(r1) << 16);
    }
    __syncthreads();

    int row0 = q * 12;
    const float* w2q = we2 + row0 * 64;
    float wa[12][2];
    #pragma unroll
    for (int j = 0; j < 12; ++j) {
        float b = be2[row0 + j];
        wa[j][0] = wa[j][1] = b;
    }
    #pragma unroll 4
    for (int c = 0; c < 64; ++c) {
        const u32 eu = *(const u32*)&e_s[c][pxl];
        float e0 = bflo(eu), e1 = bfhi(eu);
        #pragma unroll
        for (int j = 0; j < 12; ++j) {
            float wv = w2q[j * 64 + c];
            wa[j][0] = fmaf(e0, wv, wa[j][0]);
            wa[j][1] = fmaf(e1, wv, wa[j][1]);
        }
    }

    u16* wdp = wdh + (b2 * 96 + row0) * 4096 + px0;
    #pragma unroll
    for (int j = 0; j < 12; ++j)
        *(u32*)(wdp + j * 4096) = bfbits(wa[j][0]) | (bfbits(wa[j][1]) << 16);

    // GN partials: wave's 12 rows = 4 complete c1 groups
    #pragma unroll
    for (int jj = 0; jj < 4; ++jj) {
        float lsum = 0.f, lsq = 0.f;
        #pragma unroll
        for (int k = 0; k < 3; ++k)
            #pragma unroll
            for (int p = 0; p < 2; ++p) {
                float vv = wa[jj * 3 + k][p];
                lsum += vv; lsq += vv * vv;
            }
        #pragma unroll
        for (int off = 32; off; off >>= 1) {
            lsum += __shfl_down(lsum, off, 64);
            lsq  += __shfl_down(lsq,  off, 64);
        }
        if (lane == 0) {
            int c1 = q * 4 + jj;
            atomicAdd(&gnsum[b2 * 32 + c1], lsum);
            atomicAdd(&gnsq [b2 * 32 + c1], lsq);
        }
    }
}

// ---- kC2: finalize GroupNorm stats ----
__global__ __launch_bounds__(256) void kC2_gn(
    const float* __restrict__ gnsum, const float* __restrict__ gnsq,
    float* __restrict__ gnmean, float* __restrict__ gnrstd)
{
    int idx = blockIdx.x * 256 + threadIdx.x;
    const float inv = 1.f / 12288.f;
    float mu  = gnsum[idx] * inv;
    float var = fmaf(gnsq[idx], inv, -mu * mu);
    gnmean[idx] = mu;
    gnrstd[idx] = rsqrtf(fmaxf(var, 0.f) + EPSV);
}

// ---- kD: agg = SiLU(BN2(sum_k GN(wd)*unfold(v))) -> d_out (fp32), + gap ----
__global__ __launch_bounds__(256, 8) void kD_agg(
    const u16* __restrict__ wdh, const u16* __restrict__ vh,
    const float* __restrict__ gnmean, const float* __restrict__ gnrstd,
    const float* __restrict__ gng, const float* __restrict__ gnb,
    const float* __restrict__ g, const float* __restrict__ bb,
    const float* __restrict__ m, const float* __restrict__ vr,
    float* __restrict__ out, float* __restrict__ gap)
{
    int blk   = blockIdx.x;
    int strip = blk & 7;
    int c1    = (blk >> 3) & 31;
    int bi    = blk >> 8;            // grid = 4*32*8 = 1024
    int px0   = strip * 512 + threadIdx.x * 2;

    float sch[4], tch[4], gl[4];
    #pragma unroll
    for (int ch = 0; ch < 4; ++ch) {
        int c = c1 * 4 + ch;
        float s = g[c] * rsqrtf(vr[c] + EPSV);
        sch[ch] = s; tch[ch] = bb[c] - m[c] * s; gl[ch] = 0.f;
    }
    float gg[3], gb[3];
    #pragma unroll
    for (int k = 0; k < 3; ++k) { gg[k] = gng[c1 * 3 + k]; gb[k] = gnb[c1 * 3 + k]; }

    float2 vreg[4][3];
    #pragma unroll
    for (int ch = 0; ch < 4; ++ch) {
        vreg[ch][0] = make_float2(0.f, 0.f);
        u32 v1u = *(const u32*)(vh + ((bi * 8 + 0) * 128 + c1 * 4 + ch) * 4096 + px0);
        u32 v2u = *(const u32*)(vh + ((bi * 8 + 1) * 128 + c1 * 4 + ch) * 4096 + px0);
        vreg[ch][1] = make_float2(bflo(v1u), bfhi(v1u));
        vreg[ch][2] = make_float2(bflo(v2u), bfhi(v2u));
    }

    for (int ni = 0; ni < 8; ++ni) {
        int b2 = bi * 8 + ni;
        float mu = gnmean[b2 * 32 + c1], rs = gnrstd[b2 * 32 + c1];
        float2 wn[3];
        #pragma unroll
        for (int k = 0; k < 3; ++k) {
            int nf = ni + k - 1;
            if (nf >= 0 && nf < 8) {
                u32 wvu = *(const u32*)(wdh + ((b2 * 96 + c1 * 3 + k) * 4096 + px0));
                wn[k].x = fmaf((bflo(wvu) - mu) * rs, gg[k], gb[k]);
                wn[k].y = fmaf((bfhi(wvu) - mu) * rs, gg[k], gb[k]);
            } else {
                wn[k] = make_float2(0.f, 0.f);
            }
        }
        #pragma unroll
        for (int ch = 0; ch < 4; ++ch) {
            float a0 = 0.f, a1 = 0.f;
            #pragma unroll
            for (int k = 0; k < 3; ++k) {
                a0 = fmaf(wn[k].x, vreg[ch][k].x, a0);
                a1 = fmaf(wn[k].y, vreg[ch][k].y, a1);
            }
            float y0 = fmaf(a0, sch[ch], tch[ch]);
            float y1 = fmaf(a1, sch[ch], tch[ch]);
            float2 r;
            r.x = y0 / (1.f + __expf(-y0));
            r.y = y1 / (1.f + __expf(-y1));
            *(float2*)(out + (b2 * 128 + c1 * 4 + ch) * 4096 + px0) = r;
            gl[ch] += r.x + r.y;
        }
        if (ni < 7) {
            #pragma unroll
            for (int ch = 0; ch < 4; ++ch) {
                vreg[ch][0] = vreg[ch][1];
                vreg[ch][1] = vreg[ch][2];
                if (ni + 2 < 8) {
                    u32 vu = *(const u32*)(vh + ((bi * 8 + ni + 2) * 128 + c1 * 4 + ch) * 4096 + px0);
                    vreg[ch][2] = make_float2(bflo(vu), bfhi(vu));
                }
            }
        }
    }

    __shared__ float sm[4][4];
    int lane = threadIdx.x & 63, wid = threadIdx.x >> 6;
    #pragma unroll
    for (int ch = 0; ch < 4; ++ch) {
        float s = gl[ch];
        #pragma unroll
        for (int off = 32; off; off >>= 1) s += __shfl_down(s, off, 64);
        if (lane == 0) sm[ch][wid] = s;
    }
    __syncthreads();
    if (threadIdx.x < 4) {
        float* sr = sm[threadIdx.x];
        atomicAdd(&gap[bi * 128 + c1 * 4 + threadIdx.x], sr[0] + sr[1] + sr[2] + sr[3]);
    }
}

// ---- kE1: a = ReLU(BNvec(gap/32768 @ w1^T + b1)) ----
__global__ __launch_bounds__(256) void kE1_a(
    const float* __restrict__ gap,
    const float* __restrict__ w1, const float* __restrict__ b1,
    const float* __restrict__ g, const float* __restrict__ bb,
    const float* __restrict__ m, const float* __restrict__ vr,
    float* __restrict__ a_buf)
{
    int idx = blockIdx.x * 256 + threadIdx.x;
    int bi = idx >> 7, oc = idx & 127;
    float acc = b1[oc];
    const float* gp = gap + bi * 128;
    const float* wp = w1 + oc * 128;
    for (int c = 0; c < 128; c += 4) {
        const float4 w4 = *(const float4*)(wp + c);
        acc = fmaf(gp[c + 0] * (1.f / 32768.f), w4.x, acc);
        acc = fmaf(gp[c + 1] * (1.f / 32768.f), w4.y, acc);
        acc = fmaf(gp[c + 2] * (1.f / 32768.f), w4.z, acc);
        acc = fmaf(gp[c + 3] * (1.f / 32768.f), w4.w, acc);
    }
    float s = g[oc] * rsqrtf(vr[oc] + EPSV);
    a_buf[bi * 128 + oc] = fmaxf(fmaf(acc, s, bb[oc] - m[oc] * s), 0.f);
}

// ---- kE2: attn = softmax over radix-2 pairs ----
__global__ __launch_bounds__(256) void kE2_attn(
    const float* __restrict__ a_buf,
    const float* __restrict__ w2, const float* __restrict__ b2v,
    float* __restrict__ attn)
{
    int idx = blockIdx.x * 256 + threadIdx.x;
    int bi = idx >> 7, cc = idx & 127;
    float l0 = b2v[cc * 2], l1 = b2v[cc * 2 + 1];
    const float* ap  = a_buf + bi * 128;
    const float* w0p = w2 + (cc * 2) * 128;
    const float* w1p = w2 + (cc * 2 + 1) * 128;
    for (int j = 0; j < 128; j += 4) {
        const float4 wa4 = *(const float4*)(w0p + j);
        const float4 wb4 = *(const float4*)(w1p + j);
        l0 = fmaf(ap[j + 0], wa4.x, l0); l1 = fmaf(ap[j + 0], wb4.x, l1);
        l0 = fmaf(ap[j + 1], wa4.y, l0); l1 = fmaf(ap[j + 1], wb4.y, l1);
        l0 = fmaf(ap[j + 2], wa4.z, l0); l1 = fmaf(ap[j + 2], wb4.z, l1);
        l0 = fmaf(ap[j + 3], wa4.w, l0); l1 = fmaf(ap[j + 3], wb4.w, l1);
    }
    float mx = fmaxf(l0, l1);
    float e0 = __expf(l0 - mx), e1 = __expf(l1 - mx);
    float inv = 1.f / (e0 + e1);
    attn[bi * 256 + cc * 2]     = e0 * inv;
    attn[bi * 256 + cc * 2 + 1] = e1 * inv;
}

// ---- kF: out = attn0*agg + attn1*k2d(bf16); thread = 4 px ----
__global__ __launch_bounds__(256, 8) void kF_out(
    float* __restrict__ out, const u16* __restrict__ k2dh,
    const float* __restrict__ attn)
{
    int blk   = blockIdx.x;
    int strip = blk & 3;
    int c     = (blk >> 2) & 127;
    int b2    = blk >> 9;
    int bi    = b2 >> 3;
    float a0 = attn[bi * 256 + c * 2];
    float a1 = attn[bi * 256 + c * 2 + 1];
    int idx = (b2 * 128 + c) * 4096 + strip * 1024 + threadIdx.x * 4;
    float4 o4 = *(const float4*)(out + idx);
    uint2 k4 = *(const uint2*)(k2dh + idx);
    float4 r;
    r.x = fmaf(a0, o4.x, a1 * bflo(k4.x));
    r.y = fmaf(a0, o4.y, a1 * bfhi(k4.x));
    r.z = fmaf(a0, o4.z, a1 * bflo(k4.y));
    r.w = fmaf(a0, o4.w, a1 * bfhi(k4.y));
    *(float4*)(out + idx) = r;
}

extern "C" void kernel_launch(void* const* d_in, const int* in_sizes, int n_in,
                              void* d_out, int out_size, void* d_ws, size_t ws_size,
                              hipStream_t stream)
{
    const float* x      = (const float*)d_in[0];
    const float* w_key  = (const float*)d_in[1];
    const float* bnk_g  = (const float*)d_in[2];
    const float* bnk_b  = (const float*)d_in[3];
    const float* bnk_m  = (const float*)d_in[4];
    const float* bnk_v  = (const float*)d_in[5];
    const float* w_e1   = (const float*)d_in[6];
    const float* bne_g  = (const float*)d_in[7];
    const float* bne_b  = (const float*)d_in[8];
    const float* bne_m  = (const float*)d_in[9];
    const float* bne_v  = (const float*)d_in[10];
    const float* w_e2   = (const float*)d_in[11];
    const float* b_e2   = (const float*)d_in[12];
    const float* gn_g   = (const float*)d_in[13];
    const float* gn_b   = (const float*)d_in[14];
    const float* w_1x1  = (const float*)d_in[15];
    const float* bn1_g  = (const float*)d_in[16];
    const float* bn1_b  = (const float*)d_in[17];
    const float* bn1_m  = (const float*)d_in[18];
    const float* bn1_v  = (const float*)d_in[19];
    const float* bn2_g  = (const float*)d_in[20];
    const float* bn2_b  = (const float*)d_in[21];
    const float* bn2_m  = (const float*)d_in[22];
    const float* bn2_v  = (const float*)d_in[23];
    const float* w_se1  = (const float*)d_in[24];
    const float* b_se1  = (const float*)d_in[25];
    const float* bnse_g = (const float*)d_in[26];
    const float* bnse_b = (const float*)d_in[27];
    const float* bnse_m = (const float*)d_in[28];
    const float* bnse_v = (const float*)d_in[29];
    const float* w_se2  = (const float*)d_in[30];
    const float* b_se2  = (const float*)d_in[31];

    float* ws    = (float*)d_ws;
    u16*  k2dh  = (u16*)ws;                       // bf16, 16.7M elems
    u16*  vh    = (u16*)(ws + 16777216);          // bf16
    u16*  wdh   = (u16*)(ws + 33554432);          // bf16
    float* st    = ws + 46137344;
    float* gnsum  = st;
    float* gnsq   = st + 1024;
    float* gap    = st + 2048;
    float* gnmean = st + 2560;
    float* gnrstd = st + 3584;
    float* attn   = st + 4608;
    float* a_buf  = st;            // aliases gnsum (dead after kC2)

    hipMemsetAsync(gnsum, 0, 2560 * sizeof(float), stream);

    kA_key<<<1024, 256, 0, stream>>>(x, w_key, bnk_g, bnk_b, bnk_m, bnk_v, k2dh, gap);
    kB_val<<<1024, 256, 0, stream>>>(x, w_1x1, bn1_g, bn1_b, bn1_m, bn1_v, vh);
    kC_wd<<<1024, 512, 0, stream>>>(x, k2dh, w_e1, bne_g, bne_b, bne_m, bne_v,
                                    w_e2, b_e2, wdh, gnsum, gnsq);
    kC2_gn<<<4, 256, 0, stream>>>(gnsum, gnsq, gnmean, gnrstd);
    kD_agg<<<1024, 256, 0, stream>>>(wdh, vh, gnmean, gnrstd, gn_g, gn_b,
                                     bn2_g, bn2_b, bn2_m, bn2_v,
                                     (float*)d_out, gap);
    kE1_a<<<2, 256, 0, stream>>>(gap, w_se1, b_se1, bnse_g, bnse_b, bnse_m, bnse_v, a_buf);
    kE2_attn<<<2, 256, 0, stream>>>(a_buf, w_se2, b_se2, attn);
    kF_out<<<16384, 256, 0, stream>>>((float*)d_out, k2dh, attn);
}

// Round 10
// 284.009 us; speedup vs baseline: 2.4129x; 1.0915x over previous
//
#include <hip/hip_runtime.h>

#define EPSV 1e-5f
typedef unsigned short u16;
typedef unsigned int u32;

// Problem constants: B=4, N=8, B2=32, C=128, H=W=64, HW=4096, KS=3
// Workspace: k2dh(bf16) @u16-offset 0 (16.7M u16 = 32MB),
//            aggh(bf16) @float-offset 8388608 (upper half of k2d slot, 32MB),
//            vh(bf16) @float-offset 16777216, wdh(bf16) @33554432,
//            stats(fp32)@46137344: gnsum[1024] gnsq[1024] gap[512] gnmean[1024] gnrstd[1024] attn[1024]

__device__ __forceinline__ u32 bfbits(float f) {   // RNE f32->bf16 bits
    u32 u = __float_as_uint(f);
    u += 0x7fff + ((u >> 16) & 1);
    return u >> 16;
}
__device__ __forceinline__ float bflo(u32 p) { return __uint_as_float(p << 16); }
__device__ __forceinline__ float bfhi(u32 p) { return __uint_as_float(p & 0xffff0000u); }

// ---- kA: key_embed = ReLU(BN(grouped temporal conv3d)) -> bf16 k2d, + gap ----
__global__ __launch_bounds__(256, 4) void kA_key(
    const float* __restrict__ x, const float* __restrict__ wk,
    const float* __restrict__ g, const float* __restrict__ bb,
    const float* __restrict__ m, const float* __restrict__ vr,
    u16* __restrict__ k2dh, float* __restrict__ gap)
{
    int blk   = blockIdx.x;
    int strip = blk & 3;
    int half  = (blk >> 2) & 1;
    int grp   = (blk >> 3) & 3;
    int b2    = blk >> 5;
    int px0   = strip * 1024 + threadIdx.x * 4;
    int bi = b2 >> 3, ni = b2 & 7;
    int gch = grp * 32;
    int ob  = gch + half * 16;

    float acc[16][4];
    #pragma unroll
    for (int j = 0; j < 16; ++j)
        acc[j][0] = acc[j][1] = acc[j][2] = acc[j][3] = 0.f;

    #pragma unroll
    for (int dk = 0; dk < 3; ++dk) {
        int nf = ni + dk - 1;
        if (nf >= 0 && nf < 8) {
            const float* xp  = x + ((bi * 8 + nf) * 128 + gch) * 4096 + px0;
            const float* wkp = wk + ob * 96 + dk;
            #pragma unroll 4
            for (int ci = 0; ci < 32; ++ci) {
                const float4 xv = *(const float4*)(xp + ci * 4096);
                #pragma unroll
                for (int j = 0; j < 16; ++j) {
                    float wv = wkp[j * 96 + ci * 3];
                    acc[j][0] = fmaf(xv.x, wv, acc[j][0]);
                    acc[j][1] = fmaf(xv.y, wv, acc[j][1]);
                    acc[j][2] = fmaf(xv.z, wv, acc[j][2]);
                    acc[j][3] = fmaf(xv.w, wv, acc[j][3]);
                }
            }
        }
    }

    int lane = threadIdx.x & 63, wid = threadIdx.x >> 6;
    __shared__ float ssum[16][4];
    #pragma unroll
    for (int j = 0; j < 16; ++j) {
        int o = ob + j;
        float s = g[o] * rsqrtf(vr[o] + EPSV);
        float t = bb[o] - m[o] * s;
        float r0 = fmaxf(fmaf(acc[j][0], s, t), 0.f);
        float r1 = fmaxf(fmaf(acc[j][1], s, t), 0.f);
        float r2 = fmaxf(fmaf(acc[j][2], s, t), 0.f);
        float r3 = fmaxf(fmaf(acc[j][3], s, t), 0.f);
        uint2 pk;
        pk.x = bfbits(r0) | (bfbits(r1) << 16);
        pk.y = bfbits(r2) | (bfbits(r3) << 16);
        *(uint2*)(k2dh + (b2 * 128 + o) * 4096 + px0) = pk;
        float lsum = r0 + r1 + r2 + r3;
        #pragma unroll
        for (int off = 32; off; off >>= 1) lsum += __shfl_down(lsum, off, 64);
        if (lane == 0) ssum[j][wid] = lsum;
    }
    __syncthreads();
    if (threadIdx.x < 16) {
        float* sr = ssum[threadIdx.x];
        atomicAdd(&gap[bi * 128 + ob + threadIdx.x], sr[0] + sr[1] + sr[2] + sr[3]);
    }
}

// ---- kB: v = BN(x @ w_1x1) -> bf16 ----
__global__ __launch_bounds__(256, 4) void kB_val(
    const float* __restrict__ x, const float* __restrict__ w,
    const float* __restrict__ g, const float* __restrict__ bb,
    const float* __restrict__ m, const float* __restrict__ vr,
    u16* __restrict__ vh)
{
    int blk   = blockIdx.x;
    int ocg   = blk & 7;
    int strip = (blk >> 3) & 3;
    int b2    = blk >> 5;
    int px0   = strip * 1024 + threadIdx.x * 4;
    const float* xp = x + b2 * 128 * 4096 + px0;
    const float* wp = w + ocg * 16 * 128;

    float acc[16][4];
    #pragma unroll
    for (int j = 0; j < 16; ++j)
        acc[j][0] = acc[j][1] = acc[j][2] = acc[j][3] = 0.f;

    #pragma unroll 4
    for (int c = 0; c < 128; ++c) {
        const float4 xv = *(const float4*)(xp + c * 4096);
        #pragma unroll
        for (int j = 0; j < 16; ++j) {
            float wv = wp[j * 128 + c];
            acc[j][0] = fmaf(xv.x, wv, acc[j][0]);
            acc[j][1] = fmaf(xv.y, wv, acc[j][1]);
            acc[j][2] = fmaf(xv.z, wv, acc[j][2]);
            acc[j][3] = fmaf(xv.w, wv, acc[j][3]);
        }
    }
    #pragma unroll
    for (int j = 0; j < 16; ++j) {
        int o = ocg * 16 + j;
        float s = g[o] * rsqrtf(vr[o] + EPSV);
        float t = bb[o] - m[o] * s;
        uint2 pk;
        pk.x = bfbits(fmaf(acc[j][0], s, t)) | (bfbits(fmaf(acc[j][1], s, t)) << 16);
        pk.y = bfbits(fmaf(acc[j][2], s, t)) | (bfbits(fmaf(acc[j][3], s, t)) << 16);
        *(uint2*)(vh + (b2 * 128 + o) * 4096 + px0) = pk;
    }
}

// ---- kC: e = ReLU(BN([x;k2d]@w_e1)), wd = e@w_e2+b -> bf16, GN partials ----
// Round-8 shape: block 512 thr = 8 waves; tile 256 px; thread = 4 px (float4 x,
// uint2 k2d). Wave q: e-ch [8q,8q+8), wd rows [12q,12q+12). Grid 512.
// LDS bf16 e_s[64][256] = 32 KB.
__global__ __launch_bounds__(512, 4) void kC_wd(
    const float* __restrict__ x, const u16* __restrict__ k2dh,
    const float* __restrict__ we1,
    const float* __restrict__ eg, const float* __restrict__ eb,
    const float* __restrict__ em, const float* __restrict__ ev,
    const float* __restrict__ we2, const float* __restrict__ be2,
    u16* __restrict__ wdh, float* __restrict__ gnsum, float* __restrict__ gnsq)
{
    int tid  = threadIdx.x;
    int lane = tid & 63;
    int q    = __builtin_amdgcn_readfirstlane(tid >> 6);   // 0..7, wave-uniform
    int tile = blockIdx.x & 15;
    int b2   = blockIdx.x >> 4;
    int pxl  = lane * 4;
    int px0  = tile * 256 + pxl;

    const float* xp  = x    + b2 * 128 * 4096 + px0;
    const u16*   kp  = k2dh + b2 * 128 * 4096 + px0;
    const float* w1q = we1 + q * 8 * 256;

    float acc[8][4];
    #pragma unroll
    for (int j = 0; j < 8; ++j)
        acc[j][0] = acc[j][1] = acc[j][2] = acc[j][3] = 0.f;

    #pragma unroll 4
    for (int c = 0; c < 128; ++c) {
        const float4 xv = *(const float4*)(xp + c * 4096);
        #pragma unroll
        for (int j = 0; j < 8; ++j) {
            float wv = w1q[j * 256 + c];
            acc[j][0] = fmaf(xv.x, wv, acc[j][0]);
            acc[j][1] = fmaf(xv.y, wv, acc[j][1]);
            acc[j][2] = fmaf(xv.z, wv, acc[j][2]);
            acc[j][3] = fmaf(xv.w, wv, acc[j][3]);
        }
    }
    #pragma unroll 4
    for (int c = 0; c < 128; ++c) {
        const uint2 kv = *(const uint2*)(kp + c * 4096);
        float k0 = bflo(kv.x), k1 = bfhi(kv.x);
        float k2 = bflo(kv.y), k3 = bfhi(kv.y);
        #pragma unroll
        for (int j = 0; j < 8; ++j) {
            float wv = w1q[j * 256 + 128 + c];
            acc[j][0] = fmaf(k0, wv, acc[j][0]);
            acc[j][1] = fmaf(k1, wv, acc[j][1]);
            acc[j][2] = fmaf(k2, wv, acc[j][2]);
            acc[j][3] = fmaf(k3, wv, acc[j][3]);
        }
    }

    __shared__ __align__(8) u16 e_s[64][256];   // bf16, 32 KB
    #pragma unroll
    for (int j = 0; j < 8; ++j) {
        int eo = q * 8 + j;
        float s = eg[eo] * rsqrtf(ev[eo] + EPSV);
        float t = eb[eo] - em[eo] * s;
        float r0 = fmaxf(fmaf(acc[j][0], s, t), 0.f);
        float r1 = fmaxf(fmaf(acc[j][1], s, t), 0.f);
        float r2 = fmaxf(fmaf(acc[j][2], s, t), 0.f);
        float r3 = fmaxf(fmaf(acc[j][3], s, t), 0.f);
        uint2 pk;
        pk.x = bfbits(r0) | (bfbits(r1) << 16);
        pk.y = bfbits(r2) | (bfbits(r3) << 16);
        *(uint2*)&e_s[eo][pxl] = pk;
    }
    __syncthreads();

    int row0 = q * 12;
    const float* w2q = we2 + row0 * 64;
    float wa[12][4];
    #pragma unroll
    for (int j = 0; j < 12; ++j) {
        float b = be2[row0 + j];
        wa[j][0] = wa[j][1] = wa[j][2] = wa[j][3] = b;
    }
    #pragma unroll 4
    for (int c = 0; c < 64; ++c) {
        const uint2 eu = *(const uint2*)&e_s[c][pxl];
        float e0 = bflo(eu.x), e1 = bfhi(eu.x);
        float e2 = bflo(eu.y), e3 = bfhi(eu.y);
        #pragma unroll
        for (int j = 0; j < 12; ++j) {
            float wv = w2q[j * 64 + c];
            wa[j][0] = fmaf(e0, wv, wa[j][0]);
            wa[j][1] = fmaf(e1, wv, wa[j][1]);
            wa[j][2] = fmaf(e2, wv, wa[j][2]);
            wa[j][3] = fmaf(e3, wv, wa[j][3]);
        }
    }

    u16* wdp = wdh + (b2 * 96 + row0) * 4096 + px0;
    #pragma unroll
    for (int j = 0; j < 12; ++j) {
        uint2 pk;
        pk.x = bfbits(wa[j][0]) | (bfbits(wa[j][1]) << 16);
        pk.y = bfbits(wa[j][2]) | (bfbits(wa[j][3]) << 16);
        *(uint2*)(wdp + j * 4096) = pk;
    }

    // GN partials: wave's 12 rows = 4 complete c1 groups
    #pragma unroll
    for (int jj = 0; jj < 4; ++jj) {
        float lsum = 0.f, lsq = 0.f;
        #pragma unroll
        for (int k = 0; k < 3; ++k)
            #pragma unroll
            for (int p = 0; p < 4; ++p) {
                float vv = wa[jj * 3 + k][p];
                lsum += vv; lsq += vv * vv;
            }
        #pragma unroll
        for (int off = 32; off; off >>= 1) {
            lsum += __shfl_down(lsum, off, 64);
            lsq  += __shfl_down(lsq,  off, 64);
        }
        if (lane == 0) {
            int c1 = q * 4 + jj;
            atomicAdd(&gnsum[b2 * 32 + c1], lsum);
            atomicAdd(&gnsq [b2 * 32 + c1], lsq);
        }
    }
}

// ---- kC2: finalize GroupNorm stats ----
__global__ __launch_bounds__(256) void kC2_gn(
    const float* __restrict__ gnsum, const float* __restrict__ gnsq,
    float* __restrict__ gnmean, float* __restrict__ gnrstd)
{
    int idx = blockIdx.x * 256 + threadIdx.x;
    const float inv = 1.f / 12288.f;
    float mu  = gnsum[idx] * inv;
    float var = fmaf(gnsq[idx], inv, -mu * mu);
    gnmean[idx] = mu;
    gnrstd[idx] = rsqrtf(fmaxf(var, 0.f) + EPSV);
}

// ---- kD: agg = SiLU(BN2(sum_k GN(wd)*unfold(v))) -> bf16 aggh, + gap ----
__global__ __launch_bounds__(256, 8) void kD_agg(
    const u16* __restrict__ wdh, const u16* __restrict__ vh,
    const float* __restrict__ gnmean, const float* __restrict__ gnrstd,
    const float* __restrict__ gng, const float* __restrict__ gnb,
    const float* __restrict__ g, const float* __restrict__ bb,
    const float* __restrict__ m, const float* __restrict__ vr,
    u16* __restrict__ aggh, float* __restrict__ gap)
{
    int blk   = blockIdx.x;
    int strip = blk & 7;
    int c1    = (blk >> 3) & 31;
    int bi    = blk >> 8;            // grid = 4*32*8 = 1024
    int px0   = strip * 512 + threadIdx.x * 2;

    float sch[4], tch[4], gl[4];
    #pragma unroll
    for (int ch = 0; ch < 4; ++ch) {
        int c = c1 * 4 + ch;
        float s = g[c] * rsqrtf(vr[c] + EPSV);
        sch[ch] = s; tch[ch] = bb[c] - m[c] * s; gl[ch] = 0.f;
    }
    float gg[3], gb[3];
    #pragma unroll
    for (int k = 0; k < 3; ++k) { gg[k] = gng[c1 * 3 + k]; gb[k] = gnb[c1 * 3 + k]; }

    float2 vreg[4][3];
    #pragma unroll
    for (int ch = 0; ch < 4; ++ch) {
        vreg[ch][0] = make_float2(0.f, 0.f);
        u32 v1u = *(const u32*)(vh + ((bi * 8 + 0) * 128 + c1 * 4 + ch) * 4096 + px0);
        u32 v2u = *(const u32*)(vh + ((bi * 8 + 1) * 128 + c1 * 4 + ch) * 4096 + px0);
        vreg[ch][1] = make_float2(bflo(v1u), bfhi(v1u));
        vreg[ch][2] = make_float2(bflo(v2u), bfhi(v2u));
    }

    for (int ni = 0; ni < 8; ++ni) {
        int b2 = bi * 8 + ni;
        float mu = gnmean[b2 * 32 + c1], rs = gnrstd[b2 * 32 + c1];
        float2 wn[3];
        #pragma unroll
        for (int k = 0; k < 3; ++k) {
            int nf = ni + k - 1;
            if (nf >= 0 && nf < 8) {
                u32 wvu = *(const u32*)(wdh + ((b2 * 96 + c1 * 3 + k) * 4096 + px0));
                wn[k].x = fmaf((bflo(wvu) - mu) * rs, gg[k], gb[k]);
                wn[k].y = fmaf((bfhi(wvu) - mu) * rs, gg[k], gb[k]);
            } else {
                wn[k] = make_float2(0.f, 0.f);
            }
        }
        #pragma unroll
        for (int ch = 0; ch < 4; ++ch) {
            float a0 = 0.f, a1 = 0.f;
            #pragma unroll
            for (int k = 0; k < 3; ++k) {
                a0 = fmaf(wn[k].x, vreg[ch][k].x, a0);
                a1 = fmaf(wn[k].y, vreg[ch][k].y, a1);
            }
            float y0 = fmaf(a0, sch[ch], tch[ch]);
            float y1 = fmaf(a1, sch[ch], tch[ch]);
            float r0 = y0 / (1.f + __expf(-y0));
            float r1 = y1 / (1.f + __expf(-y1));
            *(u32*)(aggh + (b2 * 128 + c1 * 4 + ch) * 4096 + px0) =
                bfbits(r0) | (bfbits(r1) << 16);
            gl[ch] += r0 + r1;
        }
        if (ni < 7) {
            #pragma unroll
            for (int ch = 0; ch < 4; ++ch) {
                vreg[ch][0] = vreg[ch][1];
                vreg[ch][1] = vreg[ch][2];
                if (ni + 2 < 8) {
                    u32 vu = *(const u32*)(vh + ((bi * 8 + ni + 2) * 128 + c1 * 4 + ch) * 4096 + px0);
                    vreg[ch][2] = make_float2(bflo(vu), bfhi(vu));
                }
            }
        }
    }

    __shared__ float sm[4][4];
    int lane = threadIdx.x & 63, wid = threadIdx.x >> 6;
    #pragma unroll
    for (int ch = 0; ch < 4; ++ch) {
        float s = gl[ch];
        #pragma unroll
        for (int off = 32; off; off >>= 1) s += __shfl_down(s, off, 64);
        if (lane == 0) sm[ch][wid] = s;
    }
    __syncthreads();
    if (threadIdx.x < 4) {
        float* sr = sm[threadIdx.x];
        atomicAdd(&gap[bi * 128 + c1 * 4 + threadIdx.x], sr[0] + sr[1] + sr[2] + sr[3]);
    }
}

// ---- kE1: a = ReLU(BNvec(gap/32768 @ w1^T + b1)) ----
__global__ __launch_bounds__(256) void kE1_a(
    const float* __restrict__ gap,
    const float* __restrict__ w1, const float* __restrict__ b1,
    const float* __restrict__ g, const float* __restrict__ bb,
    const float* __restrict__ m, const float* __restrict__ vr,
    float* __restrict__ a_buf)
{
    int idx = blockIdx.x * 256 + threadIdx.x;
    int bi = idx >> 7, oc = idx & 127;
    float acc = b1[oc];
    const float* gp = gap + bi * 128;
    const float* wp = w1 + oc * 128;
    for (int c = 0; c < 128; c += 4) {
        const float4 w4 = *(const float4*)(wp + c);
        acc = fmaf(gp[c + 0] * (1.f / 32768.f), w4.x, acc);
        acc = fmaf(gp[c + 1] * (1.f / 32768.f), w4.y, acc);
        acc = fmaf(gp[c + 2] * (1.f / 32768.f), w4.z, acc);
        acc = fmaf(gp[c + 3] * (1.f / 32768.f), w4.w, acc);
    }
    float s = g[oc] * rsqrtf(vr[oc] + EPSV);
    a_buf[bi * 128 + oc] = fmaxf(fmaf(acc, s, bb[oc] - m[oc] * s), 0.f);
}

// ---- kE2: attn = softmax over radix-2 pairs ----
__global__ __launch_bounds__(256) void kE2_attn(
    const float* __restrict__ a_buf,
    const float* __restrict__ w2, const float* __restrict__ b2v,
    float* __restrict__ attn)
{
    int idx = blockIdx.x * 256 + threadIdx.x;
    int bi = idx >> 7, cc = idx & 127;
    float l0 = b2v[cc * 2], l1 = b2v[cc * 2 + 1];
    const float* ap  = a_buf + bi * 128;
    const float* w0p = w2 + (cc * 2) * 128;
    const float* w1p = w2 + (cc * 2 + 1) * 128;
    for (int j = 0; j < 128; j += 4) {
        const float4 wa4 = *(const float4*)(w0p + j);
        const float4 wb4 = *(const float4*)(w1p + j);
        l0 = fmaf(ap[j + 0], wa4.x, l0); l1 = fmaf(ap[j + 0], wb4.x, l1);
        l0 = fmaf(ap[j + 1], wa4.y, l0); l1 = fmaf(ap[j + 1], wb4.y, l1);
        l0 = fmaf(ap[j + 2], wa4.z, l0); l1 = fmaf(ap[j + 2], wb4.z, l1);
        l0 = fmaf(ap[j + 3], wa4.w, l0); l1 = fmaf(ap[j + 3], wb4.w, l1);
    }
    float mx = fmaxf(l0, l1);
    float e0 = __expf(l0 - mx), e1 = __expf(l1 - mx);
    float inv = 1.f / (e0 + e1);
    attn[bi * 256 + cc * 2]     = e0 * inv;
    attn[bi * 256 + cc * 2 + 1] = e1 * inv;
}

// ---- kF: out = attn0*agg(bf16) + attn1*k2d(bf16) -> fp32; thread = 4 px ----
__global__ __launch_bounds__(256, 8) void kF_out(
    float* __restrict__ out, const u16* __restrict__ aggh,
    const u16* __restrict__ k2dh, const float* __restrict__ attn)
{
    int blk   = blockIdx.x;
    int strip = blk & 3;
    int c     = (blk >> 2) & 127;
    int b2    = blk >> 9;
    int bi    = b2 >> 3;
    float a0 = attn[bi * 256 + c * 2];
    float a1 = attn[bi * 256 + c * 2 + 1];
    int idx = (b2 * 128 + c) * 4096 + strip * 1024 + threadIdx.x * 4;
    uint2 g4 = *(const uint2*)(aggh + idx);
    uint2 k4 = *(const uint2*)(k2dh + idx);
    float4 r;
    r.x = fmaf(a0, bflo(g4.x), a1 * bflo(k4.x));
    r.y = fmaf(a0, bfhi(g4.x), a1 * bfhi(k4.x));
    r.z = fmaf(a0, bflo(g4.y), a1 * bflo(k4.y));
    r.w = fmaf(a0, bfhi(g4.y), a1 * bfhi(k4.y));
    *(float4*)(out + idx) = r;
}

extern "C" void kernel_launch(void* const* d_in, const int* in_sizes, int n_in,
                              void* d_out, int out_size, void* d_ws, size_t ws_size,
                              hipStream_t stream)
{
    const float* x      = (const float*)d_in[0];
    const float* w_key  = (const float*)d_in[1];
    const float* bnk_g  = (const float*)d_in[2];
    const float* bnk_b  = (const float*)d_in[3];
    const float* bnk_m  = (const float*)d_in[4];
    const float* bnk_v  = (const float*)d_in[5];
    const float* w_e1   = (const float*)d_in[6];
    const float* bne_g  = (const float*)d_in[7];
    const float* bne_b  = (const float*)d_in[8];
    const float* bne_m  = (const float*)d_in[9];
    const float* bne_v  = (const float*)d_in[10];
    const float* w_e2   = (const float*)d_in[11];
    const float* b_e2   = (const float*)d_in[12];
    const float* gn_g   = (const float*)d_in[13];
    const float* gn_b   = (const float*)d_in[14];
    const float* w_1x1  = (const float*)d_in[15];
    const float* bn1_g  = (const float*)d_in[16];
    const float* bn1_b  = (const float*)d_in[17];
    const float* bn1_m  = (const float*)d_in[18];
    const float* bn1_v  = (const float*)d_in[19];
    const float* bn2_g  = (const float*)d_in[20];
    const float* bn2_b  = (const float*)d_in[21];
    const float* bn2_m  = (const float*)d_in[22];
    const float* bn2_v  = (const float*)d_in[23];
    const float* w_se1  = (const float*)d_in[24];
    const float* b_se1  = (const float*)d_in[25];
    const float* bnse_g = (const float*)d_in[26];
    const float* bnse_b = (const float*)d_in[27];
    const float* bnse_m = (const float*)d_in[28];
    const float* bnse_v = (const float*)d_in[29];
    const float* w_se2  = (const float*)d_in[30];
    const float* b_se2  = (const float*)d_in[31];

    float* ws    = (float*)d_ws;
    u16*  k2dh  = (u16*)ws;                       // bf16, 16.7M elems (32MB)
    u16*  aggh  = (u16*)(ws + 8388608);           // bf16, upper half of k2d slot
    u16*  vh    = (u16*)(ws + 16777216);          // bf16
    u16*  wdh   = (u16*)(ws + 33554432);          // bf16
    float* st    = ws + 46137344;
    float* gnsum  = st;
    float* gnsq   = st + 1024;
    float* gap    = st + 2048;
    float* gnmean = st + 2560;
    float* gnrstd = st + 3584;
    float* attn   = st + 4608;
    float* a_buf  = st;            // aliases gnsum (dead after kC2)

    hipMemsetAsync(gnsum, 0, 2560 * sizeof(float), stream);

    kA_key<<<1024, 256, 0, stream>>>(x, w_key, bnk_g, bnk_b, bnk_m, bnk_v, k2dh, gap);
    kB_val<<<1024, 256, 0, stream>>>(x, w_1x1, bn1_g, bn1_b, bn1_m, bn1_v, vh);
    kC_wd<<<512, 512, 0, stream>>>(x, k2dh, w_e1, bne_g, bne_b, bne_m, bne_v,
                                   w_e2, b_e2, wdh, gnsum, gnsq);
    kC2_gn<<<4, 256, 0, stream>>>(gnsum, gnsq, gnmean, gnrstd);
    kD_agg<<<1024, 256, 0, stream>>>(wdh, vh, gnmean, gnrstd, gn_g, gn_b,
                                     bn2_g, bn2_b, bn2_m, bn2_v, aggh, gap);
    kE1_a<<<2, 256, 0, stream>>>(gap, w_se1, b_se1, bnse_g, bnse_b, bnse_m, bnse_v, a_buf);
    kE2_attn<<<2, 256, 0, stream>>>(a_buf, w_se2, b_se2, attn);
    kF_out<<<16384, 256, 0, stream>>>((float*)d_out, aggh, k2dh, attn);
}

// Round 11
// 268.826 us; speedup vs baseline: 2.5492x; 1.0565x over previous
//
#include <hip/hip_runtime.h>

#define EPSV 1e-5f
typedef unsigned short u16;
typedef unsigned int u32;

// Problem constants: B=4, N=8, B2=32, C=128, H=W=64, HW=4096, KS=3
// Workspace (float offsets):
//   [0,        8388608)  k2dh (bf16, 16.7M u16)
//   [8388608, 16777216)  aggh (bf16)
//   [16777216,25165824)  vh   (bf16)
//   [25165824,33554432)  xh   (bf16 transcode of x)
//   [33554432,39845888)  wdh  (bf16)
//   stats @46137344: gnsum[1024] gnsq[1024] gap[512] gnmean[1024] gnrstd[1024] attn[1024]

__device__ __forceinline__ u32 bfbits(float f) {   // RNE f32->bf16 bits
    u32 u = __float_as_uint(f);
    u += 0x7fff + ((u >> 16) & 1);
    return u >> 16;
}
__device__ __forceinline__ float bflo(u32 p) { return __uint_as_float(p << 16); }
__device__ __forceinline__ float bfhi(u32 p) { return __uint_as_float(p & 0xffff0000u); }

// ---- kX: transcode x (fp32) -> xh (bf16), 8 elems/thread ----
__global__ __launch_bounds__(256, 8) void kX_cvt(
    const float* __restrict__ x, u16* __restrict__ xh)
{
    int i = (blockIdx.x * 256 + threadIdx.x) * 8;
    float4 a = *(const float4*)(x + i);
    float4 b = *(const float4*)(x + i + 4);
    uint4 p;
    p.x = bfbits(a.x) | (bfbits(a.y) << 16);
    p.y = bfbits(a.z) | (bfbits(a.w) << 16);
    p.z = bfbits(b.x) | (bfbits(b.y) << 16);
    p.w = bfbits(b.z) | (bfbits(b.w) << 16);
    *(uint4*)(xh + i) = p;
}

// ---- kA: key_embed = ReLU(BN(grouped temporal conv3d)) -> bf16 k2d, + gap ----
__global__ __launch_bounds__(256, 4) void kA_key(
    const u16* __restrict__ xh, const float* __restrict__ wk,
    const float* __restrict__ g, const float* __restrict__ bb,
    const float* __restrict__ m, const float* __restrict__ vr,
    u16* __restrict__ k2dh, float* __restrict__ gap)
{
    int blk   = blockIdx.x;
    int strip = blk & 3;
    int half  = (blk >> 2) & 1;
    int grp   = (blk >> 3) & 3;
    int b2    = blk >> 5;
    int px0   = strip * 1024 + threadIdx.x * 4;
    int bi = b2 >> 3, ni = b2 & 7;
    int gch = grp * 32;
    int ob  = gch + half * 16;

    float acc[16][4];
    #pragma unroll
    for (int j = 0; j < 16; ++j)
        acc[j][0] = acc[j][1] = acc[j][2] = acc[j][3] = 0.f;

    #pragma unroll
    for (int dk = 0; dk < 3; ++dk) {
        int nf = ni + dk - 1;
        if (nf >= 0 && nf < 8) {
            const u16* xp    = xh + ((bi * 8 + nf) * 128 + gch) * 4096 + px0;
            const float* wkp = wk + ob * 96 + dk;
            #pragma unroll 4
            for (int ci = 0; ci < 32; ++ci) {
                const uint2 xu = *(const uint2*)(xp + ci * 4096);
                float x0 = bflo(xu.x), x1 = bfhi(xu.x);
                float x2 = bflo(xu.y), x3 = bfhi(xu.y);
                #pragma unroll
                for (int j = 0; j < 16; ++j) {
                    float wv = wkp[j * 96 + ci * 3];
                    acc[j][0] = fmaf(x0, wv, acc[j][0]);
                    acc[j][1] = fmaf(x1, wv, acc[j][1]);
                    acc[j][2] = fmaf(x2, wv, acc[j][2]);
                    acc[j][3] = fmaf(x3, wv, acc[j][3]);
                }
            }
        }
    }

    int lane = threadIdx.x & 63, wid = threadIdx.x >> 6;
    __shared__ float ssum[16][4];
    #pragma unroll
    for (int j = 0; j < 16; ++j) {
        int o = ob + j;
        float s = g[o] * rsqrtf(vr[o] + EPSV);
        float t = bb[o] - m[o] * s;
        float r0 = fmaxf(fmaf(acc[j][0], s, t), 0.f);
        float r1 = fmaxf(fmaf(acc[j][1], s, t), 0.f);
        float r2 = fmaxf(fmaf(acc[j][2], s, t), 0.f);
        float r3 = fmaxf(fmaf(acc[j][3], s, t), 0.f);
        uint2 pk;
        pk.x = bfbits(r0) | (bfbits(r1) << 16);
        pk.y = bfbits(r2) | (bfbits(r3) << 16);
        *(uint2*)(k2dh + (b2 * 128 + o) * 4096 + px0) = pk;
        float lsum = r0 + r1 + r2 + r3;
        #pragma unroll
        for (int off = 32; off; off >>= 1) lsum += __shfl_down(lsum, off, 64);
        if (lane == 0) ssum[j][wid] = lsum;
    }
    __syncthreads();
    if (threadIdx.x < 16) {
        float* sr = ssum[threadIdx.x];
        atomicAdd(&gap[bi * 128 + ob + threadIdx.x], sr[0] + sr[1] + sr[2] + sr[3]);
    }
}

// ---- kB: v = BN(x @ w_1x1) -> bf16 ----
__global__ __launch_bounds__(256, 4) void kB_val(
    const u16* __restrict__ xh, const float* __restrict__ w,
    const float* __restrict__ g, const float* __restrict__ bb,
    const float* __restrict__ m, const float* __restrict__ vr,
    u16* __restrict__ vh)
{
    int blk   = blockIdx.x;
    int ocg   = blk & 7;
    int strip = (blk >> 3) & 3;
    int b2    = blk >> 5;
    int px0   = strip * 1024 + threadIdx.x * 4;
    const u16* xp   = xh + b2 * 128 * 4096 + px0;
    const float* wp = w + ocg * 16 * 128;

    float acc[16][4];
    #pragma unroll
    for (int j = 0; j < 16; ++j)
        acc[j][0] = acc[j][1] = acc[j][2] = acc[j][3] = 0.f;

    #pragma unroll 4
    for (int c = 0; c < 128; ++c) {
        const uint2 xu = *(const uint2*)(xp + c * 4096);
        float x0 = bflo(xu.x), x1 = bfhi(xu.x);
        float x2 = bflo(xu.y), x3 = bfhi(xu.y);
        #pragma unroll
        for (int j = 0; j < 16; ++j) {
            float wv = wp[j * 128 + c];
            acc[j][0] = fmaf(x0, wv, acc[j][0]);
            acc[j][1] = fmaf(x1, wv, acc[j][1]);
            acc[j][2] = fmaf(x2, wv, acc[j][2]);
            acc[j][3] = fmaf(x3, wv, acc[j][3]);
        }
    }
    #pragma unroll
    for (int j = 0; j < 16; ++j) {
        int o = ocg * 16 + j;
        float s = g[o] * rsqrtf(vr[o] + EPSV);
        float t = bb[o] - m[o] * s;
        uint2 pk;
        pk.x = bfbits(fmaf(acc[j][0], s, t)) | (bfbits(fmaf(acc[j][1], s, t)) << 16);
        pk.y = bfbits(fmaf(acc[j][2], s, t)) | (bfbits(fmaf(acc[j][3], s, t)) << 16);
        *(uint2*)(vh + (b2 * 128 + o) * 4096 + px0) = pk;
    }
}

// ---- kC: e = ReLU(BN([x;k2d]@w_e1)), wd = e@w_e2+b -> bf16, GN partials ----
// Block 512 thr = 8 waves; tile 256 px; thread = 4 px (uint2 bf16 loads).
// Wave q: e-ch [8q,8q+8), wd rows [12q,12q+12). Grid 512. LDS 32 KB.
__global__ __launch_bounds__(512, 4) void kC_wd(
    const u16* __restrict__ xh, const u16* __restrict__ k2dh,
    const float* __restrict__ we1,
    const float* __restrict__ eg, const float* __restrict__ eb,
    const float* __restrict__ em, const float* __restrict__ ev,
    const float* __restrict__ we2, const float* __restrict__ be2,
    u16* __restrict__ wdh, float* __restrict__ gnsum, float* __restrict__ gnsq)
{
    int tid  = threadIdx.x;
    int lane = tid & 63;
    int q    = __builtin_amdgcn_readfirstlane(tid >> 6);   // 0..7, wave-uniform
    int tile = blockIdx.x & 15;
    int b2   = blockIdx.x >> 4;
    int pxl  = lane * 4;
    int px0  = tile * 256 + pxl;

    const u16* xp    = xh   + b2 * 128 * 4096 + px0;
    const u16* kp    = k2dh + b2 * 128 * 4096 + px0;
    const float* w1q = we1 + q * 8 * 256;

    float acc[8][4];
    #pragma unroll
    for (int j = 0; j < 8; ++j)
        acc[j][0] = acc[j][1] = acc[j][2] = acc[j][3] = 0.f;

    #pragma unroll 4
    for (int c = 0; c < 128; ++c) {
        const uint2 xu = *(const uint2*)(xp + c * 4096);
        float x0 = bflo(xu.x), x1 = bfhi(xu.x);
        float x2 = bflo(xu.y), x3 = bfhi(xu.y);
        #pragma unroll
        for (int j = 0; j < 8; ++j) {
            float wv = w1q[j * 256 + c];
            acc[j][0] = fmaf(x0, wv, acc[j][0]);
            acc[j][1] = fmaf(x1, wv, acc[j][1]);
            acc[j][2] = fmaf(x2, wv, acc[j][2]);
            acc[j][3] = fmaf(x3, wv, acc[j][3]);
        }
    }
    #pragma unroll 4
    for (int c = 0; c < 128; ++c) {
        const uint2 kv = *(const uint2*)(kp + c * 4096);
        float k0 = bflo(kv.x), k1 = bfhi(kv.x);
        float k2 = bflo(kv.y), k3 = bfhi(kv.y);
        #pragma unroll
        for (int j = 0; j < 8; ++j) {
            float wv = w1q[j * 256 + 128 + c];
            acc[j][0] = fmaf(k0, wv, acc[j][0]);
            acc[j][1] = fmaf(k1, wv, acc[j][1]);
            acc[j][2] = fmaf(k2, wv, acc[j][2]);
            acc[j][3] = fmaf(k3, wv, acc[j][3]);
        }
    }

    __shared__ __align__(8) u16 e_s[64][256];   // bf16, 32 KB
    #pragma unroll
    for (int j = 0; j < 8; ++j) {
        int eo = q * 8 + j;
        float s = eg[eo] * rsqrtf(ev[eo] + EPSV);
        float t = eb[eo] - em[eo] * s;
        float r0 = fmaxf(fmaf(acc[j][0], s, t), 0.f);
        float r1 = fmaxf(fmaf(acc[j][1], s, t), 0.f);
        float r2 = fmaxf(fmaf(acc[j][2], s, t), 0.f);
        float r3 = fmaxf(fmaf(acc[j][3], s, t), 0.f);
        uint2 pk;
        pk.x = bfbits(r0) | (bfbits(r1) << 16);
        pk.y = bfbits(r2) | (bfbits(r3) << 16);
        *(uint2*)&e_s[eo][pxl] = pk;
    }
    __syncthreads();

    int row0 = q * 12;
    const float* w2q = we2 + row0 * 64;
    float wa[12][4];
    #pragma unroll
    for (int j = 0; j < 12; ++j) {
        float b = be2[row0 + j];
        wa[j][0] = wa[j][1] = wa[j][2] = wa[j][3] = b;
    }
    #pragma unroll 4
    for (int c = 0; c < 64; ++c) {
        const uint2 eu = *(const uint2*)&e_s[c][pxl];
        float e0 = bflo(eu.x), e1 = bfhi(eu.x);
        float e2 = bflo(eu.y), e3 = bfhi(eu.y);
        #pragma unroll
        for (int j = 0; j < 12; ++j) {
            float wv = w2q[j * 64 + c];
            wa[j][0] = fmaf(e0, wv, wa[j][0]);
            wa[j][1] = fmaf(e1, wv, wa[j][1]);
            wa[j][2] = fmaf(e2, wv, wa[j][2]);
            wa[j][3] = fmaf(e3, wv, wa[j][3]);
        }
    }

    u16* wdp = wdh + (b2 * 96 + row0) * 4096 + px0;
    #pragma unroll
    for (int j = 0; j < 12; ++j) {
        uint2 pk;
        pk.x = bfbits(wa[j][0]) | (bfbits(wa[j][1]) << 16);
        pk.y = bfbits(wa[j][2]) | (bfbits(wa[j][3]) << 16);
        *(uint2*)(wdp + j * 4096) = pk;
    }

    #pragma unroll
    for (int jj = 0; jj < 4; ++jj) {
        float lsum = 0.f, lsq = 0.f;
        #pragma unroll
        for (int k = 0; k < 3; ++k)
            #pragma unroll
            for (int p = 0; p < 4; ++p) {
                float vv = wa[jj * 3 + k][p];
                lsum += vv; lsq += vv * vv;
            }
        #pragma unroll
        for (int off = 32; off; off >>= 1) {
            lsum += __shfl_down(lsum, off, 64);
            lsq  += __shfl_down(lsq,  off, 64);
        }
        if (lane == 0) {
            int c1 = q * 4 + jj;
            atomicAdd(&gnsum[b2 * 32 + c1], lsum);
            atomicAdd(&gnsq [b2 * 32 + c1], lsq);
        }
    }
}

// ---- kC2: finalize GroupNorm stats ----
__global__ __launch_bounds__(256) void kC2_gn(
    const float* __restrict__ gnsum, const float* __restrict__ gnsq,
    float* __restrict__ gnmean, float* __restrict__ gnrstd)
{
    int idx = blockIdx.x * 256 + threadIdx.x;
    const float inv = 1.f / 12288.f;
    float mu  = gnsum[idx] * inv;
    float var = fmaf(gnsq[idx], inv, -mu * mu);
    gnmean[idx] = mu;
    gnrstd[idx] = rsqrtf(fmaxf(var, 0.f) + EPSV);
}

// ---- kD: agg = SiLU(BN2(sum_k GN(wd)*unfold(v))) -> bf16 aggh, + gap ----
__global__ __launch_bounds__(256, 8) void kD_agg(
    const u16* __restrict__ wdh, const u16* __restrict__ vh,
    const float* __restrict__ gnmean, const float* __restrict__ gnrstd,
    const float* __restrict__ gng, const float* __restrict__ gnb,
    const float* __restrict__ g, const float* __restrict__ bb,
    const float* __restrict__ m, const float* __restrict__ vr,
    u16* __restrict__ aggh, float* __restrict__ gap)
{
    int blk   = blockIdx.x;
    int strip = blk & 7;
    int c1    = (blk >> 3) & 31;
    int bi    = blk >> 8;            // grid = 4*32*8 = 1024
    int px0   = strip * 512 + threadIdx.x * 2;

    float sch[4], tch[4], gl[4];
    #pragma unroll
    for (int ch = 0; ch < 4; ++ch) {
        int c = c1 * 4 + ch;
        float s = g[c] * rsqrtf(vr[c] + EPSV);
        sch[ch] = s; tch[ch] = bb[c] - m[c] * s; gl[ch] = 0.f;
    }
    float gg[3], gb[3];
    #pragma unroll
    for (int k = 0; k < 3; ++k) { gg[k] = gng[c1 * 3 + k]; gb[k] = gnb[c1 * 3 + k]; }

    float2 vreg[4][3];
    #pragma unroll
    for (int ch = 0; ch < 4; ++ch) {
        vreg[ch][0] = make_float2(0.f, 0.f);
        u32 v1u = *(const u32*)(vh + ((bi * 8 + 0) * 128 + c1 * 4 + ch) * 4096 + px0);
        u32 v2u = *(const u32*)(vh + ((bi * 8 + 1) * 128 + c1 * 4 + ch) * 4096 + px0);
        vreg[ch][1] = make_float2(bflo(v1u), bfhi(v1u));
        vreg[ch][2] = make_float2(bflo(v2u), bfhi(v2u));
    }

    for (int ni = 0; ni < 8; ++ni) {
        int b2 = bi * 8 + ni;
        float mu = gnmean[b2 * 32 + c1], rs = gnrstd[b2 * 32 + c1];
        float2 wn[3];
        #pragma unroll
        for (int k = 0; k < 3; ++k) {
            int nf = ni + k - 1;
            if (nf >= 0 && nf < 8) {
                u32 wvu = *(const u32*)(wdh + ((b2 * 96 + c1 * 3 + k) * 4096 + px0));
                wn[k].x = fmaf((bflo(wvu) - mu) * rs, gg[k], gb[k]);
                wn[k].y = fmaf((bfhi(wvu) - mu) * rs, gg[k], gb[k]);
            } else {
                wn[k] = make_float2(0.f, 0.f);
            }
        }
        #pragma unroll
        for (int ch = 0; ch < 4; ++ch) {
            float a0 = 0.f, a1 = 0.f;
            #pragma unroll
            for (int k = 0; k < 3; ++k) {
                a0 = fmaf(wn[k].x, vreg[ch][k].x, a0);
                a1 = fmaf(wn[k].y, vreg[ch][k].y, a1);
            }
            float y0 = fmaf(a0, sch[ch], tch[ch]);
            float y1 = fmaf(a1, sch[ch], tch[ch]);
            float r0 = y0 / (1.f + __expf(-y0));
            float r1 = y1 / (1.f + __expf(-y1));
            *(u32*)(aggh + (b2 * 128 + c1 * 4 + ch) * 4096 + px0) =
                bfbits(r0) | (bfbits(r1) << 16);
            gl[ch] += r0 + r1;
        }
        if (ni < 7) {
            #pragma unroll
            for (int ch = 0; ch < 4; ++ch) {
                vreg[ch][0] = vreg[ch][1];
                vreg[ch][1] = vreg[ch][2];
                if (ni + 2 < 8) {
                    u32 vu = *(const u32*)(vh + ((bi * 8 + ni + 2) * 128 + c1 * 4 + ch) * 4096 + px0);
                    vreg[ch][2] = make_float2(bflo(vu), bfhi(vu));
                }
            }
        }
    }

    __shared__ float sm[4][4];
    int lane = threadIdx.x & 63, wid = threadIdx.x >> 6;
    #pragma unroll
    for (int ch = 0; ch < 4; ++ch) {
        float s = gl[ch];
        #pragma unroll
        for (int off = 32; off; off >>= 1) s += __shfl_down(s, off, 64);
        if (lane == 0) sm[ch][wid] = s;
    }
    __syncthreads();
    if (threadIdx.x < 4) {
        float* sr = sm[threadIdx.x];
        atomicAdd(&gap[bi * 128 + c1 * 4 + threadIdx.x], sr[0] + sr[1] + sr[2] + sr[3]);
    }
}

// ---- kE1: a = ReLU(BNvec(gap/32768 @ w1^T + b1)) ----
__global__ __launch_bounds__(256) void kE1_a(
    const float* __restrict__ gap,
    const float* __restrict__ w1, const float* __restrict__ b1,
    const float* __restrict__ g, const float* __restrict__ bb,
    const float* __restrict__ m, const float* __restrict__ vr,
    float* __restrict__ a_buf)
{
    int idx = blockIdx.x * 256 + threadIdx.x;
    int bi = idx >> 7, oc = idx & 127;
    float acc = b1[oc];
    const float* gp = gap + bi * 128;
    const float* wp = w1 + oc * 128;
    for (int c = 0; c < 128; c += 4) {
        const float4 w4 = *(const float4*)(wp + c);
        acc = fmaf(gp[c + 0] * (1.f / 32768.f), w4.x, acc);
        acc = fmaf(gp[c + 1] * (1.f / 32768.f), w4.y, acc);
        acc = fmaf(gp[c + 2] * (1.f / 32768.f), w4.z, acc);
        acc = fmaf(gp[c + 3] * (1.f / 32768.f), w4.w, acc);
    }
    float s = g[oc] * rsqrtf(vr[oc] + EPSV);
    a_buf[bi * 128 + oc] = fmaxf(fmaf(acc, s, bb[oc] - m[oc] * s), 0.f);
}

// ---- kE2: attn = softmax over radix-2 pairs ----
__global__ __launch_bounds__(256) void kE2_attn(
    const float* __restrict__ a_buf,
    const float* __restrict__ w2, const float* __restrict__ b2v,
    float* __restrict__ attn)
{
    int idx = blockIdx.x * 256 + threadIdx.x;
    int bi = idx >> 7, cc = idx & 127;
    float l0 = b2v[cc * 2], l1 = b2v[cc * 2 + 1];
    const float* ap  = a_buf + bi * 128;
    const float* w0p = w2 + (cc * 2) * 128;
    const float* w1p = w2 + (cc * 2 + 1) * 128;
    for (int j = 0; j < 128; j += 4) {
        const float4 wa4 = *(const float4*)(w0p + j);
        const float4 wb4 = *(const float4*)(w1p + j);
        l0 = fmaf(ap[j + 0], wa4.x, l0); l1 = fmaf(ap[j + 0], wb4.x, l1);
        l0 = fmaf(ap[j + 1], wa4.y, l0); l1 = fmaf(ap[j + 1], wb4.y, l1);
        l0 = fmaf(ap[j + 2], wa4.z, l0); l1 = fmaf(ap[j + 2], wb4.z, l1);
        l0 = fmaf(ap[j + 3], wa4.w, l0); l1 = fmaf(ap[j + 3], wb4.w, l1);
    }
    float mx = fmaxf(l0, l1);
    float e0 = __expf(l0 - mx), e1 = __expf(l1 - mx);
    float inv = 1.f / (e0 + e1);
    attn[bi * 256 + cc * 2]     = e0 * inv;
    attn[bi * 256 + cc * 2 + 1] = e1 * inv;
}

// ---- kF: out = attn0*agg(bf16) + attn1*k2d(bf16) -> fp32; thread = 4 px ----
__global__ __launch_bounds__(256, 8) void kF_out(
    float* __restrict__ out, const u16* __restrict__ aggh,
    const u16* __restrict__ k2dh, const float* __restrict__ attn)
{
    int blk   = blockIdx.x;
    int strip = blk & 3;
    int c     = (blk >> 2) & 127;
    int b2    = blk >> 9;
    int bi    = b2 >> 3;
    float a0 = attn[bi * 256 + c * 2];
    float a1 = attn[bi * 256 + c * 2 + 1];
    int idx = (b2 * 128 + c) * 4096 + strip * 1024 + threadIdx.x * 4;
    uint2 g4 = *(const uint2*)(aggh + idx);
    uint2 k4 = *(const uint2*)(k2dh + idx);
    float4 r;
    r.x = fmaf(a0, bflo(g4.x), a1 * bflo(k4.x));
    r.y = fmaf(a0, bfhi(g4.x), a1 * bfhi(k4.x));
    r.z = fmaf(a0, bflo(g4.y), a1 * bflo(k4.y));
    r.w = fmaf(a0, bfhi(g4.y), a1 * bfhi(k4.y));
    *(float4*)(out + idx) = r;
}

extern "C" void kernel_launch(void* const* d_in, const int* in_sizes, int n_in,
                              void* d_out, int out_size, void* d_ws, size_t ws_size,
                              hipStream_t stream)
{
    const float* x      = (const float*)d_in[0];
    const float* w_key  = (const float*)d_in[1];
    const float* bnk_g  = (const float*)d_in[2];
    const float* bnk_b  = (const float*)d_in[3];
    const float* bnk_m  = (const float*)d_in[4];
    const float* bnk_v  = (const float*)d_in[5];
    const float* w_e1   = (const float*)d_in[6];
    const float* bne_g  = (const float*)d_in[7];
    const float* bne_b  = (const float*)d_in[8];
    const float* bne_m  = (const float*)d_in[9];
    const float* bne_v  = (const float*)d_in[10];
    const float* w_e2   = (const float*)d_in[11];
    const float* b_e2   = (const float*)d_in[12];
    const float* gn_g   = (const float*)d_in[13];
    const float* gn_b   = (const float*)d_in[14];
    const float* w_1x1  = (const float*)d_in[15];
    const float* bn1_g  = (const float*)d_in[16];
    const float* bn1_b  = (const float*)d_in[17];
    const float* bn1_m  = (const float*)d_in[18];
    const float* bn1_v  = (const float*)d_in[19];
    const float* bn2_g  = (const float*)d_in[20];
    const float* bn2_b  = (const float*)d_in[21];
    const float* bn2_m  = (const float*)d_in[22];
    const float* bn2_v  = (const float*)d_in[23];
    const float* w_se1  = (const float*)d_in[24];
    const float* b_se1  = (const float*)d_in[25];
    const float* bnse_g = (const float*)d_in[26];
    const float* bnse_b = (const float*)d_in[27];
    const float* bnse_m = (const float*)d_in[28];
    const float* bnse_v = (const float*)d_in[29];
    const float* w_se2  = (const float*)d_in[30];
    const float* b_se2  = (const float*)d_in[31];

    float* ws   = (float*)d_ws;
    u16*  k2dh = (u16*)ws;                        // bf16, 16.7M u16
    u16*  aggh = (u16*)(ws + 8388608);            // bf16
    u16*  vh   = (u16*)(ws + 16777216);           // bf16
    u16*  xh   = (u16*)(ws + 25165824);           // bf16 transcode of x
    u16*  wdh  = (u16*)(ws + 33554432);           // bf16
    float* st   = ws + 46137344;
    float* gnsum  = st;
    float* gnsq   = st + 1024;
    float* gap    = st + 2048;
    float* gnmean = st + 2560;
    float* gnrstd = st + 3584;
    float* attn   = st + 4608;
    float* a_buf  = st;            // aliases gnsum (dead after kC2)

    hipMemsetAsync(gnsum, 0, 2560 * sizeof(float), stream);

    kX_cvt<<<8192, 256, 0, stream>>>(x, xh);
    kA_key<<<1024, 256, 0, stream>>>(xh, w_key, bnk_g, bnk_b, bnk_m, bnk_v, k2dh, gap);
    kB_val<<<1024, 256, 0, stream>>>(xh, w_1x1, bn1_g, bn1_b, bn1_m, bn1_v, vh);
    kC_wd<<<512, 512, 0, stream>>>(xh, k2dh, w_e1, bne_g, bne_b, bne_m, bne_v,
                                   w_e2, b_e2, wdh, gnsum, gnsq);
    kC2_gn<<<4, 256, 0, stream>>>(gnsum, gnsq, gnmean, gnrstd);
    kD_agg<<<1024, 256, 0, stream>>>(wdh, vh, gnmean, gnrstd, gn_g, gn_b,
                                     bn2_g, bn2_b, bn2_m, bn2_v, aggh, gap);
    kE1_a<<<2, 256, 0, stream>>>(gap, w_se1, b_se1, bnse_g, bnse_b, bnse_m, bnse_v, a_buf);
    kE2_attn<<<2, 256, 0, stream>>>(a_buf, w_se2, b_se2, attn);
    kF_out<<<16384, 256, 0, stream>>>((float*)d_out, aggh, k2dh, attn);
}

// Round 12
// 256.622 us; speedup vs baseline: 2.6705x; 1.0476x over previous
//
#include <hip/hip_runtime.h>

#define EPSV 1e-5f
typedef unsigned short u16;
typedef unsigned int u32;

// Problem constants: B=4, N=8, B2=32, C=128, H=W=64, HW=4096, KS=3
// Workspace (float offsets):
//   [0,        8388608)  xh2   (u32 pair-interleaved bf16 x: dword=(ch2c2,ch2c2+1))
//   [8388608, 16777216)  k2dh2 (u32 pair-interleaved bf16 k2d)
//   [16777216,25165824)  vh    (u16 bf16, standard layout)
//   [25165824,33554432)  aggh  (u16 bf16, standard layout)
//   [33554432,39845888)  wdh   (u16 bf16, standard layout)
//   [39845888,39871488)  packed weights (u32 bf16 pairs)
//   stats @46137344: gnsum[1024] gnsq[1024] gap[512] gnmean[1024] gnrstd[1024] attn[1024]

__device__ __forceinline__ u32 bfbits(float f) {   // RNE f32->bf16 bits
    u32 u = __float_as_uint(f);
    u += 0x7fff + ((u >> 16) & 1);
    return u >> 16;
}
__device__ __forceinline__ float bflo(u32 p) { return __uint_as_float(p << 16); }
__device__ __forceinline__ float bfhi(u32 p) { return __uint_as_float(p & 0xffff0000u); }

// D = a.bf16[0]*b.bf16[0] + a.bf16[1]*b.bf16[1] + c   (VOP3P, full-rate)
__device__ __forceinline__ float dot2bf(u32 a, u32 b, float c) {
    float d;
    asm("v_dot2_f32_bf16 %0, %1, %2, %3" : "=v"(d) : "v"(a), "v"(b), "v"(c));
    return d;
}

// ---- kW: pack weights into bf16-pair tables ----
__global__ __launch_bounds__(256) void kW_pack(
    const float* __restrict__ wk, const float* __restrict__ w1,
    const float* __restrict__ we1, const float* __restrict__ we2,
    u32* __restrict__ wk2, u32* __restrict__ w12,
    u32* __restrict__ we12, u32* __restrict__ we22)
{
    int i = blockIdx.x * 256 + threadIdx.x;
    if (i < 6144) {                       // wk2[(o*3+dk)*16 + c2]
        int o = i / 48, r = i % 48, dk = r / 16, c2 = r % 16;
        wk2[i] = 0;  // placeholder ordering below
        wk2[(o * 3 + dk) * 16 + c2] =
            bfbits(wk[o * 96 + 6 * c2 + dk]) | (bfbits(wk[o * 96 + 6 * c2 + 3 + dk]) << 16);
    } else if (i < 14336) {               // w12[o*64 + c2]
        int j = i - 6144, o = j >> 6, c2 = j & 63;
        w12[j] = bfbits(w1[o * 128 + 2 * c2]) | (bfbits(w1[o * 128 + 2 * c2 + 1]) << 16);
    } else if (i < 22528) {               // we12[eo*128 + c2]  (c2<64: x-chs, >=64: k2d-chs)
        int j = i - 14336, eo = j >> 7, c2 = j & 127;
        we12[j] = bfbits(we1[eo * 256 + 2 * c2]) | (bfbits(we1[eo * 256 + 2 * c2 + 1]) << 16);
    } else if (i < 25600) {               // we22[row*32 + c2]
        int j = i - 22528, row = j >> 5, c2 = j & 31;
        we22[j] = bfbits(we2[row * 64 + 2 * c2]) | (bfbits(we2[row * 64 + 2 * c2 + 1]) << 16);
    }
}

// ---- kX: x (fp32) -> xh2 (u32 channel-pair bf16) ----
__global__ __launch_bounds__(256, 8) void kX_cvt(
    const float* __restrict__ x, u32* __restrict__ xh2)
{
    int qid = blockIdx.x * 256 + threadIdx.x;   // 2,097,152 total
    int px  = (qid & 1023) * 4;
    int c2g = qid >> 10;                        // b2*64 + c2
    const float4 a = *(const float4*)(x + (c2g * 2) * 4096 + px);
    const float4 b = *(const float4*)(x + (c2g * 2 + 1) * 4096 + px);
    uint4 o;
    o.x = bfbits(a.x) | (bfbits(b.x) << 16);
    o.y = bfbits(a.y) | (bfbits(b.y) << 16);
    o.z = bfbits(a.z) | (bfbits(b.z) << 16);
    o.w = bfbits(a.w) | (bfbits(b.w) << 16);
    *(uint4*)(xh2 + c2g * 4096 + px) = o;
}

// ---- kA: key_embed -> k2dh2 (pair-interleaved), + gap ----
__global__ __launch_bounds__(256, 4) void kA_key(
    const u32* __restrict__ xh2, const u32* __restrict__ wk2,
    const float* __restrict__ g, const float* __restrict__ bb,
    const float* __restrict__ m, const float* __restrict__ vr,
    u32* __restrict__ k2dh2, float* __restrict__ gap)
{
    int blk   = blockIdx.x;
    int strip = blk & 3;
    int half  = (blk >> 2) & 1;
    int grp   = (blk >> 3) & 3;
    int b2    = blk >> 5;
    int px0   = strip * 1024 + threadIdx.x * 4;
    int bi = b2 >> 3, ni = b2 & 7;
    int ob = grp * 32 + half * 16;

    float acc[16][4];
    #pragma unroll
    for (int j = 0; j < 16; ++j)
        acc[j][0] = acc[j][1] = acc[j][2] = acc[j][3] = 0.f;

    #pragma unroll
    for (int dk = 0; dk < 3; ++dk) {
        int nf = ni + dk - 1;
        if (nf >= 0 && nf < 8) {
            const u32* xp = xh2 + ((bi * 8 + nf) * 64 + grp * 16) * 4096 + px0;
            const u32* wp = wk2 + (ob * 3 + dk) * 16;   // [j]: +j*48, [c2]: +c2
            #pragma unroll 4
            for (int c2 = 0; c2 < 16; ++c2) {
                const uint4 xv = *(const uint4*)(xp + c2 * 4096);
                #pragma unroll
                for (int j = 0; j < 16; ++j) {
                    u32 w = wp[j * 48 + c2];
                    acc[j][0] = dot2bf(xv.x, w, acc[j][0]);
                    acc[j][1] = dot2bf(xv.y, w, acc[j][1]);
                    acc[j][2] = dot2bf(xv.z, w, acc[j][2]);
                    acc[j][3] = dot2bf(xv.w, w, acc[j][3]);
                }
            }
        }
    }

    int lane = threadIdx.x & 63, wid = threadIdx.x >> 6;
    __shared__ float ssum[16][4];
    float r[16][4];
    #pragma unroll
    for (int j = 0; j < 16; ++j) {
        int o = ob + j;
        float s = g[o] * rsqrtf(vr[o] + EPSV);
        float t = bb[o] - m[o] * s;
        float lsum = 0.f;
        #pragma unroll
        for (int p = 0; p < 4; ++p) {
            r[j][p] = fmaxf(fmaf(acc[j][p], s, t), 0.f);
            lsum += r[j][p];
        }
        #pragma unroll
        for (int off = 32; off; off >>= 1) lsum += __shfl_down(lsum, off, 64);
        if (lane == 0) ssum[j][wid] = lsum;
    }
    // pack (o, o+1) pairs -> k2dh2
    #pragma unroll
    for (int jj = 0; jj < 8; ++jj) {
        int c2out = grp * 16 + half * 8 + jj;
        uint4 pk;
        pk.x = bfbits(r[2 * jj][0]) | (bfbits(r[2 * jj + 1][0]) << 16);
        pk.y = bfbits(r[2 * jj][1]) | (bfbits(r[2 * jj + 1][1]) << 16);
        pk.z = bfbits(r[2 * jj][2]) | (bfbits(r[2 * jj + 1][2]) << 16);
        pk.w = bfbits(r[2 * jj][3]) | (bfbits(r[2 * jj + 1][3]) << 16);
        *(uint4*)(k2dh2 + (b2 * 64 + c2out) * 4096 + px0) = pk;
    }
    __syncthreads();
    if (threadIdx.x < 16) {
        float* sr = ssum[threadIdx.x];
        atomicAdd(&gap[bi * 128 + ob + threadIdx.x], sr[0] + sr[1] + sr[2] + sr[3]);
    }
}

// ---- kB: v = BN(x @ w_1x1) -> bf16 (standard layout) ----
__global__ __launch_bounds__(256, 4) void kB_val(
    const u32* __restrict__ xh2, const u32* __restrict__ w12,
    const float* __restrict__ g, const float* __restrict__ bb,
    const float* __restrict__ m, const float* __restrict__ vr,
    u16* __restrict__ vh)
{
    int blk   = blockIdx.x;
    int ocg   = blk & 7;
    int strip = (blk >> 3) & 3;
    int b2    = blk >> 5;
    int px0   = strip * 1024 + threadIdx.x * 4;
    const u32* xp = xh2 + b2 * 64 * 4096 + px0;
    const u32* wp = w12 + ocg * 16 * 64;

    float acc[16][4];
    #pragma unroll
    for (int j = 0; j < 16; ++j)
        acc[j][0] = acc[j][1] = acc[j][2] = acc[j][3] = 0.f;

    #pragma unroll 4
    for (int c2 = 0; c2 < 64; ++c2) {
        const uint4 xv = *(const uint4*)(xp + c2 * 4096);
        #pragma unroll
        for (int j = 0; j < 16; ++j) {
            u32 w = wp[j * 64 + c2];
            acc[j][0] = dot2bf(xv.x, w, acc[j][0]);
            acc[j][1] = dot2bf(xv.y, w, acc[j][1]);
            acc[j][2] = dot2bf(xv.z, w, acc[j][2]);
            acc[j][3] = dot2bf(xv.w, w, acc[j][3]);
        }
    }
    #pragma unroll
    for (int j = 0; j < 16; ++j) {
        int o = ocg * 16 + j;
        float s = g[o] * rsqrtf(vr[o] + EPSV);
        float t = bb[o] - m[o] * s;
        uint2 pk;
        pk.x = bfbits(fmaf(acc[j][0], s, t)) | (bfbits(fmaf(acc[j][1], s, t)) << 16);
        pk.y = bfbits(fmaf(acc[j][2], s, t)) | (bfbits(fmaf(acc[j][3], s, t)) << 16);
        *(uint2*)(vh + (b2 * 128 + o) * 4096 + px0) = pk;
    }
}

// ---- kC: e = ReLU(BN([x;k2d]@w_e1)), wd = e@w_e2+b -> bf16, GN partials ----
// Block 512 thr = 8 waves; tile 256 px; thread = 4 px. dot2 core.
__global__ __launch_bounds__(512, 4) void kC_wd(
    const u32* __restrict__ xh2, const u32* __restrict__ k2dh2,
    const u32* __restrict__ we12,
    const float* __restrict__ eg, const float* __restrict__ eb,
    const float* __restrict__ em, const float* __restrict__ ev,
    const u32* __restrict__ we22, const float* __restrict__ be2,
    u16* __restrict__ wdh, float* __restrict__ gnsum, float* __restrict__ gnsq)
{
    int tid  = threadIdx.x;
    int lane = tid & 63;
    int q    = __builtin_amdgcn_readfirstlane(tid >> 6);   // 0..7, wave-uniform
    int tile = blockIdx.x & 15;
    int b2   = blockIdx.x >> 4;
    int pxl  = lane * 4;
    int px0  = tile * 256 + pxl;

    const u32* xp  = xh2   + b2 * 64 * 4096 + px0;
    const u32* kp  = k2dh2 + b2 * 64 * 4096 + px0;
    const u32* w1q = we12 + q * 8 * 128;

    float acc[8][4];
    #pragma unroll
    for (int j = 0; j < 8; ++j)
        acc[j][0] = acc[j][1] = acc[j][2] = acc[j][3] = 0.f;

    #pragma unroll 4
    for (int c2 = 0; c2 < 64; ++c2) {
        const uint4 xv = *(const uint4*)(xp + c2 * 4096);
        #pragma unroll
        for (int j = 0; j < 8; ++j) {
            u32 w = w1q[j * 128 + c2];
            acc[j][0] = dot2bf(xv.x, w, acc[j][0]);
            acc[j][1] = dot2bf(xv.y, w, acc[j][1]);
            acc[j][2] = dot2bf(xv.z, w, acc[j][2]);
            acc[j][3] = dot2bf(xv.w, w, acc[j][3]);
        }
    }
    #pragma unroll 4
    for (int c2 = 0; c2 < 64; ++c2) {
        const uint4 kv = *(const uint4*)(kp + c2 * 4096);
        #pragma unroll
        for (int j = 0; j < 8; ++j) {
            u32 w = w1q[j * 128 + 64 + c2];
            acc[j][0] = dot2bf(kv.x, w, acc[j][0]);
            acc[j][1] = dot2bf(kv.y, w, acc[j][1]);
            acc[j][2] = dot2bf(kv.z, w, acc[j][2]);
            acc[j][3] = dot2bf(kv.w, w, acc[j][3]);
        }
    }

    __shared__ __align__(16) u32 e_s2[32][256];   // bf16 pairs, 32 KB
    float r[8][4];
    #pragma unroll
    for (int j = 0; j < 8; ++j) {
        int eo = q * 8 + j;
        float s = eg[eo] * rsqrtf(ev[eo] + EPSV);
        float t = eb[eo] - em[eo] * s;
        #pragma unroll
        for (int p = 0; p < 4; ++p)
            r[j][p] = fmaxf(fmaf(acc[j][p], s, t), 0.f);
    }
    #pragma unroll
    for (int jj = 0; jj < 4; ++jj) {
        uint4 pk;
        pk.x = bfbits(r[2 * jj][0]) | (bfbits(r[2 * jj + 1][0]) << 16);
        pk.y = bfbits(r[2 * jj][1]) | (bfbits(r[2 * jj + 1][1]) << 16);
        pk.z = bfbits(r[2 * jj][2]) | (bfbits(r[2 * jj + 1][2]) << 16);
        pk.w = bfbits(r[2 * jj][3]) | (bfbits(r[2 * jj + 1][3]) << 16);
        *(uint4*)&e_s2[q * 4 + jj][pxl] = pk;
    }
    __syncthreads();

    int row0 = q * 12;
    const u32* w2q = we22 + row0 * 32;
    float wa[12][4];
    #pragma unroll
    for (int j = 0; j < 12; ++j) {
        float b = be2[row0 + j];
        wa[j][0] = wa[j][1] = wa[j][2] = wa[j][3] = b;
    }
    #pragma unroll 4
    for (int c2 = 0; c2 < 32; ++c2) {
        const uint4 eu = *(const uint4*)&e_s2[c2][pxl];
        #pragma unroll
        for (int j = 0; j < 12; ++j) {
            u32 w = w2q[j * 32 + c2];
            wa[j][0] = dot2bf(eu.x, w, wa[j][0]);
            wa[j][1] = dot2bf(eu.y, w, wa[j][1]);
            wa[j][2] = dot2bf(eu.z, w, wa[j][2]);
            wa[j][3] = dot2bf(eu.w, w, wa[j][3]);
        }
    }

    u16* wdp = wdh + (b2 * 96 + row0) * 4096 + px0;
    #pragma unroll
    for (int j = 0; j < 12; ++j) {
        uint2 pk;
        pk.x = bfbits(wa[j][0]) | (bfbits(wa[j][1]) << 16);
        pk.y = bfbits(wa[j][2]) | (bfbits(wa[j][3]) << 16);
        *(uint2*)(wdp + j * 4096) = pk;
    }

    #pragma unroll
    for (int jj = 0; jj < 4; ++jj) {
        float lsum = 0.f, lsq = 0.f;
        #pragma unroll
        for (int k = 0; k < 3; ++k)
            #pragma unroll
            for (int p = 0; p < 4; ++p) {
                float vv = wa[jj * 3 + k][p];
                lsum += vv; lsq += vv * vv;
            }
        #pragma unroll
        for (int off = 32; off; off >>= 1) {
            lsum += __shfl_down(lsum, off, 64);
            lsq  += __shfl_down(lsq,  off, 64);
        }
        if (lane == 0) {
            int c1 = q * 4 + jj;
            atomicAdd(&gnsum[b2 * 32 + c1], lsum);
            atomicAdd(&gnsq [b2 * 32 + c1], lsq);
        }
    }
}

// ---- kC2: finalize GroupNorm stats ----
__global__ __launch_bounds__(256) void kC2_gn(
    const float* __restrict__ gnsum, const float* __restrict__ gnsq,
    float* __restrict__ gnmean, float* __restrict__ gnrstd)
{
    int idx = blockIdx.x * 256 + threadIdx.x;
    const float inv = 1.f / 12288.f;
    float mu  = gnsum[idx] * inv;
    float var = fmaf(gnsq[idx], inv, -mu * mu);
    gnmean[idx] = mu;
    gnrstd[idx] = rsqrtf(fmaxf(var, 0.f) + EPSV);
}

// ---- kD: agg = SiLU(BN2(sum_k GN(wd)*unfold(v))) -> bf16 aggh, + gap ----
__global__ __launch_bounds__(256, 8) void kD_agg(
    const u16* __restrict__ wdh, const u16* __restrict__ vh,
    const float* __restrict__ gnmean, const float* __restrict__ gnrstd,
    const float* __restrict__ gng, const float* __restrict__ gnb,
    const float* __restrict__ g, const float* __restrict__ bb,
    const float* __restrict__ m, const float* __restrict__ vr,
    u16* __restrict__ aggh, float* __restrict__ gap)
{
    int blk   = blockIdx.x;
    int strip = blk & 7;
    int c1    = (blk >> 3) & 31;
    int bi    = blk >> 8;
    int px0   = strip * 512 + threadIdx.x * 2;

    float sch[4], tch[4], gl[4];
    #pragma unroll
    for (int ch = 0; ch < 4; ++ch) {
        int c = c1 * 4 + ch;
        float s = g[c] * rsqrtf(vr[c] + EPSV);
        sch[ch] = s; tch[ch] = bb[c] - m[c] * s; gl[ch] = 0.f;
    }
    float gg[3], gb[3];
    #pragma unroll
    for (int k = 0; k < 3; ++k) { gg[k] = gng[c1 * 3 + k]; gb[k] = gnb[c1 * 3 + k]; }

    float2 vreg[4][3];
    #pragma unroll
    for (int ch = 0; ch < 4; ++ch) {
        vreg[ch][0] = make_float2(0.f, 0.f);
        u32 v1u = *(const u32*)(vh + ((bi * 8 + 0) * 128 + c1 * 4 + ch) * 4096 + px0);
        u32 v2u = *(const u32*)(vh + ((bi * 8 + 1) * 128 + c1 * 4 + ch) * 4096 + px0);
        vreg[ch][1] = make_float2(bflo(v1u), bfhi(v1u));
        vreg[ch][2] = make_float2(bflo(v2u), bfhi(v2u));
    }

    for (int ni = 0; ni < 8; ++ni) {
        int b2 = bi * 8 + ni;
        float mu = gnmean[b2 * 32 + c1], rs = gnrstd[b2 * 32 + c1];
        float2 wn[3];
        #pragma unroll
        for (int k = 0; k < 3; ++k) {
            int nf = ni + k - 1;
            if (nf >= 0 && nf < 8) {
                u32 wvu = *(const u32*)(wdh + ((b2 * 96 + c1 * 3 + k) * 4096 + px0));
                wn[k].x = fmaf((bflo(wvu) - mu) * rs, gg[k], gb[k]);
                wn[k].y = fmaf((bfhi(wvu) - mu) * rs, gg[k], gb[k]);
            } else {
                wn[k] = make_float2(0.f, 0.f);
            }
        }
        #pragma unroll
        for (int ch = 0; ch < 4; ++ch) {
            float a0 = 0.f, a1 = 0.f;
            #pragma unroll
            for (int k = 0; k < 3; ++k) {
                a0 = fmaf(wn[k].x, vreg[ch][k].x, a0);
                a1 = fmaf(wn[k].y, vreg[ch][k].y, a1);
            }
            float y0 = fmaf(a0, sch[ch], tch[ch]);
            float y1 = fmaf(a1, sch[ch], tch[ch]);
            float r0 = y0 / (1.f + __expf(-y0));
            float r1 = y1 / (1.f + __expf(-y1));
            *(u32*)(aggh + (b2 * 128 + c1 * 4 + ch) * 4096 + px0) =
                bfbits(r0) | (bfbits(r1) << 16);
            gl[ch] += r0 + r1;
        }
        if (ni < 7) {
            #pragma unroll
            for (int ch = 0; ch < 4; ++ch) {
                vreg[ch][0] = vreg[ch][1];
                vreg[ch][1] = vreg[ch][2];
                if (ni + 2 < 8) {
                    u32 vu = *(const u32*)(vh + ((bi * 8 + ni + 2) * 128 + c1 * 4 + ch) * 4096 + px0);
                    vreg[ch][2] = make_float2(bflo(vu), bfhi(vu));
                }
            }
        }
    }

    __shared__ float sm[4][4];
    int lane = threadIdx.x & 63, wid = threadIdx.x >> 6;
    #pragma unroll
    for (int ch = 0; ch < 4; ++ch) {
        float s = gl[ch];
        #pragma unroll
        for (int off = 32; off; off >>= 1) s += __shfl_down(s, off, 64);
        if (lane == 0) sm[ch][wid] = s;
    }
    __syncthreads();
    if (threadIdx.x < 4) {
        float* sr = sm[threadIdx.x];
        atomicAdd(&gap[bi * 128 + c1 * 4 + threadIdx.x], sr[0] + sr[1] + sr[2] + sr[3]);
    }
}

// ---- kE1: a = ReLU(BNvec(gap/32768 @ w1^T + b1)) ----
__global__ __launch_bounds__(256) void kE1_a(
    const float* __restrict__ gap,
    const float* __restrict__ w1, const float* __restrict__ b1,
    const float* __restrict__ g, const float* __restrict__ bb,
    const float* __restrict__ m, const float* __restrict__ vr,
    float* __restrict__ a_buf)
{
    int idx = blockIdx.x * 256 + threadIdx.x;
    int bi = idx >> 7, oc = idx & 127;
    float acc = b1[oc];
    const float* gp = gap + bi * 128;
    const float* wp = w1 + oc * 128;
    for (int c = 0; c < 128; c += 4) {
        const float4 w4 = *(const float4*)(wp + c);
        acc = fmaf(gp[c + 0] * (1.f / 32768.f), w4.x, acc);
        acc = fmaf(gp[c + 1] * (1.f / 32768.f), w4.y, acc);
        acc = fmaf(gp[c + 2] * (1.f / 32768.f), w4.z, acc);
        acc = fmaf(gp[c + 3] * (1.f / 32768.f), w4.w, acc);
    }
    float s = g[oc] * rsqrtf(vr[oc] + EPSV);
    a_buf[bi * 128 + oc] = fmaxf(fmaf(acc, s, bb[oc] - m[oc] * s), 0.f);
}

// ---- kE2: attn = softmax over radix-2 pairs ----
__global__ __launch_bounds__(256) void kE2_attn(
    const float* __restrict__ a_buf,
    const float* __restrict__ w2, const float* __restrict__ b2v,
    float* __restrict__ attn)
{
    int idx = blockIdx.x * 256 + threadIdx.x;
    int bi = idx >> 7, cc = idx & 127;
    float l0 = b2v[cc * 2], l1 = b2v[cc * 2 + 1];
    const float* ap  = a_buf + bi * 128;
    const float* w0p = w2 + (cc * 2) * 128;
    const float* w1p = w2 + (cc * 2 + 1) * 128;
    for (int j = 0; j < 128; j += 4) {
        const float4 wa4 = *(const float4*)(w0p + j);
        const float4 wb4 = *(const float4*)(w1p + j);
        l0 = fmaf(ap[j + 0], wa4.x, l0); l1 = fmaf(ap[j + 0], wb4.x, l1);
        l0 = fmaf(ap[j + 1], wa4.y, l0); l1 = fmaf(ap[j + 1], wb4.y, l1);
        l0 = fmaf(ap[j + 2], wa4.z, l0); l1 = fmaf(ap[j + 2], wb4.z, l1);
        l0 = fmaf(ap[j + 3], wa4.w, l0); l1 = fmaf(ap[j + 3], wb4.w, l1);
    }
    float mx = fmaxf(l0, l1);
    float e0 = __expf(l0 - mx), e1 = __expf(l1 - mx);
    float inv = 1.f / (e0 + e1);
    attn[bi * 256 + cc * 2]     = e0 * inv;
    attn[bi * 256 + cc * 2 + 1] = e1 * inv;
}

// ---- kF: out = attn0*agg + attn1*k2d; block = (b2, c2-pair, strip) ----
__global__ __launch_bounds__(256, 8) void kF_out(
    float* __restrict__ out, const u16* __restrict__ aggh,
    const u32* __restrict__ k2dh2, const float* __restrict__ attn)
{
    int blk   = blockIdx.x;
    int strip = blk & 3;
    int c2    = (blk >> 2) & 63;
    int b2    = blk >> 8;
    int bi    = b2 >> 3;
    int px0   = strip * 1024 + threadIdx.x * 4;

    float a0e = attn[bi * 256 + 4 * c2];
    float a1e = attn[bi * 256 + 4 * c2 + 1];
    float a0o = attn[bi * 256 + 4 * c2 + 2];
    float a1o = attn[bi * 256 + 4 * c2 + 3];

    uint4 kk = *(const uint4*)(k2dh2 + (b2 * 64 + c2) * 4096 + px0);
    uint2 g0 = *(const uint2*)(aggh + (b2 * 128 + 2 * c2) * 4096 + px0);
    uint2 g1 = *(const uint2*)(aggh + (b2 * 128 + 2 * c2 + 1) * 4096 + px0);

    float4 re, ro;
    re.x = fmaf(a0e, bflo(g0.x), a1e * bflo(kk.x));
    re.y = fmaf(a0e, bfhi(g0.x), a1e * bflo(kk.y));
    re.z = fmaf(a0e, bflo(g0.y), a1e * bflo(kk.z));
    re.w = fmaf(a0e, bfhi(g0.y), a1e * bflo(kk.w));
    ro.x = fmaf(a0o, bflo(g1.x), a1o * bfhi(kk.x));
    ro.y = fmaf(a0o, bfhi(g1.x), a1o * bfhi(kk.y));
    ro.z = fmaf(a0o, bflo(g1.y), a1o * bfhi(kk.z));
    ro.w = fmaf(a0o, bfhi(g1.y), a1o * bfhi(kk.w));
    *(float4*)(out + (b2 * 128 + 2 * c2) * 4096 + px0) = re;
    *(float4*)(out + (b2 * 128 + 2 * c2 + 1) * 4096 + px0) = ro;
}

extern "C" void kernel_launch(void* const* d_in, const int* in_sizes, int n_in,
                              void* d_out, int out_size, void* d_ws, size_t ws_size,
                              hipStream_t stream)
{
    const float* x      = (const float*)d_in[0];
    const float* w_key  = (const float*)d_in[1];
    const float* bnk_g  = (const float*)d_in[2];
    const float* bnk_b  = (const float*)d_in[3];
    const float* bnk_m  = (const float*)d_in[4];
    const float* bnk_v  = (const float*)d_in[5];
    const float* w_e1   = (const float*)d_in[6];
    const float* bne_g  = (const float*)d_in[7];
    const float* bne_b  = (const float*)d_in[8];
    const float* bne_m  = (const float*)d_in[9];
    const float* bne_v  = (const float*)d_in[10];
    const float* w_e2   = (const float*)d_in[11];
    const float* b_e2   = (const float*)d_in[12];
    const float* gn_g   = (const float*)d_in[13];
    const float* gn_b   = (const float*)d_in[14];
    const float* w_1x1  = (const float*)d_in[15];
    const float* bn1_g  = (const float*)d_in[16];
    const float* bn1_b  = (const float*)d_in[17];
    const float* bn1_m  = (const float*)d_in[18];
    const float* bn1_v  = (const float*)d_in[19];
    const float* bn2_g  = (const float*)d_in[20];
    const float* bn2_b  = (const float*)d_in[21];
    const float* bn2_m  = (const float*)d_in[22];
    const float* bn2_v  = (const float*)d_in[23];
    const float* w_se1  = (const float*)d_in[24];
    const float* b_se1  = (const float*)d_in[25];
    const float* bnse_g = (const float*)d_in[26];
    const float* bnse_b = (const float*)d_in[27];
    const float* bnse_m = (const float*)d_in[28];
    const float* bnse_v = (const float*)d_in[29];
    const float* w_se2  = (const float*)d_in[30];
    const float* b_se2  = (const float*)d_in[31];

    float* ws    = (float*)d_ws;
    u32*  xh2   = (u32*)ws;                       // pair-interleaved bf16 x
    u32*  k2dh2 = (u32*)(ws + 8388608);           // pair-interleaved bf16 k2d
    u16*  vh    = (u16*)(ws + 16777216);          // bf16
    u16*  aggh  = (u16*)(ws + 25165824);          // bf16
    u16*  wdh   = (u16*)(ws + 33554432);          // bf16
    u32*  wk2   = (u32*)(ws + 39845888);
    u32*  w12   = wk2 + 6144;
    u32*  we12  = w12 + 8192;
    u32*  we22  = we12 + 8192;
    float* st   = ws + 46137344;
    float* gnsum  = st;
    float* gnsq   = st + 1024;
    float* gap    = st + 2048;
    float* gnmean = st + 2560;
    float* gnrstd = st + 3584;
    float* attn   = st + 4608;
    float* a_buf  = st;            // aliases gnsum (dead after kC2)

    hipMemsetAsync(gnsum, 0, 2560 * sizeof(float), stream);

    kW_pack<<<100, 256, 0, stream>>>(w_key, w_1x1, w_e1, w_e2, wk2, w12, we12, we22);
    kX_cvt<<<8192, 256, 0, stream>>>(x, xh2);
    kA_key<<<1024, 256, 0, stream>>>(xh2, wk2, bnk_g, bnk_b, bnk_m, bnk_v, k2dh2, gap);
    kB_val<<<1024, 256, 0, stream>>>(xh2, w12, bn1_g, bn1_b, bn1_m, bn1_v, vh);
    kC_wd<<<512, 512, 0, stream>>>(xh2, k2dh2, we12, bne_g, bne_b, bne_m, bne_v,
                                   we22, b_e2, wdh, gnsum, gnsq);
    kC2_gn<<<4, 256, 0, stream>>>(gnsum, gnsq, gnmean, gnrstd);
    kD_agg<<<1024, 256, 0, stream>>>(wdh, vh, gnmean, gnrstd, gn_g, gn_b,
                                     bn2_g, bn2_b, bn2_m, bn2_v, aggh, gap);
    kE1_a<<<2, 256, 0, stream>>>(gap, w_se1, b_se1, bnse_g, bnse_b, bnse_m, bnse_v, a_buf);
    kE2_attn<<<2, 256, 0, stream>>>(a_buf, w_se2, b_se2, attn);
    kF_out<<<8192, 256, 0, stream>>>((float*)d_out, aggh, k2dh2, attn);
}

// Round 13
// 245.542 us; speedup vs baseline: 2.7910x; 1.0451x over previous
//
#include <hip/hip_runtime.h>

#define EPSV 1e-5f
typedef unsigned short u16;
typedef unsigned int u32;

// Problem constants: B=4, N=8, B2=32, C=128, H=W=64, HW=4096, KS=3
// Workspace (float offsets):
//   [0,        8388608)  xh2   (u32 pair-interleaved bf16 x: dword=(ch2c2,ch2c2+1))
//   [8388608, 16777216)  k2dh2 (u32 pair-interleaved bf16 k2d)
//   [16777216,25165824)  vh    (u16 bf16, standard layout)
//   [25165824,33554432)  aggh  (u16 bf16, standard layout)
//   [33554432,39845888)  wdh   (u16 bf16, standard layout)
//   [39845888,39871488)  packed weights: wk2[6144] w12[8192] wB[8192] we22[3072]
//   stats @46137344: gnsum[1024] gnsq[1024] gap[512] gnmean[1024] gnrstd[1024] attn[1024]

typedef __attribute__((ext_vector_type(8))) __bf16 bf16x8;
typedef __attribute__((ext_vector_type(4))) float f32x4;
union ABcast { uint4 u; bf16x8 v; };

__device__ __forceinline__ u32 bfbits(float f) {   // RNE f32->bf16 bits
    u32 u = __float_as_uint(f);
    u += 0x7fff + ((u >> 16) & 1);
    return u >> 16;
}
__device__ __forceinline__ float bflo(u32 p) { return __uint_as_float(p << 16); }
__device__ __forceinline__ float bfhi(u32 p) { return __uint_as_float(p & 0xffff0000u); }

__device__ __forceinline__ float dot2bf(u32 a, u32 b, float c) {
    float d;
    asm("v_dot2_f32_bf16 %0, %1, %2, %3" : "=v"(d) : "v"(a), "v"(b), "v"(c));
    return d;
}

// ---- kW: pack weights ----
__global__ __launch_bounds__(256) void kW_pack(
    const float* __restrict__ wk, const float* __restrict__ w1,
    const float* __restrict__ we1, const float* __restrict__ we2,
    u32* __restrict__ wk2, u32* __restrict__ w12,
    u32* __restrict__ wB, u32* __restrict__ we22)
{
    int i = blockIdx.x * 256 + threadIdx.x;
    if (i < 6144) {                       // wk2[(o*3+dk)*16 + c2]
        int o = i / 48, r = i % 48, dk = r / 16, c2 = r % 16;
        wk2[(o * 3 + dk) * 16 + c2] =
            bfbits(wk[o * 96 + 6 * c2 + dk]) | (bfbits(wk[o * 96 + 6 * c2 + 3 + dk]) << 16);
    } else if (i < 14336) {               // w12[o*64 + c2]
        int j = i - 6144, o = j >> 6, c2 = j & 63;
        w12[j] = bfbits(w1[o * 128 + 2 * c2]) | (bfbits(w1[o * 128 + 2 * c2 + 1]) << 16);
    } else if (i < 22528) {               // wB: MFMA B-fragments of w_e1
        int j2 = i - 14336;               // ((kb*4+nt)*64+ln)*4 + jj
        int jj = j2 & 3;
        int ln = (j2 >> 2) & 63;
        int nt = (j2 >> 8) & 3;
        int kb = j2 >> 10;
        int n  = nt * 16 + (ln & 15);
        int k  = kb * 32 + (ln >> 4) * 8 + 2 * jj;
        wB[j2] = bfbits(we1[n * 256 + k]) | (bfbits(we1[n * 256 + k + 1]) << 16);
    } else if (i < 25600) {               // we22[row*32 + c2]
        int j = i - 22528, row = j >> 5, c2 = j & 31;
        we22[j] = bfbits(we2[row * 64 + 2 * c2]) | (bfbits(we2[row * 64 + 2 * c2 + 1]) << 16);
    }
}

// ---- kX: x (fp32) -> xh2 (u32 channel-pair bf16) ----
__global__ __launch_bounds__(256, 8) void kX_cvt(
    const float* __restrict__ x, u32* __restrict__ xh2)
{
    int qid = blockIdx.x * 256 + threadIdx.x;
    int px  = (qid & 1023) * 4;
    int c2g = qid >> 10;
    const float4 a = *(const float4*)(x + (c2g * 2) * 4096 + px);
    const float4 b = *(const float4*)(x + (c2g * 2 + 1) * 4096 + px);
    uint4 o;
    o.x = bfbits(a.x) | (bfbits(b.x) << 16);
    o.y = bfbits(a.y) | (bfbits(b.y) << 16);
    o.z = bfbits(a.z) | (bfbits(b.z) << 16);
    o.w = bfbits(a.w) | (bfbits(b.w) << 16);
    *(uint4*)(xh2 + c2g * 4096 + px) = o;
}

// ---- kA: key_embed -> k2dh2 (pair-interleaved), + gap ----
__global__ __launch_bounds__(256, 4) void kA_key(
    const u32* __restrict__ xh2, const u32* __restrict__ wk2,
    const float* __restrict__ g, const float* __restrict__ bb,
    const float* __restrict__ m, const float* __restrict__ vr,
    u32* __restrict__ k2dh2, float* __restrict__ gap)
{
    int blk   = blockIdx.x;
    int strip = blk & 3;
    int half  = (blk >> 2) & 1;
    int grp   = (blk >> 3) & 3;
    int b2    = blk >> 5;
    int px0   = strip * 1024 + threadIdx.x * 4;
    int bi = b2 >> 3, ni = b2 & 7;
    int ob = grp * 32 + half * 16;

    float acc[16][4];
    #pragma unroll
    for (int j = 0; j < 16; ++j)
        acc[j][0] = acc[j][1] = acc[j][2] = acc[j][3] = 0.f;

    #pragma unroll
    for (int dk = 0; dk < 3; ++dk) {
        int nf = ni + dk - 1;
        if (nf >= 0 && nf < 8) {
            const u32* xp = xh2 + ((bi * 8 + nf) * 64 + grp * 16) * 4096 + px0;
            const u32* wp = wk2 + (ob * 3 + dk) * 16;
            #pragma unroll 4
            for (int c2 = 0; c2 < 16; ++c2) {
                const uint4 xv = *(const uint4*)(xp + c2 * 4096);
                #pragma unroll
                for (int j = 0; j < 16; ++j) {
                    u32 w = wp[j * 48 + c2];
                    acc[j][0] = dot2bf(xv.x, w, acc[j][0]);
                    acc[j][1] = dot2bf(xv.y, w, acc[j][1]);
                    acc[j][2] = dot2bf(xv.z, w, acc[j][2]);
                    acc[j][3] = dot2bf(xv.w, w, acc[j][3]);
                }
            }
        }
    }

    int lane = threadIdx.x & 63, wid = threadIdx.x >> 6;
    __shared__ float ssum[16][4];
    float r[16][4];
    #pragma unroll
    for (int j = 0; j < 16; ++j) {
        int o = ob + j;
        float s = g[o] * rsqrtf(vr[o] + EPSV);
        float t = bb[o] - m[o] * s;
        float lsum = 0.f;
        #pragma unroll
        for (int p = 0; p < 4; ++p) {
            r[j][p] = fmaxf(fmaf(acc[j][p], s, t), 0.f);
            lsum += r[j][p];
        }
        #pragma unroll
        for (int off = 32; off; off >>= 1) lsum += __shfl_down(lsum, off, 64);
        if (lane == 0) ssum[j][wid] = lsum;
    }
    #pragma unroll
    for (int jj = 0; jj < 8; ++jj) {
        int c2out = grp * 16 + half * 8 + jj;
        uint4 pk;
        pk.x = bfbits(r[2 * jj][0]) | (bfbits(r[2 * jj + 1][0]) << 16);
        pk.y = bfbits(r[2 * jj][1]) | (bfbits(r[2 * jj + 1][1]) << 16);
        pk.z = bfbits(r[2 * jj][2]) | (bfbits(r[2 * jj + 1][2]) << 16);
        pk.w = bfbits(r[2 * jj][3]) | (bfbits(r[2 * jj + 1][3]) << 16);
        *(uint4*)(k2dh2 + (b2 * 64 + c2out) * 4096 + px0) = pk;
    }
    __syncthreads();
    if (threadIdx.x < 16) {
        float* sr = ssum[threadIdx.x];
        atomicAdd(&gap[bi * 128 + ob + threadIdx.x], sr[0] + sr[1] + sr[2] + sr[3]);
    }
}

// ---- kB: v = BN(x @ w_1x1) -> bf16 (standard layout) ----
__global__ __launch_bounds__(256, 4) void kB_val(
    const u32* __restrict__ xh2, const u32* __restrict__ w12,
    const float* __restrict__ g, const float* __restrict__ bb,
    const float* __restrict__ m, const float* __restrict__ vr,
    u16* __restrict__ vh)
{
    int blk   = blockIdx.x;
    int ocg   = blk & 7;
    int strip = (blk >> 3) & 3;
    int b2    = blk >> 5;
    int px0   = strip * 1024 + threadIdx.x * 4;
    const u32* xp = xh2 + b2 * 64 * 4096 + px0;
    const u32* wp = w12 + ocg * 16 * 64;

    float acc[16][4];
    #pragma unroll
    for (int j = 0; j < 16; ++j)
        acc[j][0] = acc[j][1] = acc[j][2] = acc[j][3] = 0.f;

    #pragma unroll 4
    for (int c2 = 0; c2 < 64; ++c2) {
        const uint4 xv = *(const uint4*)(xp + c2 * 4096);
        #pragma unroll
        for (int j = 0; j < 16; ++j) {
            u32 w = wp[j * 64 + c2];
            acc[j][0] = dot2bf(xv.x, w, acc[j][0]);
            acc[j][1] = dot2bf(xv.y, w, acc[j][1]);
            acc[j][2] = dot2bf(xv.z, w, acc[j][2]);
            acc[j][3] = dot2bf(xv.w, w, acc[j][3]);
        }
    }
    #pragma unroll
    for (int j = 0; j < 16; ++j) {
        int o = ocg * 16 + j;
        float s = g[o] * rsqrtf(vr[o] + EPSV);
        float t = bb[o] - m[o] * s;
        uint2 pk;
        pk.x = bfbits(fmaf(acc[j][0], s, t)) | (bfbits(fmaf(acc[j][1], s, t)) << 16);
        pk.y = bfbits(fmaf(acc[j][2], s, t)) | (bfbits(fmaf(acc[j][3], s, t)) << 16);
        *(uint2*)(vh + (b2 * 128 + o) * 4096 + px0) = pk;
    }
}

// ---- kC: stage1 e = ReLU(BN([x;k2d]@w_e1)) via MFMA 16x16x32 bf16;
//          stage2 wd = e@w_e2+b via dot2; GN partials.
// Block 256 thr = 4 waves, tile 128 px (8 M-tiles). Wave q: M-tiles 2q,2q+1 x 4 N-tiles.
// Grid 1024. LDS e_s2[32][132] u32 pairs (~16.9 KB).
__global__ __launch_bounds__(256, 3) void kC_wd(
    const u32* __restrict__ xh2, const u32* __restrict__ k2dh2,
    const u32* __restrict__ wB,
    const float* __restrict__ eg, const float* __restrict__ eb,
    const float* __restrict__ em, const float* __restrict__ ev,
    const u32* __restrict__ we22, const float* __restrict__ be2,
    u16* __restrict__ wdh, float* __restrict__ gnsum, float* __restrict__ gnsq)
{
    int tid  = threadIdx.x;
    int lane = tid & 63;
    int q    = __builtin_amdgcn_readfirstlane(tid >> 6);   // 0..3
    int tile = blockIdx.x & 31;
    int b2   = blockIdx.x >> 5;
    int px0  = tile * 128;
    int lrow = lane & 15;     // A row / D col
    int lk   = lane >> 4;     // k sub-block / D row group

    const u32* xb = xh2   + b2 * 64 * 4096;
    const u32* kb = k2dh2 + b2 * 64 * 4096;
    const uint4* wB4 = (const uint4*)wB;

    f32x4 acc[2][4];
    #pragma unroll
    for (int mt = 0; mt < 2; ++mt)
        #pragma unroll
        for (int nt = 0; nt < 4; ++nt)
            acc[mt][nt] = (f32x4){0.f, 0.f, 0.f, 0.f};

    int pxA0 = px0 + (2 * q) * 16 + lrow;
    int pxA1 = pxA0 + 16;

    #pragma unroll
    for (int kblk = 0; kblk < 8; ++kblk) {
        const u32* src = (kblk < 4) ? xb : kb;
        int c2b = (((kblk & 3) * 16) + lk * 4) * 4096;
        ABcast a0, a1;
        a0.u.x = src[c2b         + pxA0];
        a0.u.y = src[c2b + 4096  + pxA0];
        a0.u.z = src[c2b + 8192  + pxA0];
        a0.u.w = src[c2b + 12288 + pxA0];
        a1.u.x = src[c2b         + pxA1];
        a1.u.y = src[c2b + 4096  + pxA1];
        a1.u.z = src[c2b + 8192  + pxA1];
        a1.u.w = src[c2b + 12288 + pxA1];
        #pragma unroll
        for (int nt = 0; nt < 4; ++nt) {
            ABcast bfr;
            bfr.u = wB4[(kblk * 4 + nt) * 64 + lane];
            acc[0][nt] = __builtin_amdgcn_mfma_f32_16x16x32_bf16(a0.v, bfr.v, acc[0][nt], 0, 0, 0);
            acc[1][nt] = __builtin_amdgcn_mfma_f32_16x16x32_bf16(a1.v, bfr.v, acc[1][nt], 0, 0, 0);
        }
    }

    // epilogue: BN+ReLU, pack channel pairs via shfl_xor, write LDS
    __shared__ __align__(16) u32 e_s2[32][132];
    #pragma unroll
    for (int nt = 0; nt < 4; ++nt) {
        int ch = nt * 16 + lrow;
        float s = eg[ch] * rsqrtf(ev[ch] + EPSV);
        float t = eb[ch] - em[ch] * s;
        #pragma unroll
        for (int mt = 0; mt < 2; ++mt) {
            float r0 = fmaxf(fmaf(acc[mt][nt].x, s, t), 0.f);
            float r1 = fmaxf(fmaf(acc[mt][nt].y, s, t), 0.f);
            float r2 = fmaxf(fmaf(acc[mt][nt].z, s, t), 0.f);
            float r3 = fmaxf(fmaf(acc[mt][nt].w, s, t), 0.f);
            float p0 = __shfl_xor(r0, 1, 64);
            float p1 = __shfl_xor(r1, 1, 64);
            float p2 = __shfl_xor(r2, 1, 64);
            float p3 = __shfl_xor(r3, 1, 64);
            if (!(lane & 1)) {
                uint4 pk;
                pk.x = bfbits(r0) | (bfbits(p0) << 16);
                pk.y = bfbits(r1) | (bfbits(p1) << 16);
                pk.z = bfbits(r2) | (bfbits(p2) << 16);
                pk.w = bfbits(r3) | (bfbits(p3) << 16);
                *(uint4*)&e_s2[nt * 8 + (lrow >> 1)][(2 * q + mt) * 16 + lk * 4] = pk;
            }
        }
    }
    __syncthreads();

    // stage 2: wave q -> wd rows [24q, 24q+24); thread = 2 px
    int pxl  = lane * 2;
    int row0 = q * 24;
    const u32* w2q = we22 + row0 * 32;
    float wa[24][2];
    #pragma unroll
    for (int j = 0; j < 24; ++j) {
        float b = be2[row0 + j];
        wa[j][0] = wa[j][1] = b;
    }
    #pragma unroll 4
    for (int c2 = 0; c2 < 32; ++c2) {
        const uint2 eu = *(const uint2*)&e_s2[c2][pxl];
        #pragma unroll
        for (int j = 0; j < 24; ++j) {
            u32 w = w2q[j * 32 + c2];
            wa[j][0] = dot2bf(eu.x, w, wa[j][0]);
            wa[j][1] = dot2bf(eu.y, w, wa[j][1]);
        }
    }

    u16* wdp = wdh + (b2 * 96 + row0) * 4096 + px0 + pxl;
    #pragma unroll
    for (int j = 0; j < 24; ++j)
        *(u32*)(wdp + j * 4096) = bfbits(wa[j][0]) | (bfbits(wa[j][1]) << 16);

    #pragma unroll
    for (int jj = 0; jj < 8; ++jj) {
        float lsum = 0.f, lsq = 0.f;
        #pragma unroll
        for (int k = 0; k < 3; ++k)
            #pragma unroll
            for (int p = 0; p < 2; ++p) {
                float vv = wa[jj * 3 + k][p];
                lsum += vv; lsq += vv * vv;
            }
        #pragma unroll
        for (int off = 32; off; off >>= 1) {
            lsum += __shfl_down(lsum, off, 64);
            lsq  += __shfl_down(lsq,  off, 64);
        }
        if (lane == 0) {
            atomicAdd(&gnsum[b2 * 32 + q * 8 + jj], lsum);
            atomicAdd(&gnsq [b2 * 32 + q * 8 + jj], lsq);
        }
    }
}

// ---- kC2: finalize GroupNorm stats ----
__global__ __launch_bounds__(256) void kC2_gn(
    const float* __restrict__ gnsum, const float* __restrict__ gnsq,
    float* __restrict__ gnmean, float* __restrict__ gnrstd)
{
    int idx = blockIdx.x * 256 + threadIdx.x;
    const float inv = 1.f / 12288.f;
    float mu  = gnsum[idx] * inv;
    float var = fmaf(gnsq[idx], inv, -mu * mu);
    gnmean[idx] = mu;
    gnrstd[idx] = rsqrtf(fmaxf(var, 0.f) + EPSV);
}

// ---- kD: agg = SiLU(BN2(sum_k GN(wd)*unfold(v))) -> bf16 aggh, + gap ----
__global__ __launch_bounds__(256, 8) void kD_agg(
    const u16* __restrict__ wdh, const u16* __restrict__ vh,
    const float* __restrict__ gnmean, const float* __restrict__ gnrstd,
    const float* __restrict__ gng, const float* __restrict__ gnb,
    const float* __restrict__ g, const float* __restrict__ bb,
    const float* __restrict__ m, const float* __restrict__ vr,
    u16* __restrict__ aggh, float* __restrict__ gap)
{
    int blk   = blockIdx.x;
    int strip = blk & 7;
    int c1    = (blk >> 3) & 31;
    int bi    = blk >> 8;
    int px0   = strip * 512 + threadIdx.x * 2;

    float sch[4], tch[4], gl[4];
    #pragma unroll
    for (int ch = 0; ch < 4; ++ch) {
        int c = c1 * 4 + ch;
        float s = g[c] * rsqrtf(vr[c] + EPSV);
        sch[ch] = s; tch[ch] = bb[c] - m[c] * s; gl[ch] = 0.f;
    }
    float gg[3], gb[3];
    #pragma unroll
    for (int k = 0; k < 3; ++k) { gg[k] = gng[c1 * 3 + k]; gb[k] = gnb[c1 * 3 + k]; }

    float2 vreg[4][3];
    #pragma unroll
    for (int ch = 0; ch < 4; ++ch) {
        vreg[ch][0] = make_float2(0.f, 0.f);
        u32 v1u = *(const u32*)(vh + ((bi * 8 + 0) * 128 + c1 * 4 + ch) * 4096 + px0);
        u32 v2u = *(const u32*)(vh + ((bi * 8 + 1) * 128 + c1 * 4 + ch) * 4096 + px0);
        vreg[ch][1] = make_float2(bflo(v1u), bfhi(v1u));
        vreg[ch][2] = make_float2(bflo(v2u), bfhi(v2u));
    }

    for (int ni = 0; ni < 8; ++ni) {
        int b2 = bi * 8 + ni;
        float mu = gnmean[b2 * 32 + c1], rs = gnrstd[b2 * 32 + c1];
        float2 wn[3];
        #pragma unroll
        for (int k = 0; k < 3; ++k) {
            int nf = ni + k - 1;
            if (nf >= 0 && nf < 8) {
                u32 wvu = *(const u32*)(wdh + ((b2 * 96 + c1 * 3 + k) * 4096 + px0));
                wn[k].x = fmaf((bflo(wvu) - mu) * rs, gg[k], gb[k]);
                wn[k].y = fmaf((bfhi(wvu) - mu) * rs, gg[k], gb[k]);
            } else {
                wn[k] = make_float2(0.f, 0.f);
            }
        }
        #pragma unroll
        for (int ch = 0; ch < 4; ++ch) {
            float a0 = 0.f, a1 = 0.f;
            #pragma unroll
            for (int k = 0; k < 3; ++k) {
                a0 = fmaf(wn[k].x, vreg[ch][k].x, a0);
                a1 = fmaf(wn[k].y, vreg[ch][k].y, a1);
            }
            float y0 = fmaf(a0, sch[ch], tch[ch]);
            float y1 = fmaf(a1, sch[ch], tch[ch]);
            float r0 = y0 / (1.f + __expf(-y0));
            float r1 = y1 / (1.f + __expf(-y1));
            *(u32*)(aggh + (b2 * 128 + c1 * 4 + ch) * 4096 + px0) =
                bfbits(r0) | (bfbits(r1) << 16);
            gl[ch] += r0 + r1;
        }
        if (ni < 7) {
            #pragma unroll
            for (int ch = 0; ch < 4; ++ch) {
                vreg[ch][0] = vreg[ch][1];
                vreg[ch][1] = vreg[ch][2];
                if (ni + 2 < 8) {
                    u32 vu = *(const u32*)(vh + ((bi * 8 + ni + 2) * 128 + c1 * 4 + ch) * 4096 + px0);
                    vreg[ch][2] = make_float2(bflo(vu), bfhi(vu));
                }
            }
        }
    }

    __shared__ float sm[4][4];
    int lane = threadIdx.x & 63, wid = threadIdx.x >> 6;
    #pragma unroll
    for (int ch = 0; ch < 4; ++ch) {
        float s = gl[ch];
        #pragma unroll
        for (int off = 32; off; off >>= 1) s += __shfl_down(s, off, 64);
        if (lane == 0) sm[ch][wid] = s;
    }
    __syncthreads();
    if (threadIdx.x < 4) {
        float* sr = sm[threadIdx.x];
        atomicAdd(&gap[bi * 128 + c1 * 4 + threadIdx.x], sr[0] + sr[1] + sr[2] + sr[3]);
    }
}

// ---- kE1: a = ReLU(BNvec(gap/32768 @ w1^T + b1)) ----
__global__ __launch_bounds__(256) void kE1_a(
    const float* __restrict__ gap,
    const float* __restrict__ w1, const float* __restrict__ b1,
    const float* __restrict__ g, const float* __restrict__ bb,
    const float* __restrict__ m, const float* __restrict__ vr,
    float* __restrict__ a_buf)
{
    int idx = blockIdx.x * 256 + threadIdx.x;
    int bi = idx >> 7, oc = idx & 127;
    float acc = b1[oc];
    const float* gp = gap + bi * 128;
    const float* wp = w1 + oc * 128;
    for (int c = 0; c < 128; c += 4) {
        const float4 w4 = *(const float4*)(wp + c);
        acc = fmaf(gp[c + 0] * (1.f / 32768.f), w4.x, acc);
        acc = fmaf(gp[c + 1] * (1.f / 32768.f), w4.y, acc);
        acc = fmaf(gp[c + 2] * (1.f / 32768.f), w4.z, acc);
        acc = fmaf(gp[c + 3] * (1.f / 32768.f), w4.w, acc);
    }
    float s = g[oc] * rsqrtf(vr[oc] + EPSV);
    a_buf[bi * 128 + oc] = fmaxf(fmaf(acc, s, bb[oc] - m[oc] * s), 0.f);
}

// ---- kE2: attn = softmax over radix-2 pairs ----
__global__ __launch_bounds__(256) void kE2_attn(
    const float* __restrict__ a_buf,
    const float* __restrict__ w2, const float* __restrict__ b2v,
    float* __restrict__ attn)
{
    int idx = blockIdx.x * 256 + threadIdx.x;
    int bi = idx >> 7, cc = idx & 127;
    float l0 = b2v[cc * 2], l1 = b2v[cc * 2 + 1];
    const float* ap  = a_buf + bi * 128;
    const float* w0p = w2 + (cc * 2) * 128;
    const float* w1p = w2 + (cc * 2 + 1) * 128;
    for (int j = 0; j < 128; j += 4) {
        const float4 wa4 = *(const float4*)(w0p + j);
        const float4 wb4 = *(const float4*)(w1p + j);
        l0 = fmaf(ap[j + 0], wa4.x, l0); l1 = fmaf(ap[j + 0], wb4.x, l1);
        l0 = fmaf(ap[j + 1], wa4.y, l0); l1 = fmaf(ap[j + 1], wb4.y, l1);
        l0 = fmaf(ap[j + 2], wa4.z, l0); l1 = fmaf(ap[j + 2], wb4.z, l1);
        l0 = fmaf(ap[j + 3], wa4.w, l0); l1 = fmaf(ap[j + 3], wb4.w, l1);
    }
    float mx = fmaxf(l0, l1);
    float e0 = __expf(l0 - mx), e1 = __expf(l1 - mx);
    float inv = 1.f / (e0 + e1);
    attn[bi * 256 + cc * 2]     = e0 * inv;
    attn[bi * 256 + cc * 2 + 1] = e1 * inv;
}

// ---- kF: out = attn0*agg + attn1*k2d; block = (b2, c2-pair, strip) ----
__global__ __launch_bounds__(256, 8) void kF_out(
    float* __restrict__ out, const u16* __restrict__ aggh,
    const u32* __restrict__ k2dh2, const float* __restrict__ attn)
{
    int blk   = blockIdx.x;
    int strip = blk & 3;
    int c2    = (blk >> 2) & 63;
    int b2    = blk >> 8;
    int bi    = b2 >> 3;
    int px0   = strip * 1024 + threadIdx.x * 4;

    float a0e = attn[bi * 256 + 4 * c2];
    float a1e = attn[bi * 256 + 4 * c2 + 1];
    float a0o = attn[bi * 256 + 4 * c2 + 2];
    float a1o = attn[bi * 256 + 4 * c2 + 3];

    uint4 kk = *(const uint4*)(k2dh2 + (b2 * 64 + c2) * 4096 + px0);
    uint2 g0 = *(const uint2*)(aggh + (b2 * 128 + 2 * c2) * 4096 + px0);
    uint2 g1 = *(const uint2*)(aggh + (b2 * 128 + 2 * c2 + 1) * 4096 + px0);

    float4 re, ro;
    re.x = fmaf(a0e, bflo(g0.x), a1e * bflo(kk.x));
    re.y = fmaf(a0e, bfhi(g0.x), a1e * bflo(kk.y));
    re.z = fmaf(a0e, bflo(g0.y), a1e * bflo(kk.z));
    re.w = fmaf(a0e, bfhi(g0.y), a1e * bflo(kk.w));
    ro.x = fmaf(a0o, bflo(g1.x), a1o * bfhi(kk.x));
    ro.y = fmaf(a0o, bfhi(g1.x), a1o * bfhi(kk.y));
    ro.z = fmaf(a0o, bflo(g1.y), a1o * bfhi(kk.z));
    ro.w = fmaf(a0o, bfhi(g1.y), a1o * bfhi(kk.w));
    *(float4*)(out + (b2 * 128 + 2 * c2) * 4096 + px0) = re;
    *(float4*)(out + (b2 * 128 + 2 * c2 + 1) * 4096 + px0) = ro;
}

extern "C" void kernel_launch(void* const* d_in, const int* in_sizes, int n_in,
                              void* d_out, int out_size, void* d_ws, size_t ws_size,
                              hipStream_t stream)
{
    const float* x      = (const float*)d_in[0];
    const float* w_key  = (const float*)d_in[1];
    const float* bnk_g  = (const float*)d_in[2];
    const float* bnk_b  = (const float*)d_in[3];
    const float* bnk_m  = (const float*)d_in[4];
    const float* bnk_v  = (const float*)d_in[5];
    const float* w_e1   = (const float*)d_in[6];
    const float* bne_g  = (const float*)d_in[7];
    const float* bne_b  = (const float*)d_in[8];
    const float* bne_m  = (const float*)d_in[9];
    const float* bne_v  = (const float*)d_in[10];
    const float* w_e2   = (const float*)d_in[11];
    const float* b_e2   = (const float*)d_in[12];
    const float* gn_g   = (const float*)d_in[13];
    const float* gn_b   = (const float*)d_in[14];
    const float* w_1x1  = (const float*)d_in[15];
    const float* bn1_g  = (const float*)d_in[16];
    const float* bn1_b  = (const float*)d_in[17];
    const float* bn1_m  = (const float*)d_in[18];
    const float* bn1_v  = (const float*)d_in[19];
    const float* bn2_g  = (const float*)d_in[20];
    const float* bn2_b  = (const float*)d_in[21];
    const float* bn2_m  = (const float*)d_in[22];
    const float* bn2_v  = (const float*)d_in[23];
    const float* w_se1  = (const float*)d_in[24];
    const float* b_se1  = (const float*)d_in[25];
    const float* bnse_g = (const float*)d_in[26];
    const float* bnse_b = (const float*)d_in[27];
    const float* bnse_m = (const float*)d_in[28];
    const float* bnse_v = (const float*)d_in[29];
    const float* w_se2  = (const float*)d_in[30];
    const float* b_se2  = (const float*)d_in[31];

    float* ws    = (float*)d_ws;
    u32*  xh2   = (u32*)ws;
    u32*  k2dh2 = (u32*)(ws + 8388608);
    u16*  vh    = (u16*)(ws + 16777216);
    u16*  aggh  = (u16*)(ws + 25165824);
    u16*  wdh   = (u16*)(ws + 33554432);
    u32*  wk2   = (u32*)(ws + 39845888);
    u32*  w12   = wk2 + 6144;
    u32*  wB    = w12 + 8192;
    u32*  we22  = wB + 8192;
    float* st   = ws + 46137344;
    float* gnsum  = st;
    float* gnsq   = st + 1024;
    float* gap    = st + 2048;
    float* gnmean = st + 2560;
    float* gnrstd = st + 3584;
    float* attn   = st + 4608;
    float* a_buf  = st;            // aliases gnsum (dead after kC2)

    hipMemsetAsync(gnsum, 0, 2560 * sizeof(float), stream);

    kW_pack<<<100, 256, 0, stream>>>(w_key, w_1x1, w_e1, w_e2, wk2, w12, wB, we22);
    kX_cvt<<<8192, 256, 0, stream>>>(x, xh2);
    kA_key<<<1024, 256, 0, stream>>>(xh2, wk2, bnk_g, bnk_b, bnk_m, bnk_v, k2dh2, gap);
    kB_val<<<1024, 256, 0, stream>>>(xh2, w12, bn1_g, bn1_b, bn1_m, bn1_v, vh);
    kC_wd<<<1024, 256, 0, stream>>>(xh2, k2dh2, wB, bne_g, bne_b, bne_m, bne_v,
                                    we22, b_e2, wdh, gnsum, gnsq);
    kC2_gn<<<4, 256, 0, stream>>>(gnsum, gnsq, gnmean, gnrstd);
    kD_agg<<<1024, 256, 0, stream>>>(wdh, vh, gnmean, gnrstd, gn_g, gn_b,
                                     bn2_g, bn2_b, bn2_m, bn2_v, aggh, gap);
    kE1_a<<<2, 256, 0, stream>>>(gap, w_se1, b_se1, bnse_g, bnse_b, bnse_m, bnse_v, a_buf);
    kE2_attn<<<2, 256, 0, stream>>>(a_buf, w_se2, b_se2, attn);
    kF_out<<<8192, 256, 0, stream>>>((float*)d_out, aggh, k2dh2, attn);
}

// Round 14
// 179.528 us; speedup vs baseline: 3.8172x; 1.3677x over previous
//
#include <hip/hip_runtime.h>

#define EPSV 1e-5f
typedef unsigned short u16;
typedef unsigned int u32;

// Problem constants: B=4, N=8, B2=32, C=128, H=W=64, HW=4096, KS=3
// Workspace (float offsets):
//   [0,        8388608)  xh2   (u32 pair-interleaved bf16 x)
//   [8388608, 16777216)  k2dh2 (u32 pair-interleaved bf16 k2d)
//   [16777216,25165824)  vh    (u16 bf16, standard layout)
//   [25165824,33554432)  aggh  (u16 bf16, standard layout)
//   [33554432,39845888)  wdh   (u16 bf16, standard layout)
//   [39845888,39871488)  packed weights: wkF[6144] wB1[8192] wB[8192] we22[3072]
//   stats @46137344: gnsum[1024] gnsq[1024] gap[512] gnmean[1024] gnrstd[1024] attn[1024]

typedef __attribute__((ext_vector_type(8))) __bf16 bf16x8;
typedef __attribute__((ext_vector_type(4))) float f32x4;
union ABcast { uint4 u; bf16x8 v; };

__device__ __forceinline__ u32 bfbits(float f) {   // RNE f32->bf16 bits
    u32 u = __float_as_uint(f);
    u += 0x7fff + ((u >> 16) & 1);
    return u >> 16;
}
__device__ __forceinline__ float bflo(u32 p) { return __uint_as_float(p << 16); }
__device__ __forceinline__ float bfhi(u32 p) { return __uint_as_float(p & 0xffff0000u); }

__device__ __forceinline__ float dot2bf(u32 a, u32 b, float c) {
    float d;
    asm("v_dot2_f32_bf16 %0, %1, %2, %3" : "=v"(d) : "v"(a), "v"(b), "v"(c));
    return d;
}

// ---- kW: pack weights (MFMA fragments + dot2 tables) ----
__global__ __launch_bounds__(256) void kW_pack(
    const float* __restrict__ wk, const float* __restrict__ w1,
    const float* __restrict__ we1, const float* __restrict__ we2,
    u32* __restrict__ wkF, u32* __restrict__ wB1,
    u32* __restrict__ wB, u32* __restrict__ we22)
{
    int i = blockIdx.x * 256 + threadIdx.x;
    if (i < 6144) {                       // wkF: MFMA B-frags of w_key per (grp,dk)
        int jj = i & 3;
        int ln = (i >> 2) & 63;
        int nt = (i >> 8) & 1;
        int rest = i >> 9;                // grp*3+dk
        int grp = rest / 3, dk = rest % 3;
        int n = nt * 16 + (ln & 15);
        int k = (ln >> 4) * 8 + 2 * jj;
        int o = grp * 32 + n;
        wkF[i] = bfbits(wk[o * 96 + k * 3 + dk]) |
                 (bfbits(wk[o * 96 + (k + 1) * 3 + dk]) << 16);
    } else if (i < 14336) {               // wB1: MFMA B-frags of w_1x1
        int j2 = i - 6144;
        int jj = j2 & 3;
        int ln = (j2 >> 2) & 63;
        int nt = (j2 >> 8) & 7;
        int kb = j2 >> 11;
        int n = nt * 16 + (ln & 15);
        int k = kb * 32 + (ln >> 4) * 8 + 2 * jj;
        wB1[j2] = bfbits(w1[n * 128 + k]) | (bfbits(w1[n * 128 + k + 1]) << 16);
    } else if (i < 22528) {               // wB: MFMA B-frags of w_e1
        int j2 = i - 14336;
        int jj = j2 & 3;
        int ln = (j2 >> 2) & 63;
        int nt = (j2 >> 8) & 3;
        int kb = j2 >> 10;
        int n  = nt * 16 + (ln & 15);
        int k  = kb * 32 + (ln >> 4) * 8 + 2 * jj;
        wB[j2] = bfbits(we1[n * 256 + k]) | (bfbits(we1[n * 256 + k + 1]) << 16);
    } else if (i < 25600) {               // we22[row*32 + c2]
        int j = i - 22528, row = j >> 5, c2 = j & 31;
        we22[j] = bfbits(we2[row * 64 + 2 * c2]) | (bfbits(we2[row * 64 + 2 * c2 + 1]) << 16);
    }
}

// ---- kX: x (fp32) -> xh2 (u32 channel-pair bf16) ----
__global__ __launch_bounds__(256, 8) void kX_cvt(
    const float* __restrict__ x, u32* __restrict__ xh2)
{
    int qid = blockIdx.x * 256 + threadIdx.x;
    int px  = (qid & 1023) * 4;
    int c2g = qid >> 10;
    const float4 a = *(const float4*)(x + (c2g * 2) * 4096 + px);
    const float4 b = *(const float4*)(x + (c2g * 2 + 1) * 4096 + px);
    uint4 o;
    o.x = bfbits(a.x) | (bfbits(b.x) << 16);
    o.y = bfbits(a.y) | (bfbits(b.y) << 16);
    o.z = bfbits(a.z) | (bfbits(b.z) << 16);
    o.w = bfbits(a.w) | (bfbits(b.w) << 16);
    *(uint4*)(xh2 + c2g * 4096 + px) = o;
}

// ---- kA: key_embed via MFMA -> k2dh2 (pair-interleaved), + gap ----
// Block = (b2, grp, 256-px tile), 4 waves; wave q: M-tiles 4q..4q+3 x 2 N-tiles.
// K = 32 per dk (1 kblk), 3 conditional dk accumulations. Grid 2048.
__global__ __launch_bounds__(256, 4) void kA_key(
    const u32* __restrict__ xh2, const u32* __restrict__ wkF,
    const float* __restrict__ g, const float* __restrict__ bb,
    const float* __restrict__ m, const float* __restrict__ vr,
    u32* __restrict__ k2dh2, float* __restrict__ gap)
{
    int tid  = threadIdx.x;
    int lane = tid & 63;
    int q    = __builtin_amdgcn_readfirstlane(tid >> 6);   // 0..3
    int blk  = blockIdx.x;
    int tile = blk & 15;
    int grp  = (blk >> 4) & 3;
    int b2   = blk >> 6;
    int px0  = tile * 256;
    int bi = b2 >> 3, ni = b2 & 7;
    int lrow = lane & 15, lk = lane >> 4;
    const uint4* wkF4 = (const uint4*)wkF;

    f32x4 acc[4][2];
    #pragma unroll
    for (int mt = 0; mt < 4; ++mt)
        #pragma unroll
        for (int nt = 0; nt < 2; ++nt)
            acc[mt][nt] = (f32x4){0.f, 0.f, 0.f, 0.f};

    int pxA[4];
    #pragma unroll
    for (int mt = 0; mt < 4; ++mt) pxA[mt] = px0 + (4 * q + mt) * 16 + lrow;

    #pragma unroll
    for (int dk = 0; dk < 3; ++dk) {
        int nf = ni + dk - 1;
        if (nf >= 0 && nf < 8) {
            const u32* src = xh2 + ((bi * 8 + nf) * 64 + grp * 16) * 4096;
            int c2b = (lk * 4) * 4096;
            ABcast a[4];
            #pragma unroll
            for (int mt = 0; mt < 4; ++mt) {
                a[mt].u.x = src[c2b         + pxA[mt]];
                a[mt].u.y = src[c2b + 4096  + pxA[mt]];
                a[mt].u.z = src[c2b + 8192  + pxA[mt]];
                a[mt].u.w = src[c2b + 12288 + pxA[mt]];
            }
            #pragma unroll
            for (int nt = 0; nt < 2; ++nt) {
                ABcast bfr;
                bfr.u = wkF4[((grp * 3 + dk) * 2 + nt) * 64 + lane];
                #pragma unroll
                for (int mt = 0; mt < 4; ++mt)
                    acc[mt][nt] = __builtin_amdgcn_mfma_f32_16x16x32_bf16(
                        a[mt].v, bfr.v, acc[mt][nt], 0, 0, 0);
            }
        }
    }

    __shared__ float ssum[32][4];
    #pragma unroll
    for (int nt = 0; nt < 2; ++nt) {
        int ch = grp * 32 + nt * 16 + lrow;
        float s = g[ch] * rsqrtf(vr[ch] + EPSV);
        float t = bb[ch] - m[ch] * s;
        float lsum = 0.f;
        #pragma unroll
        for (int mt = 0; mt < 4; ++mt) {
            float r0 = fmaxf(fmaf(acc[mt][nt].x, s, t), 0.f);
            float r1 = fmaxf(fmaf(acc[mt][nt].y, s, t), 0.f);
            float r2 = fmaxf(fmaf(acc[mt][nt].z, s, t), 0.f);
            float r3 = fmaxf(fmaf(acc[mt][nt].w, s, t), 0.f);
            lsum += r0 + r1 + r2 + r3;
            float p0 = __shfl_xor(r0, 1, 64);
            float p1 = __shfl_xor(r1, 1, 64);
            float p2 = __shfl_xor(r2, 1, 64);
            float p3 = __shfl_xor(r3, 1, 64);
            if (!(lane & 1)) {
                int c2out = grp * 16 + nt * 8 + (lrow >> 1);
                uint4 pk;
                pk.x = bfbits(r0) | (bfbits(p0) << 16);
                pk.y = bfbits(r1) | (bfbits(p1) << 16);
                pk.z = bfbits(r2) | (bfbits(p2) << 16);
                pk.w = bfbits(r3) | (bfbits(p3) << 16);
                *(uint4*)(k2dh2 + (b2 * 64 + c2out) * 4096 +
                          px0 + (4 * q + mt) * 16 + lk * 4) = pk;
            }
        }
        lsum += __shfl_xor(lsum, 16, 64);
        lsum += __shfl_xor(lsum, 32, 64);
        if (lane < 16) ssum[nt * 16 + lrow][q] = lsum;
    }
    __syncthreads();
    if (tid < 32) {
        float* sr = ssum[tid];
        atomicAdd(&gap[bi * 128 + grp * 32 + tid], sr[0] + sr[1] + sr[2] + sr[3]);
    }
}

// ---- kB: v = BN(x @ w_1x1) via MFMA -> bf16 vh (standard layout) ----
// Block = (b2, 128-px tile), 4 waves; wave q: M-tiles 2q,2q+1 x 8 N-tiles. Grid 1024.
__global__ __launch_bounds__(256, 3) void kB_val(
    const u32* __restrict__ xh2, const u32* __restrict__ wB1,
    const float* __restrict__ g, const float* __restrict__ bb,
    const float* __restrict__ m, const float* __restrict__ vr,
    u16* __restrict__ vh)
{
    int tid  = threadIdx.x;
    int lane = tid & 63;
    int q    = __builtin_amdgcn_readfirstlane(tid >> 6);   // 0..3
    int tile = blockIdx.x & 31;
    int b2   = blockIdx.x >> 5;
    int px0  = tile * 128;
    int lrow = lane & 15, lk = lane >> 4;

    const u32* xb = xh2 + b2 * 64 * 4096;
    const uint4* wB14 = (const uint4*)wB1;

    f32x4 acc[2][8];
    #pragma unroll
    for (int mt = 0; mt < 2; ++mt)
        #pragma unroll
        for (int nt = 0; nt < 8; ++nt)
            acc[mt][nt] = (f32x4){0.f, 0.f, 0.f, 0.f};

    int pxA0 = px0 + (2 * q) * 16 + lrow;
    int pxA1 = pxA0 + 16;

    #pragma unroll
    for (int kblk = 0; kblk < 4; ++kblk) {
        int c2b = (kblk * 16 + lk * 4) * 4096;
        ABcast a0, a1;
        a0.u.x = xb[c2b         + pxA0];
        a0.u.y = xb[c2b + 4096  + pxA0];
        a0.u.z = xb[c2b + 8192  + pxA0];
        a0.u.w = xb[c2b + 12288 + pxA0];
        a1.u.x = xb[c2b         + pxA1];
        a1.u.y = xb[c2b + 4096  + pxA1];
        a1.u.z = xb[c2b + 8192  + pxA1];
        a1.u.w = xb[c2b + 12288 + pxA1];
        #pragma unroll
        for (int nt = 0; nt < 8; ++nt) {
            ABcast bfr;
            bfr.u = wB14[(kblk * 8 + nt) * 64 + lane];
            acc[0][nt] = __builtin_amdgcn_mfma_f32_16x16x32_bf16(a0.v, bfr.v, acc[0][nt], 0, 0, 0);
            acc[1][nt] = __builtin_amdgcn_mfma_f32_16x16x32_bf16(a1.v, bfr.v, acc[1][nt], 0, 0, 0);
        }
    }

    #pragma unroll
    for (int nt = 0; nt < 8; ++nt) {
        int ch = nt * 16 + lrow;
        float s = g[ch] * rsqrtf(vr[ch] + EPSV);
        float t = bb[ch] - m[ch] * s;
        #pragma unroll
        for (int mt = 0; mt < 2; ++mt) {
            float r0 = fmaf(acc[mt][nt].x, s, t);
            float r1 = fmaf(acc[mt][nt].y, s, t);
            float r2 = fmaf(acc[mt][nt].z, s, t);
            float r3 = fmaf(acc[mt][nt].w, s, t);
            uint2 pk;
            pk.x = bfbits(r0) | (bfbits(r1) << 16);
            pk.y = bfbits(r2) | (bfbits(r3) << 16);
            *(uint2*)(vh + (b2 * 128 + ch) * 4096 +
                      px0 + (2 * q + mt) * 16 + lk * 4) = pk;
        }
    }
}

// ---- kC: stage1 e via MFMA; stage2 wd via dot2; GN partials ----
__global__ __launch_bounds__(256, 3) void kC_wd(
    const u32* __restrict__ xh2, const u32* __restrict__ k2dh2,
    const u32* __restrict__ wB,
    const float* __restrict__ eg, const float* __restrict__ eb,
    const float* __restrict__ em, const float* __restrict__ ev,
    const u32* __restrict__ we22, const float* __restrict__ be2,
    u16* __restrict__ wdh, float* __restrict__ gnsum, float* __restrict__ gnsq)
{
    int tid  = threadIdx.x;
    int lane = tid & 63;
    int q    = __builtin_amdgcn_readfirstlane(tid >> 6);   // 0..3
    int tile = blockIdx.x & 31;
    int b2   = blockIdx.x >> 5;
    int px0  = tile * 128;
    int lrow = lane & 15;
    int lk   = lane >> 4;

    const u32* xb = xh2   + b2 * 64 * 4096;
    const u32* kb = k2dh2 + b2 * 64 * 4096;
    const uint4* wB4 = (const uint4*)wB;

    f32x4 acc[2][4];
    #pragma unroll
    for (int mt = 0; mt < 2; ++mt)
        #pragma unroll
        for (int nt = 0; nt < 4; ++nt)
            acc[mt][nt] = (f32x4){0.f, 0.f, 0.f, 0.f};

    int pxA0 = px0 + (2 * q) * 16 + lrow;
    int pxA1 = pxA0 + 16;

    #pragma unroll
    for (int kblk = 0; kblk < 8; ++kblk) {
        const u32* src = (kblk < 4) ? xb : kb;
        int c2b = (((kblk & 3) * 16) + lk * 4) * 4096;
        ABcast a0, a1;
        a0.u.x = src[c2b         + pxA0];
        a0.u.y = src[c2b + 4096  + pxA0];
        a0.u.z = src[c2b + 8192  + pxA0];
        a0.u.w = src[c2b + 12288 + pxA0];
        a1.u.x = src[c2b         + pxA1];
        a1.u.y = src[c2b + 4096  + pxA1];
        a1.u.z = src[c2b + 8192  + pxA1];
        a1.u.w = src[c2b + 12288 + pxA1];
        #pragma unroll
        for (int nt = 0; nt < 4; ++nt) {
            ABcast bfr;
            bfr.u = wB4[(kblk * 4 + nt) * 64 + lane];
            acc[0][nt] = __builtin_amdgcn_mfma_f32_16x16x32_bf16(a0.v, bfr.v, acc[0][nt], 0, 0, 0);
            acc[1][nt] = __builtin_amdgcn_mfma_f32_16x16x32_bf16(a1.v, bfr.v, acc[1][nt], 0, 0, 0);
        }
    }

    __shared__ __align__(16) u32 e_s2[32][132];
    #pragma unroll
    for (int nt = 0; nt < 4; ++nt) {
        int ch = nt * 16 + lrow;
        float s = eg[ch] * rsqrtf(ev[ch] + EPSV);
        float t = eb[ch] - em[ch] * s;
        #pragma unroll
        for (int mt = 0; mt < 2; ++mt) {
            float r0 = fmaxf(fmaf(acc[mt][nt].x, s, t), 0.f);
            float r1 = fmaxf(fmaf(acc[mt][nt].y, s, t), 0.f);
            float r2 = fmaxf(fmaf(acc[mt][nt].z, s, t), 0.f);
            float r3 = fmaxf(fmaf(acc[mt][nt].w, s, t), 0.f);
            float p0 = __shfl_xor(r0, 1, 64);
            float p1 = __shfl_xor(r1, 1, 64);
            float p2 = __shfl_xor(r2, 1, 64);
            float p3 = __shfl_xor(r3, 1, 64);
            if (!(lane & 1)) {
                uint4 pk;
                pk.x = bfbits(r0) | (bfbits(p0) << 16);
                pk.y = bfbits(r1) | (bfbits(p1) << 16);
                pk.z = bfbits(r2) | (bfbits(p2) << 16);
                pk.w = bfbits(r3) | (bfbits(p3) << 16);
                *(uint4*)&e_s2[nt * 8 + (lrow >> 1)][(2 * q + mt) * 16 + lk * 4] = pk;
            }
        }
    }
    __syncthreads();

    int pxl  = lane * 2;
    int row0 = q * 24;
    const u32* w2q = we22 + row0 * 32;
    float wa[24][2];
    #pragma unroll
    for (int j = 0; j < 24; ++j) {
        float b = be2[row0 + j];
        wa[j][0] = wa[j][1] = b;
    }
    #pragma unroll 4
    for (int c2 = 0; c2 < 32; ++c2) {
        const uint2 eu = *(const uint2*)&e_s2[c2][pxl];
        #pragma unroll
        for (int j = 0; j < 24; ++j) {
            u32 w = w2q[j * 32 + c2];
            wa[j][0] = dot2bf(eu.x, w, wa[j][0]);
            wa[j][1] = dot2bf(eu.y, w, wa[j][1]);
        }
    }

    u16* wdp = wdh + (b2 * 96 + row0) * 4096 + px0 + pxl;
    #pragma unroll
    for (int j = 0; j < 24; ++j)
        *(u32*)(wdp + j * 4096) = bfbits(wa[j][0]) | (bfbits(wa[j][1]) << 16);

    #pragma unroll
    for (int jj = 0; jj < 8; ++jj) {
        float lsum = 0.f, lsq = 0.f;
        #pragma unroll
        for (int k = 0; k < 3; ++k)
            #pragma unroll
            for (int p = 0; p < 2; ++p) {
                float vv = wa[jj * 3 + k][p];
                lsum += vv; lsq += vv * vv;
            }
        #pragma unroll
        for (int off = 32; off; off >>= 1) {
            lsum += __shfl_down(lsum, off, 64);
            lsq  += __shfl_down(lsq,  off, 64);
        }
        if (lane == 0) {
            atomicAdd(&gnsum[b2 * 32 + q * 8 + jj], lsum);
            atomicAdd(&gnsq [b2 * 32 + q * 8 + jj], lsq);
        }
    }
}

// ---- kC2: finalize GroupNorm stats ----
__global__ __launch_bounds__(256) void kC2_gn(
    const float* __restrict__ gnsum, const float* __restrict__ gnsq,
    float* __restrict__ gnmean, float* __restrict__ gnrstd)
{
    int idx = blockIdx.x * 256 + threadIdx.x;
    const float inv = 1.f / 12288.f;
    float mu  = gnsum[idx] * inv;
    float var = fmaf(gnsq[idx], inv, -mu * mu);
    gnmean[idx] = mu;
    gnrstd[idx] = rsqrtf(fmaxf(var, 0.f) + EPSV);
}

// ---- kD: agg = SiLU(BN2(sum_k GN(wd)*unfold(v))) -> bf16 aggh, + gap ----
__global__ __launch_bounds__(256, 8) void kD_agg(
    const u16* __restrict__ wdh, const u16* __restrict__ vh,
    const float* __restrict__ gnmean, const float* __restrict__ gnrstd,
    const float* __restrict__ gng, const float* __restrict__ gnb,
    const float* __restrict__ g, const float* __restrict__ bb,
    const float* __restrict__ m, const float* __restrict__ vr,
    u16* __restrict__ aggh, float* __restrict__ gap)
{
    int blk   = blockIdx.x;
    int strip = blk & 7;
    int c1    = (blk >> 3) & 31;
    int bi    = blk >> 8;
    int px0   = strip * 512 + threadIdx.x * 2;

    float sch[4], tch[4], gl[4];
    #pragma unroll
    for (int ch = 0; ch < 4; ++ch) {
        int c = c1 * 4 + ch;
        float s = g[c] * rsqrtf(vr[c] + EPSV);
        sch[ch] = s; tch[ch] = bb[c] - m[c] * s; gl[ch] = 0.f;
    }
    float gg[3], gb[3];
    #pragma unroll
    for (int k = 0; k < 3; ++k) { gg[k] = gng[c1 * 3 + k]; gb[k] = gnb[c1 * 3 + k]; }

    float2 vreg[4][3];
    #pragma unroll
    for (int ch = 0; ch < 4; ++ch) {
        vreg[ch][0] = make_float2(0.f, 0.f);
        u32 v1u = *(const u32*)(vh + ((bi * 8 + 0) * 128 + c1 * 4 + ch) * 4096 + px0);
        u32 v2u = *(const u32*)(vh + ((bi * 8 + 1) * 128 + c1 * 4 + ch) * 4096 + px0);
        vreg[ch][1] = make_float2(bflo(v1u), bfhi(v1u));
        vreg[ch][2] = make_float2(bflo(v2u), bfhi(v2u));
    }

    for (int ni = 0; ni < 8; ++ni) {
        int b2 = bi * 8 + ni;
        float mu = gnmean[b2 * 32 + c1], rs = gnrstd[b2 * 32 + c1];
        float2 wn[3];
        #pragma unroll
        for (int k = 0; k < 3; ++k) {
            int nf = ni + k - 1;
            if (nf >= 0 && nf < 8) {
                u32 wvu = *(const u32*)(wdh + ((b2 * 96 + c1 * 3 + k) * 4096 + px0));
                wn[k].x = fmaf((bflo(wvu) - mu) * rs, gg[k], gb[k]);
                wn[k].y = fmaf((bfhi(wvu) - mu) * rs, gg[k], gb[k]);
            } else {
                wn[k] = make_float2(0.f, 0.f);
            }
        }
        #pragma unroll
        for (int ch = 0; ch < 4; ++ch) {
            float a0 = 0.f, a1 = 0.f;
            #pragma unroll
            for (int k = 0; k < 3; ++k) {
                a0 = fmaf(wn[k].x, vreg[ch][k].x, a0);
                a1 = fmaf(wn[k].y, vreg[ch][k].y, a1);
            }
            float y0 = fmaf(a0, sch[ch], tch[ch]);
            float y1 = fmaf(a1, sch[ch], tch[ch]);
            float r0 = y0 / (1.f + __expf(-y0));
            float r1 = y1 / (1.f + __expf(-y1));
            *(u32*)(aggh + (b2 * 128 + c1 * 4 + ch) * 4096 + px0) =
                bfbits(r0) | (bfbits(r1) << 16);
            gl[ch] += r0 + r1;
        }
        if (ni < 7) {
            #pragma unroll
            for (int ch = 0; ch < 4; ++ch) {
                vreg[ch][0] = vreg[ch][1];
                vreg[ch][1] = vreg[ch][2];
                if (ni + 2 < 8) {
                    u32 vu = *(const u32*)(vh + ((bi * 8 + ni + 2) * 128 + c1 * 4 + ch) * 4096 + px0);
                    vreg[ch][2] = make_float2(bflo(vu), bfhi(vu));
                }
            }
        }
    }

    __shared__ float sm[4][4];
    int lane = threadIdx.x & 63, wid = threadIdx.x >> 6;
    #pragma unroll
    for (int ch = 0; ch < 4; ++ch) {
        float s = gl[ch];
        #pragma unroll
        for (int off = 32; off; off >>= 1) s += __shfl_down(s, off, 64);
        if (lane == 0) sm[ch][wid] = s;
    }
    __syncthreads();
    if (threadIdx.x < 4) {
        float* sr = sm[threadIdx.x];
        atomicAdd(&gap[bi * 128 + c1 * 4 + threadIdx.x], sr[0] + sr[1] + sr[2] + sr[3]);
    }
}

// ---- kE1: a = ReLU(BNvec(gap/32768 @ w1^T + b1)) ----
__global__ __launch_bounds__(256) void kE1_a(
    const float* __restrict__ gap,
    const float* __restrict__ w1, const float* __restrict__ b1,
    const float* __restrict__ g, const float* __restrict__ bb,
    const float* __restrict__ m, const float* __restrict__ vr,
    float* __restrict__ a_buf)
{
    int idx = blockIdx.x * 256 + threadIdx.x;
    int bi = idx >> 7, oc = idx & 127;
    float acc = b1[oc];
    const float* gp = gap + bi * 128;
    const float* wp = w1 + oc * 128;
    for (int c = 0; c < 128; c += 4) {
        const float4 w4 = *(const float4*)(wp + c);
        acc = fmaf(gp[c + 0] * (1.f / 32768.f), w4.x, acc);
        acc = fmaf(gp[c + 1] * (1.f / 32768.f), w4.y, acc);
        acc = fmaf(gp[c + 2] * (1.f / 32768.f), w4.z, acc);
        acc = fmaf(gp[c + 3] * (1.f / 32768.f), w4.w, acc);
    }
    float s = g[oc] * rsqrtf(vr[oc] + EPSV);
    a_buf[bi * 128 + oc] = fmaxf(fmaf(acc, s, bb[oc] - m[oc] * s), 0.f);
}

// ---- kE2: attn = softmax over radix-2 pairs ----
__global__ __launch_bounds__(256) void kE2_attn(
    const float* __restrict__ a_buf,
    const float* __restrict__ w2, const float* __restrict__ b2v,
    float* __restrict__ attn)
{
    int idx = blockIdx.x * 256 + threadIdx.x;
    int bi = idx >> 7, cc = idx & 127;
    float l0 = b2v[cc * 2], l1 = b2v[cc * 2 + 1];
    const float* ap  = a_buf + bi * 128;
    const float* w0p = w2 + (cc * 2) * 128;
    const float* w1p = w2 + (cc * 2 + 1) * 128;
    for (int j = 0; j < 128; j += 4) {
        const float4 wa4 = *(const float4*)(w0p + j);
        const float4 wb4 = *(const float4*)(w1p + j);
        l0 = fmaf(ap[j + 0], wa4.x, l0); l1 = fmaf(ap[j + 0], wb4.x, l1);
        l0 = fmaf(ap[j + 1], wa4.y, l0); l1 = fmaf(ap[j + 1], wb4.y, l1);
        l0 = fmaf(ap[j + 2], wa4.z, l0); l1 = fmaf(ap[j + 2], wb4.z, l1);
        l0 = fmaf(ap[j + 3], wa4.w, l0); l1 = fmaf(ap[j + 3], wb4.w, l1);
    }
    float mx = fmaxf(l0, l1);
    float e0 = __expf(l0 - mx), e1 = __expf(l1 - mx);
    float inv = 1.f / (e0 + e1);
    attn[bi * 256 + cc * 2]     = e0 * inv;
    attn[bi * 256 + cc * 2 + 1] = e1 * inv;
}

// ---- kF: out = attn0*agg + attn1*k2d; block = (b2, c2-pair, strip) ----
__global__ __launch_bounds__(256, 8) void kF_out(
    float* __restrict__ out, const u16* __restrict__ aggh,
    const u32* __restrict__ k2dh2, const float* __restrict__ attn)
{
    int blk   = blockIdx.x;
    int strip = blk & 3;
    int c2    = (blk >> 2) & 63;
    int b2    = blk >> 8;
    int bi    = b2 >> 3;
    int px0   = strip * 1024 + threadIdx.x * 4;

    float a0e = attn[bi * 256 + 4 * c2];
    float a1e = attn[bi * 256 + 4 * c2 + 1];
    float a0o = attn[bi * 256 + 4 * c2 + 2];
    float a1o = attn[bi * 256 + 4 * c2 + 3];

    uint4 kk = *(const uint4*)(k2dh2 + (b2 * 64 + c2) * 4096 + px0);
    uint2 g0 = *(const uint2*)(aggh + (b2 * 128 + 2 * c2) * 4096 + px0);
    uint2 g1 = *(const uint2*)(aggh + (b2 * 128 + 2 * c2 + 1) * 4096 + px0);

    float4 re, ro;
    re.x = fmaf(a0e, bflo(g0.x), a1e * bflo(kk.x));
    re.y = fmaf(a0e, bfhi(g0.x), a1e * bflo(kk.y));
    re.z = fmaf(a0e, bflo(g0.y), a1e * bflo(kk.z));
    re.w = fmaf(a0e, bfhi(g0.y), a1e * bflo(kk.w));
    ro.x = fmaf(a0o, bflo(g1.x), a1o * bfhi(kk.x));
    ro.y = fmaf(a0o, bfhi(g1.x), a1o * bfhi(kk.y));
    ro.z = fmaf(a0o, bflo(g1.y), a1o * bfhi(kk.z));
    ro.w = fmaf(a0o, bfhi(g1.y), a1o * bfhi(kk.w));
    *(float4*)(out + (b2 * 128 + 2 * c2) * 4096 + px0) = re;
    *(float4*)(out + (b2 * 128 + 2 * c2 + 1) * 4096 + px0) = ro;
}

extern "C" void kernel_launch(void* const* d_in, const int* in_sizes, int n_in,
                              void* d_out, int out_size, void* d_ws, size_t ws_size,
                              hipStream_t stream)
{
    const float* x      = (const float*)d_in[0];
    const float* w_key  = (const float*)d_in[1];
    const float* bnk_g  = (const float*)d_in[2];
    const float* bnk_b  = (const float*)d_in[3];
    const float* bnk_m  = (const float*)d_in[4];
    const float* bnk_v  = (const float*)d_in[5];
    const float* w_e1   = (const float*)d_in[6];
    const float* bne_g  = (const float*)d_in[7];
    const float* bne_b  = (const float*)d_in[8];
    const float* bne_m  = (const float*)d_in[9];
    const float* bne_v  = (const float*)d_in[10];
    const float* w_e2   = (const float*)d_in[11];
    const float* b_e2   = (const float*)d_in[12];
    const float* gn_g   = (const float*)d_in[13];
    const float* gn_b   = (const float*)d_in[14];
    const float* w_1x1  = (const float*)d_in[15];
    const float* bn1_g  = (const float*)d_in[16];
    const float* bn1_b  = (const float*)d_in[17];
    const float* bn1_m  = (const float*)d_in[18];
    const float* bn1_v  = (const float*)d_in[19];
    const float* bn2_g  = (const float*)d_in[20];
    const float* bn2_b  = (const float*)d_in[21];
    const float* bn2_m  = (const float*)d_in[22];
    const float* bn2_v  = (const float*)d_in[23];
    const float* w_se1  = (const float*)d_in[24];
    const float* b_se1  = (const float*)d_in[25];
    const float* bnse_g = (const float*)d_in[26];
    const float* bnse_b = (const float*)d_in[27];
    const float* bnse_m = (const float*)d_in[28];
    const float* bnse_v = (const float*)d_in[29];
    const float* w_se2  = (const float*)d_in[30];
    const float* b_se2  = (const float*)d_in[31];

    float* ws    = (float*)d_ws;
    u32*  xh2   = (u32*)ws;
    u32*  k2dh2 = (u32*)(ws + 8388608);
    u16*  vh    = (u16*)(ws + 16777216);
    u16*  aggh  = (u16*)(ws + 25165824);
    u16*  wdh   = (u16*)(ws + 33554432);
    u32*  wkF   = (u32*)(ws + 39845888);
    u32*  wB1   = wkF + 6144;
    u32*  wB    = wB1 + 8192;
    u32*  we22  = wB + 8192;
    float* st   = ws + 46137344;
    float* gnsum  = st;
    float* gnsq   = st + 1024;
    float* gap    = st + 2048;
    float* gnmean = st + 2560;
    float* gnrstd = st + 3584;
    float* attn   = st + 4608;
    float* a_buf  = st;            // aliases gnsum (dead after kC2)

    hipMemsetAsync(gnsum, 0, 2560 * sizeof(float), stream);

    kW_pack<<<100, 256, 0, stream>>>(w_key, w_1x1, w_e1, w_e2, wkF, wB1, wB, we22);
    kX_cvt<<<8192, 256, 0, stream>>>(x, xh2);
    kA_key<<<2048, 256, 0, stream>>>(xh2, wkF, bnk_g, bnk_b, bnk_m, bnk_v, k2dh2, gap);
    kB_val<<<1024, 256, 0, stream>>>(xh2, wB1, bn1_g, bn1_b, bn1_m, bn1_v, vh);
    kC_wd<<<1024, 256, 0, stream>>>(xh2, k2dh2, wB, bne_g, bne_b, bne_m, bne_v,
                                    we22, b_e2, wdh, gnsum, gnsq);
    kC2_gn<<<4, 256, 0, stream>>>(gnsum, gnsq, gnmean, gnrstd);
    kD_agg<<<1024, 256, 0, stream>>>(wdh, vh, gnmean, gnrstd, gn_g, gn_b,
                                     bn2_g, bn2_b, bn2_m, bn2_v, aggh, gap);
    kE1_a<<<2, 256, 0, stream>>>(gap, w_se1, b_se1, bnse_g, bnse_b, bnse_m, bnse_v, a_buf);
    kE2_attn<<<2, 256, 0, stream>>>(a_buf, w_se2, b_se2, attn);
    kF_out<<<8192, 256, 0, stream>>>((float*)d_out, aggh, k2dh2, attn);
}

// Round 15
// 169.368 us; speedup vs baseline: 4.0462x; 1.0600x over previous
//
#include <hip/hip_runtime.h>

#define EPSV 1e-5f
typedef unsigned short u16;
typedef unsigned int u32;

// Problem constants: B=4, N=8, B2=32, C=128, H=W=64, HW=4096, KS=3
// Workspace (float offsets):
//   [0,        8388608)  xh2   (u32 pair-interleaved bf16 x)
//   [8388608, 16777216)  k2dh2 (u32 pair-interleaved bf16 k2d)
//   [16777216,25165824)  vh    (u16 bf16, standard layout)
//   [25165824,33554432)  aggh  (u16 bf16, standard layout)
//   [33554432,39845888)  wdh   (u16 bf16, standard layout)
//   [39845888,39871488)  packed weights: wkF[6144] wB1[8192] wB[8192] wB2[3072]
//   stats @46137344: gnsum[1024] gnsq[1024] gap[512] gnmean[1024] gnrstd[1024] attn[1024]

typedef __attribute__((ext_vector_type(8))) __bf16 bf16x8;
typedef __attribute__((ext_vector_type(4))) float f32x4;
union ABcast { uint4 u; bf16x8 v; };

__device__ __forceinline__ u32 bfbits(float f) {   // RNE f32->bf16 bits
    u32 u = __float_as_uint(f);
    u += 0x7fff + ((u >> 16) & 1);
    return u >> 16;
}
__device__ __forceinline__ float bflo(u32 p) { return __uint_as_float(p << 16); }
__device__ __forceinline__ float bfhi(u32 p) { return __uint_as_float(p & 0xffff0000u); }

// ---- kW: pack weights (MFMA fragments) ----
__global__ __launch_bounds__(256) void kW_pack(
    const float* __restrict__ wk, const float* __restrict__ w1,
    const float* __restrict__ we1, const float* __restrict__ we2,
    u32* __restrict__ wkF, u32* __restrict__ wB1,
    u32* __restrict__ wB, u32* __restrict__ wB2)
{
    int i = blockIdx.x * 256 + threadIdx.x;
    if (i < 6144) {                       // wkF: MFMA B-frags of w_key per (grp,dk)
        int jj = i & 3;
        int ln = (i >> 2) & 63;
        int nt = (i >> 8) & 1;
        int rest = i >> 9;                // grp*3+dk
        int grp = rest / 3, dk = rest % 3;
        int n = nt * 16 + (ln & 15);
        int k = (ln >> 4) * 8 + 2 * jj;
        int o = grp * 32 + n;
        wkF[i] = bfbits(wk[o * 96 + k * 3 + dk]) |
                 (bfbits(wk[o * 96 + (k + 1) * 3 + dk]) << 16);
    } else if (i < 14336) {               // wB1: MFMA B-frags of w_1x1
        int j2 = i - 6144;
        int jj = j2 & 3;
        int ln = (j2 >> 2) & 63;
        int nt = (j2 >> 8) & 7;
        int kb = j2 >> 11;
        int n = nt * 16 + (ln & 15);
        int k = kb * 32 + (ln >> 4) * 8 + 2 * jj;
        wB1[j2] = bfbits(w1[n * 128 + k]) | (bfbits(w1[n * 128 + k + 1]) << 16);
    } else if (i < 22528) {               // wB: MFMA B-frags of w_e1
        int j2 = i - 14336;
        int jj = j2 & 3;
        int ln = (j2 >> 2) & 63;
        int nt = (j2 >> 8) & 3;
        int kb = j2 >> 10;
        int n  = nt * 16 + (ln & 15);
        int k  = kb * 32 + (ln >> 4) * 8 + 2 * jj;
        wB[j2] = bfbits(we1[n * 256 + k]) | (bfbits(we1[n * 256 + k + 1]) << 16);
    } else if (i < 25600) {               // wB2: MFMA B-frags of w_e2 (96x64)
        int j2 = i - 22528;               // ((kb*6+nt)*64+ln)*4+jj, 3072 total
        int jj = j2 & 3;
        int ln = (j2 >> 2) & 63;
        int rest = j2 >> 8;               // 0..11
        int kb = rest / 6, nt = rest % 6;
        int n = nt * 16 + (ln & 15);
        int k = kb * 32 + (ln >> 4) * 8 + 2 * jj;
        wB2[j2] = bfbits(we2[n * 64 + k]) | (bfbits(we2[n * 64 + k + 1]) << 16);
    }
}

// ---- kX: x (fp32) -> xh2 (u32 channel-pair bf16) ----
__global__ __launch_bounds__(256, 8) void kX_cvt(
    const float* __restrict__ x, u32* __restrict__ xh2)
{
    int qid = blockIdx.x * 256 + threadIdx.x;
    int px  = (qid & 1023) * 4;
    int c2g = qid >> 10;
    const float4 a = *(const float4*)(x + (c2g * 2) * 4096 + px);
    const float4 b = *(const float4*)(x + (c2g * 2 + 1) * 4096 + px);
    uint4 o;
    o.x = bfbits(a.x) | (bfbits(b.x) << 16);
    o.y = bfbits(a.y) | (bfbits(b.y) << 16);
    o.z = bfbits(a.z) | (bfbits(b.z) << 16);
    o.w = bfbits(a.w) | (bfbits(b.w) << 16);
    *(uint4*)(xh2 + c2g * 4096 + px) = o;
}

// ---- kA: key_embed via MFMA -> k2dh2 (pair-interleaved), + gap ----
__global__ __launch_bounds__(256, 4) void kA_key(
    const u32* __restrict__ xh2, const u32* __restrict__ wkF,
    const float* __restrict__ g, const float* __restrict__ bb,
    const float* __restrict__ m, const float* __restrict__ vr,
    u32* __restrict__ k2dh2, float* __restrict__ gap)
{
    int tid  = threadIdx.x;
    int lane = tid & 63;
    int q    = __builtin_amdgcn_readfirstlane(tid >> 6);   // 0..3
    int blk  = blockIdx.x;
    int tile = blk & 15;
    int grp  = (blk >> 4) & 3;
    int b2   = blk >> 6;
    int px0  = tile * 256;
    int bi = b2 >> 3, ni = b2 & 7;
    int lrow = lane & 15, lk = lane >> 4;
    const uint4* wkF4 = (const uint4*)wkF;

    f32x4 acc[4][2];
    #pragma unroll
    for (int mt = 0; mt < 4; ++mt)
        #pragma unroll
        for (int nt = 0; nt < 2; ++nt)
            acc[mt][nt] = (f32x4){0.f, 0.f, 0.f, 0.f};

    int pxA[4];
    #pragma unroll
    for (int mt = 0; mt < 4; ++mt) pxA[mt] = px0 + (4 * q + mt) * 16 + lrow;

    #pragma unroll
    for (int dk = 0; dk < 3; ++dk) {
        int nf = ni + dk - 1;
        if (nf >= 0 && nf < 8) {
            const u32* src = xh2 + ((bi * 8 + nf) * 64 + grp * 16) * 4096;
            int c2b = (lk * 4) * 4096;
            ABcast a[4];
            #pragma unroll
            for (int mt = 0; mt < 4; ++mt) {
                a[mt].u.x = src[c2b         + pxA[mt]];
                a[mt].u.y = src[c2b + 4096  + pxA[mt]];
                a[mt].u.z = src[c2b + 8192  + pxA[mt]];
                a[mt].u.w = src[c2b + 12288 + pxA[mt]];
            }
            #pragma unroll
            for (int nt = 0; nt < 2; ++nt) {
                ABcast bfr;
                bfr.u = wkF4[((grp * 3 + dk) * 2 + nt) * 64 + lane];
                #pragma unroll
                for (int mt = 0; mt < 4; ++mt)
                    acc[mt][nt] = __builtin_amdgcn_mfma_f32_16x16x32_bf16(
                        a[mt].v, bfr.v, acc[mt][nt], 0, 0, 0);
            }
        }
    }

    __shared__ float ssum[32][4];
    #pragma unroll
    for (int nt = 0; nt < 2; ++nt) {
        int ch = grp * 32 + nt * 16 + lrow;
        float s = g[ch] * rsqrtf(vr[ch] + EPSV);
        float t = bb[ch] - m[ch] * s;
        float lsum = 0.f;
        #pragma unroll
        for (int mt = 0; mt < 4; ++mt) {
            float r0 = fmaxf(fmaf(acc[mt][nt].x, s, t), 0.f);
            float r1 = fmaxf(fmaf(acc[mt][nt].y, s, t), 0.f);
            float r2 = fmaxf(fmaf(acc[mt][nt].z, s, t), 0.f);
            float r3 = fmaxf(fmaf(acc[mt][nt].w, s, t), 0.f);
            lsum += r0 + r1 + r2 + r3;
            float p0 = __shfl_xor(r0, 1, 64);
            float p1 = __shfl_xor(r1, 1, 64);
            float p2 = __shfl_xor(r2, 1, 64);
            float p3 = __shfl_xor(r3, 1, 64);
            if (!(lane & 1)) {
                int c2out = grp * 16 + nt * 8 + (lrow >> 1);
                uint4 pk;
                pk.x = bfbits(r0) | (bfbits(p0) << 16);
                pk.y = bfbits(r1) | (bfbits(p1) << 16);
                pk.z = bfbits(r2) | (bfbits(p2) << 16);
                pk.w = bfbits(r3) | (bfbits(p3) << 16);
                *(uint4*)(k2dh2 + (b2 * 64 + c2out) * 4096 +
                          px0 + (4 * q + mt) * 16 + lk * 4) = pk;
            }
        }
        lsum += __shfl_xor(lsum, 16, 64);
        lsum += __shfl_xor(lsum, 32, 64);
        if (lane < 16) ssum[nt * 16 + lrow][q] = lsum;
    }
    __syncthreads();
    if (tid < 32) {
        float* sr = ssum[tid];
        atomicAdd(&gap[bi * 128 + grp * 32 + tid], sr[0] + sr[1] + sr[2] + sr[3]);
    }
}

// ---- kB: v = BN(x @ w_1x1) via MFMA -> bf16 vh (standard layout) ----
__global__ __launch_bounds__(256, 3) void kB_val(
    const u32* __restrict__ xh2, const u32* __restrict__ wB1,
    const float* __restrict__ g, const float* __restrict__ bb,
    const float* __restrict__ m, const float* __restrict__ vr,
    u16* __restrict__ vh)
{
    int tid  = threadIdx.x;
    int lane = tid & 63;
    int q    = __builtin_amdgcn_readfirstlane(tid >> 6);   // 0..3
    int tile = blockIdx.x & 31;
    int b2   = blockIdx.x >> 5;
    int px0  = tile * 128;
    int lrow = lane & 15, lk = lane >> 4;

    const u32* xb = xh2 + b2 * 64 * 4096;
    const uint4* wB14 = (const uint4*)wB1;

    f32x4 acc[2][8];
    #pragma unroll
    for (int mt = 0; mt < 2; ++mt)
        #pragma unroll
        for (int nt = 0; nt < 8; ++nt)
            acc[mt][nt] = (f32x4){0.f, 0.f, 0.f, 0.f};

    int pxA0 = px0 + (2 * q) * 16 + lrow;
    int pxA1 = pxA0 + 16;

    #pragma unroll
    for (int kblk = 0; kblk < 4; ++kblk) {
        int c2b = (kblk * 16 + lk * 4) * 4096;
        ABcast a0, a1;
        a0.u.x = xb[c2b         + pxA0];
        a0.u.y = xb[c2b + 4096  + pxA0];
        a0.u.z = xb[c2b + 8192  + pxA0];
        a0.u.w = xb[c2b + 12288 + pxA0];
        a1.u.x = xb[c2b         + pxA1];
        a1.u.y = xb[c2b + 4096  + pxA1];
        a1.u.z = xb[c2b + 8192  + pxA1];
        a1.u.w = xb[c2b + 12288 + pxA1];
        #pragma unroll
        for (int nt = 0; nt < 8; ++nt) {
            ABcast bfr;
            bfr.u = wB14[(kblk * 8 + nt) * 64 + lane];
            acc[0][nt] = __builtin_amdgcn_mfma_f32_16x16x32_bf16(a0.v, bfr.v, acc[0][nt], 0, 0, 0);
            acc[1][nt] = __builtin_amdgcn_mfma_f32_16x16x32_bf16(a1.v, bfr.v, acc[1][nt], 0, 0, 0);
        }
    }

    #pragma unroll
    for (int nt = 0; nt < 8; ++nt) {
        int ch = nt * 16 + lrow;
        float s = g[ch] * rsqrtf(vr[ch] + EPSV);
        float t = bb[ch] - m[ch] * s;
        #pragma unroll
        for (int mt = 0; mt < 2; ++mt) {
            float r0 = fmaf(acc[mt][nt].x, s, t);
            float r1 = fmaf(acc[mt][nt].y, s, t);
            float r2 = fmaf(acc[mt][nt].z, s, t);
            float r3 = fmaf(acc[mt][nt].w, s, t);
            uint2 pk;
            pk.x = bfbits(r0) | (bfbits(r1) << 16);
            pk.y = bfbits(r2) | (bfbits(r3) << 16);
            *(uint2*)(vh + (b2 * 128 + ch) * 4096 +
                      px0 + (2 * q + mt) * 16 + lk * 4) = pk;
        }
    }
}

// ---- kC: stage1 e via MFMA; stage2 wd via MFMA; GN partials ----
// Block 256 thr = 4 waves, tile 128 px. Wave q: M-tiles 2q,2q+1.
// Stage1: x 4 N-tiles (e channels). Stage2: x 6 N-tiles (wd rows), K=64 from e_s2.
__global__ __launch_bounds__(256, 3) void kC_wd(
    const u32* __restrict__ xh2, const u32* __restrict__ k2dh2,
    const u32* __restrict__ wB,
    const float* __restrict__ eg, const float* __restrict__ eb,
    const float* __restrict__ em, const float* __restrict__ ev,
    const u32* __restrict__ wB2, const float* __restrict__ be2,
    u16* __restrict__ wdh, float* __restrict__ gnsum, float* __restrict__ gnsq)
{
    int tid  = threadIdx.x;
    int lane = tid & 63;
    int q    = __builtin_amdgcn_readfirstlane(tid >> 6);   // 0..3
    int tile = blockIdx.x & 31;
    int b2   = blockIdx.x >> 5;
    int px0  = tile * 128;
    int lrow = lane & 15;
    int lk   = lane >> 4;

    const u32* xb = xh2   + b2 * 64 * 4096;
    const u32* kb = k2dh2 + b2 * 64 * 4096;
    const uint4* wB4 = (const uint4*)wB;

    f32x4 acc[2][4];
    #pragma unroll
    for (int mt = 0; mt < 2; ++mt)
        #pragma unroll
        for (int nt = 0; nt < 4; ++nt)
            acc[mt][nt] = (f32x4){0.f, 0.f, 0.f, 0.f};

    int pxA0 = px0 + (2 * q) * 16 + lrow;
    int pxA1 = pxA0 + 16;

    #pragma unroll
    for (int kblk = 0; kblk < 8; ++kblk) {
        const u32* src = (kblk < 4) ? xb : kb;
        int c2b = (((kblk & 3) * 16) + lk * 4) * 4096;
        ABcast a0, a1;
        a0.u.x = src[c2b         + pxA0];
        a0.u.y = src[c2b + 4096  + pxA0];
        a0.u.z = src[c2b + 8192  + pxA0];
        a0.u.w = src[c2b + 12288 + pxA0];
        a1.u.x = src[c2b         + pxA1];
        a1.u.y = src[c2b + 4096  + pxA1];
        a1.u.z = src[c2b + 8192  + pxA1];
        a1.u.w = src[c2b + 12288 + pxA1];
        #pragma unroll
        for (int nt = 0; nt < 4; ++nt) {
            ABcast bfr;
            bfr.u = wB4[(kblk * 4 + nt) * 64 + lane];
            acc[0][nt] = __builtin_amdgcn_mfma_f32_16x16x32_bf16(a0.v, bfr.v, acc[0][nt], 0, 0, 0);
            acc[1][nt] = __builtin_amdgcn_mfma_f32_16x16x32_bf16(a1.v, bfr.v, acc[1][nt], 0, 0, 0);
        }
    }

    // stage1 epilogue: BN+ReLU, pack channel pairs, write e_s2[c2][px]
    __shared__ __align__(16) u32 e_s2[32][132];
    #pragma unroll
    for (int nt = 0; nt < 4; ++nt) {
        int ch = nt * 16 + lrow;
        float s = eg[ch] * rsqrtf(ev[ch] + EPSV);
        float t = eb[ch] - em[ch] * s;
        #pragma unroll
        for (int mt = 0; mt < 2; ++mt) {
            float r0 = fmaxf(fmaf(acc[mt][nt].x, s, t), 0.f);
            float r1 = fmaxf(fmaf(acc[mt][nt].y, s, t), 0.f);
            float r2 = fmaxf(fmaf(acc[mt][nt].z, s, t), 0.f);
            float r3 = fmaxf(fmaf(acc[mt][nt].w, s, t), 0.f);
            float p0 = __shfl_xor(r0, 1, 64);
            float p1 = __shfl_xor(r1, 1, 64);
            float p2 = __shfl_xor(r2, 1, 64);
            float p3 = __shfl_xor(r3, 1, 64);
            if (!(lane & 1)) {
                uint4 pk;
                pk.x = bfbits(r0) | (bfbits(p0) << 16);
                pk.y = bfbits(r1) | (bfbits(p1) << 16);
                pk.z = bfbits(r2) | (bfbits(p2) << 16);
                pk.w = bfbits(r3) | (bfbits(p3) << 16);
                *(uint4*)&e_s2[nt * 8 + (lrow >> 1)][(2 * q + mt) * 16 + lk * 4] = pk;
            }
        }
    }
    __syncthreads();

    // stage2: wd = e @ we2^T + bias via MFMA. M-tiles 2q,2q+1; 6 N-tiles; K=64.
    const uint4* wB24 = (const uint4*)wB2;
    f32x4 acc2[2][6];
    #pragma unroll
    for (int mt = 0; mt < 2; ++mt)
        #pragma unroll
        for (int nt = 0; nt < 6; ++nt)
            acc2[mt][nt] = (f32x4){0.f, 0.f, 0.f, 0.f};

    #pragma unroll
    for (int kb2 = 0; kb2 < 2; ++kb2) {
        int c2r = kb2 * 16 + lk * 4;
        ABcast a0, a1;
        int pl0 = (2 * q) * 16 + lrow;
        int pl1 = pl0 + 16;
        a0.u.x = e_s2[c2r + 0][pl0];
        a0.u.y = e_s2[c2r + 1][pl0];
        a0.u.z = e_s2[c2r + 2][pl0];
        a0.u.w = e_s2[c2r + 3][pl0];
        a1.u.x = e_s2[c2r + 0][pl1];
        a1.u.y = e_s2[c2r + 1][pl1];
        a1.u.z = e_s2[c2r + 2][pl1];
        a1.u.w = e_s2[c2r + 3][pl1];
        #pragma unroll
        for (int nt = 0; nt < 6; ++nt) {
            ABcast bfr;
            bfr.u = wB24[(kb2 * 6 + nt) * 64 + lane];
            acc2[0][nt] = __builtin_amdgcn_mfma_f32_16x16x32_bf16(a0.v, bfr.v, acc2[0][nt], 0, 0, 0);
            acc2[1][nt] = __builtin_amdgcn_mfma_f32_16x16x32_bf16(a1.v, bfr.v, acc2[1][nt], 0, 0, 0);
        }
    }

    // stage2 epilogue: bias, store wd (lane holds 4 consecutive px of one channel),
    // GN partial sums per channel -> LDS -> combine triples.
    __shared__ float s_sum[96][4], s_sq[96][4];
    #pragma unroll
    for (int nt = 0; nt < 6; ++nt) {
        int ch = nt * 16 + lrow;               // wd row 0..95
        float bias = be2[ch];
        float lsum = 0.f, lsq = 0.f;
        #pragma unroll
        for (int mt = 0; mt < 2; ++mt) {
            float v0 = acc2[mt][nt].x + bias;
            float v1 = acc2[mt][nt].y + bias;
            float v2 = acc2[mt][nt].z + bias;
            float v3 = acc2[mt][nt].w + bias;
            uint2 pk;
            pk.x = bfbits(v0) | (bfbits(v1) << 16);
            pk.y = bfbits(v2) | (bfbits(v3) << 16);
            *(uint2*)(wdh + (b2 * 96 + ch) * 4096 +
                      px0 + (2 * q + mt) * 16 + lk * 4) = pk;
            lsum += v0 + v1 + v2 + v3;
            lsq  += v0 * v0 + v1 * v1 + v2 * v2 + v3 * v3;
        }
        lsum += __shfl_xor(lsum, 16, 64);
        lsum += __shfl_xor(lsum, 32, 64);
        lsq  += __shfl_xor(lsq, 16, 64);
        lsq  += __shfl_xor(lsq, 32, 64);
        if (lane < 16) { s_sum[ch][q] = lsum; s_sq[ch][q] = lsq; }
    }
    __syncthreads();
    if (tid < 32) {
        float ss = 0.f, sq = 0.f;
        #pragma unroll
        for (int j = 0; j < 3; ++j) {
            int ch = tid * 3 + j;
            ss += s_sum[ch][0] + s_sum[ch][1] + s_sum[ch][2] + s_sum[ch][3];
            sq += s_sq[ch][0] + s_sq[ch][1] + s_sq[ch][2] + s_sq[ch][3];
        }
        atomicAdd(&gnsum[b2 * 32 + tid], ss);
        atomicAdd(&gnsq [b2 * 32 + tid], sq);
    }
}

// ---- kC2: finalize GroupNorm stats ----
__global__ __launch_bounds__(256) void kC2_gn(
    const float* __restrict__ gnsum, const float* __restrict__ gnsq,
    float* __restrict__ gnmean, float* __restrict__ gnrstd)
{
    int idx = blockIdx.x * 256 + threadIdx.x;
    const float inv = 1.f / 12288.f;
    float mu  = gnsum[idx] * inv;
    float var = fmaf(gnsq[idx], inv, -mu * mu);
    gnmean[idx] = mu;
    gnrstd[idx] = rsqrtf(fmaxf(var, 0.f) + EPSV);
}

// ---- kD: agg = SiLU(BN2(sum_k GN(wd)*unfold(v))) -> bf16 aggh, + gap ----
__global__ __launch_bounds__(256, 8) void kD_agg(
    const u16* __restrict__ wdh, const u16* __restrict__ vh,
    const float* __restrict__ gnmean, const float* __restrict__ gnrstd,
    const float* __restrict__ gng, const float* __restrict__ gnb,
    const float* __restrict__ g, const float* __restrict__ bb,
    const float* __restrict__ m, const float* __restrict__ vr,
    u16* __restrict__ aggh, float* __restrict__ gap)
{
    int blk   = blockIdx.x;
    int strip = blk & 7;
    int c1    = (blk >> 3) & 31;
    int bi    = blk >> 8;
    int px0   = strip * 512 + threadIdx.x * 2;

    float sch[4], tch[4], gl[4];
    #pragma unroll
    for (int ch = 0; ch < 4; ++ch) {
        int c = c1 * 4 + ch;
        float s = g[c] * rsqrtf(vr[c] + EPSV);
        sch[ch] = s; tch[ch] = bb[c] - m[c] * s; gl[ch] = 0.f;
    }
    float gg[3], gb[3];
    #pragma unroll
    for (int k = 0; k < 3; ++k) { gg[k] = gng[c1 * 3 + k]; gb[k] = gnb[c1 * 3 + k]; }

    float2 vreg[4][3];
    #pragma unroll
    for (int ch = 0; ch < 4; ++ch) {
        vreg[ch][0] = make_float2(0.f, 0.f);
        u32 v1u = *(const u32*)(vh + ((bi * 8 + 0) * 128 + c1 * 4 + ch) * 4096 + px0);
        u32 v2u = *(const u32*)(vh + ((bi * 8 + 1) * 128 + c1 * 4 + ch) * 4096 + px0);
        vreg[ch][1] = make_float2(bflo(v1u), bfhi(v1u));
        vreg[ch][2] = make_float2(bflo(v2u), bfhi(v2u));
    }

    for (int ni = 0; ni < 8; ++ni) {
        int b2 = bi * 8 + ni;
        float mu = gnmean[b2 * 32 + c1], rs = gnrstd[b2 * 32 + c1];
        float2 wn[3];
        #pragma unroll
        for (int k = 0; k < 3; ++k) {
            int nf = ni + k - 1;
            if (nf >= 0 && nf < 8) {
                u32 wvu = *(const u32*)(wdh + ((b2 * 96 + c1 * 3 + k) * 4096 + px0));
                wn[k].x = fmaf((bflo(wvu) - mu) * rs, gg[k], gb[k]);
                wn[k].y = fmaf((bfhi(wvu) - mu) * rs, gg[k], gb[k]);
            } else {
                wn[k] = make_float2(0.f, 0.f);
            }
        }
        #pragma unroll
        for (int ch = 0; ch < 4; ++ch) {
            float a0 = 0.f, a1 = 0.f;
            #pragma unroll
            for (int k = 0; k < 3; ++k) {
                a0 = fmaf(wn[k].x, vreg[ch][k].x, a0);
                a1 = fmaf(wn[k].y, vreg[ch][k].y, a1);
            }
            float y0 = fmaf(a0, sch[ch], tch[ch]);
            float y1 = fmaf(a1, sch[ch], tch[ch]);
            float r0 = y0 / (1.f + __expf(-y0));
            float r1 = y1 / (1.f + __expf(-y1));
            *(u32*)(aggh + (b2 * 128 + c1 * 4 + ch) * 4096 + px0) =
                bfbits(r0) | (bfbits(r1) << 16);
            gl[ch] += r0 + r1;
        }
        if (ni < 7) {
            #pragma unroll
            for (int ch = 0; ch < 4; ++ch) {
                vreg[ch][0] = vreg[ch][1];
                vreg[ch][1] = vreg[ch][2];
                if (ni + 2 < 8) {
                    u32 vu = *(const u32*)(vh + ((bi * 8 + ni + 2) * 128 + c1 * 4 + ch) * 4096 + px0);
                    vreg[ch][2] = make_float2(bflo(vu), bfhi(vu));
                }
            }
        }
    }

    __shared__ float sm[4][4];
    int lane = threadIdx.x & 63, wid = threadIdx.x >> 6;
    #pragma unroll
    for (int ch = 0; ch < 4; ++ch) {
        float s = gl[ch];
        #pragma unroll
        for (int off = 32; off; off >>= 1) s += __shfl_down(s, off, 64);
        if (lane == 0) sm[ch][wid] = s;
    }
    __syncthreads();
    if (threadIdx.x < 4) {
        float* sr = sm[threadIdx.x];
        atomicAdd(&gap[bi * 128 + c1 * 4 + threadIdx.x], sr[0] + sr[1] + sr[2] + sr[3]);
    }
}

// ---- kE1: a = ReLU(BNvec(gap/32768 @ w1^T + b1)) ----
__global__ __launch_bounds__(256) void kE1_a(
    const float* __restrict__ gap,
    const float* __restrict__ w1, const float* __restrict__ b1,
    const float* __restrict__ g, const float* __restrict__ bb,
    const float* __restrict__ m, const float* __restrict__ vr,
    float* __restrict__ a_buf)
{
    int idx = blockIdx.x * 256 + threadIdx.x;
    int bi = idx >> 7, oc = idx & 127;
    float acc = b1[oc];
    const float* gp = gap + bi * 128;
    const float* wp = w1 + oc * 128;
    for (int c = 0; c < 128; c += 4) {
        const float4 w4 = *(const float4*)(wp + c);
        acc = fmaf(gp[c + 0] * (1.f / 32768.f), w4.x, acc);
        acc = fmaf(gp[c + 1] * (1.f / 32768.f), w4.y, acc);
        acc = fmaf(gp[c + 2] * (1.f / 32768.f), w4.z, acc);
        acc = fmaf(gp[c + 3] * (1.f / 32768.f), w4.w, acc);
    }
    float s = g[oc] * rsqrtf(vr[oc] + EPSV);
    a_buf[bi * 128 + oc] = fmaxf(fmaf(acc, s, bb[oc] - m[oc] * s), 0.f);
}

// ---- kE2: attn = softmax over radix-2 pairs ----
__global__ __launch_bounds__(256) void kE2_attn(
    const float* __restrict__ a_buf,
    const float* __restrict__ w2, const float* __restrict__ b2v,
    float* __restrict__ attn)
{
    int idx = blockIdx.x * 256 + threadIdx.x;
    int bi = idx >> 7, cc = idx & 127;
    float l0 = b2v[cc * 2], l1 = b2v[cc * 2 + 1];
    const float* ap  = a_buf + bi * 128;
    const float* w0p = w2 + (cc * 2) * 128;
    const float* w1p = w2 + (cc * 2 + 1) * 128;
    for (int j = 0; j < 128; j += 4) {
        const float4 wa4 = *(const float4*)(w0p + j);
        const float4 wb4 = *(const float4*)(w1p + j);
        l0 = fmaf(ap[j + 0], wa4.x, l0); l1 = fmaf(ap[j + 0], wb4.x, l1);
        l0 = fmaf(ap[j + 1], wa4.y, l0); l1 = fmaf(ap[j + 1], wb4.y, l1);
        l0 = fmaf(ap[j + 2], wa4.z, l0); l1 = fmaf(ap[j + 2], wb4.z, l1);
        l0 = fmaf(ap[j + 3], wa4.w, l0); l1 = fmaf(ap[j + 3], wb4.w, l1);
    }
    float mx = fmaxf(l0, l1);
    float e0 = __expf(l0 - mx), e1 = __expf(l1 - mx);
    float inv = 1.f / (e0 + e1);
    attn[bi * 256 + cc * 2]     = e0 * inv;
    attn[bi * 256 + cc * 2 + 1] = e1 * inv;
}

// ---- kF: out = attn0*agg + attn1*k2d; block = (b2, c2-pair, strip) ----
__global__ __launch_bounds__(256, 8) void kF_out(
    float* __restrict__ out, const u16* __restrict__ aggh,
    const u32* __restrict__ k2dh2, const float* __restrict__ attn)
{
    int blk   = blockIdx.x;
    int strip = blk & 3;
    int c2    = (blk >> 2) & 63;
    int b2    = blk >> 8;
    int bi    = b2 >> 3;
    int px0   = strip * 1024 + threadIdx.x * 4;

    float a0e = attn[bi * 256 + 4 * c2];
    float a1e = attn[bi * 256 + 4 * c2 + 1];
    float a0o = attn[bi * 256 + 4 * c2 + 2];
    float a1o = attn[bi * 256 + 4 * c2 + 3];

    uint4 kk = *(const uint4*)(k2dh2 + (b2 * 64 + c2) * 4096 + px0);
    uint2 g0 = *(const uint2*)(aggh + (b2 * 128 + 2 * c2) * 4096 + px0);
    uint2 g1 = *(const uint2*)(aggh + (b2 * 128 + 2 * c2 + 1) * 4096 + px0);

    float4 re, ro;
    re.x = fmaf(a0e, bflo(g0.x), a1e * bflo(kk.x));
    re.y = fmaf(a0e, bfhi(g0.x), a1e * bflo(kk.y));
    re.z = fmaf(a0e, bflo(g0.y), a1e * bflo(kk.z));
    re.w = fmaf(a0e, bfhi(g0.y), a1e * bflo(kk.w));
    ro.x = fmaf(a0o, bflo(g1.x), a1o * bfhi(kk.x));
    ro.y = fmaf(a0o, bfhi(g1.x), a1o * bfhi(kk.y));
    ro.z = fmaf(a0o, bflo(g1.y), a1o * bfhi(kk.z));
    ro.w = fmaf(a0o, bfhi(g1.y), a1o * bfhi(kk.w));
    *(float4*)(out + (b2 * 128 + 2 * c2) * 4096 + px0) = re;
    *(float4*)(out + (b2 * 128 + 2 * c2 + 1) * 4096 + px0) = ro;
}

extern "C" void kernel_launch(void* const* d_in, const int* in_sizes, int n_in,
                              void* d_out, int out_size, void* d_ws, size_t ws_size,
                              hipStream_t stream)
{
    const float* x      = (const float*)d_in[0];
    const float* w_key  = (const float*)d_in[1];
    const float* bnk_g  = (const float*)d_in[2];
    const float* bnk_b  = (const float*)d_in[3];
    const float* bnk_m  = (const float*)d_in[4];
    const float* bnk_v  = (const float*)d_in[5];
    const float* w_e1   = (const float*)d_in[6];
    const float* bne_g  = (const float*)d_in[7];
    const float* bne_b  = (const float*)d_in[8];
    const float* bne_m  = (const float*)d_in[9];
    const float* bne_v  = (const float*)d_in[10];
    const float* w_e2   = (const float*)d_in[11];
    const float* b_e2   = (const float*)d_in[12];
    const float* gn_g   = (const float*)d_in[13];
    const float* gn_b   = (const float*)d_in[14];
    const float* w_1x1  = (const float*)d_in[15];
    const float* bn1_g  = (const float*)d_in[16];
    const float* bn1_b  = (const float*)d_in[17];
    const float* bn1_m  = (const float*)d_in[18];
    const float* bn1_v  = (const float*)d_in[19];
    const float* bn2_g  = (const float*)d_in[20];
    const float* bn2_b  = (const float*)d_in[21];
    const float* bn2_m  = (const float*)d_in[22];
    const float* bn2_v  = (const float*)d_in[23];
    const float* w_se1  = (const float*)d_in[24];
    const float* b_se1  = (const float*)d_in[25];
    const float* bnse_g = (const float*)d_in[26];
    const float* bnse_b = (const float*)d_in[27];
    const float* bnse_m = (const float*)d_in[28];
    const float* bnse_v = (const float*)d_in[29];
    const float* w_se2  = (const float*)d_in[30];
    const float* b_se2  = (const float*)d_in[31];

    float* ws    = (float*)d_ws;
    u32*  xh2   = (u32*)ws;
    u32*  k2dh2 = (u32*)(ws + 8388608);
    u16*  vh    = (u16*)(ws + 16777216);
    u16*  aggh  = (u16*)(ws + 25165824);
    u16*  wdh   = (u16*)(ws + 33554432);
    u32*  wkF   = (u32*)(ws + 39845888);
    u32*  wB1   = wkF + 6144;
    u32*  wB    = wB1 + 8192;
    u32*  wB2   = wB + 8192;
    float* st   = ws + 46137344;
    float* gnsum  = st;
    float* gnsq   = st + 1024;
    float* gap    = st + 2048;
    float* gnmean = st + 2560;
    float* gnrstd = st + 3584;
    float* attn   = st + 4608;
    float* a_buf  = st;            // aliases gnsum (dead after kC2)

    hipMemsetAsync(gnsum, 0, 2560 * sizeof(float), stream);

    kW_pack<<<100, 256, 0, stream>>>(w_key, w_1x1, w_e1, w_e2, wkF, wB1, wB, wB2);
    kX_cvt<<<8192, 256, 0, stream>>>(x, xh2);
    kA_key<<<2048, 256, 0, stream>>>(xh2, wkF, bnk_g, bnk_b, bnk_m, bnk_v, k2dh2, gap);
    kB_val<<<1024, 256, 0, stream>>>(xh2, wB1, bn1_g, bn1_b, bn1_m, bn1_v, vh);
    kC_wd<<<1024, 256, 0, stream>>>(xh2, k2dh2, wB, bne_g, bne_b, bne_m, bne_v,
                                    wB2, b_e2, wdh, gnsum, gnsq);
    kC2_gn<<<4, 256, 0, stream>>>(gnsum, gnsq, gnmean, gnrstd);
    kD_agg<<<1024, 256, 0, stream>>>(wdh, vh, gnmean, gnrstd, gn_g, gn_b,
                                     bn2_g, bn2_b, bn2_m, bn2_v, aggh, gap);
    kE1_a<<<2, 256, 0, stream>>>(gap, w_se1, b_se1, bnse_g, bnse_b, bnse_m, bnse_v, a_buf);
    kE2_attn<<<2, 256, 0, stream>>>(a_buf, w_se2, b_se2, attn);
    kF_out<<<8192, 256, 0, stream>>>((float*)d_out, aggh, k2dh2, attn);
}

// Round 16
// 152.185 us; speedup vs baseline: 4.5031x; 1.1129x over previous
//
#include <hip/hip_runtime.h>

#define EPSV 1e-5f
typedef unsigned short u16;
typedef unsigned int u32;

// Problem constants: B=4, N=8, B2=32, C=128, H=W=64, HW=4096, KS=3
// Workspace (float offsets):
//   [0,        8388608)  xq    (u32 quad-interleaved bf16 x: [b2][c8][px][4dw], dw j = ch pair (8c8+2j,8c8+2j+1))
//   [8388608, 16777216)  k2dh2 (u32 pair-interleaved bf16 k2d)
//   [16777216,25165824)  vh    (u16 bf16, standard layout)
//   [25165824,33554432)  aggh  (u16 bf16, standard layout)
//   [33554432,39845888)  wdh   (u16 bf16, standard layout)
//   [39845888,39871488)  packed weights: wkF[6144] wB1[8192] wB[8192] wB2[3072]
//   stats @46137344: gnsum[1024] gnsq[1024] gap[512] gnmean[1024] gnrstd[1024] attn[1024]

typedef __attribute__((ext_vector_type(8))) __bf16 bf16x8;
typedef __attribute__((ext_vector_type(4))) float f32x4;
union ABcast { uint4 u; bf16x8 v; };

__device__ __forceinline__ u32 bfbits(float f) {   // RNE f32->bf16 bits
    u32 u = __float_as_uint(f);
    u += 0x7fff + ((u >> 16) & 1);
    return u >> 16;
}
__device__ __forceinline__ float bflo(u32 p) { return __uint_as_float(p << 16); }
__device__ __forceinline__ float bfhi(u32 p) { return __uint_as_float(p & 0xffff0000u); }

// ---- kW: pack weights (MFMA fragments) ----
__global__ __launch_bounds__(256) void kW_pack(
    const float* __restrict__ wk, const float* __restrict__ w1,
    const float* __restrict__ we1, const float* __restrict__ we2,
    u32* __restrict__ wkF, u32* __restrict__ wB1,
    u32* __restrict__ wB, u32* __restrict__ wB2)
{
    int i = blockIdx.x * 256 + threadIdx.x;
    if (i < 6144) {                       // wkF: MFMA B-frags of w_key per (grp,dk)
        int jj = i & 3;
        int ln = (i >> 2) & 63;
        int nt = (i >> 8) & 1;
        int rest = i >> 9;                // grp*3+dk
        int grp = rest / 3, dk = rest % 3;
        int n = nt * 16 + (ln & 15);
        int k = (ln >> 4) * 8 + 2 * jj;
        int o = grp * 32 + n;
        wkF[i] = bfbits(wk[o * 96 + k * 3 + dk]) |
                 (bfbits(wk[o * 96 + (k + 1) * 3 + dk]) << 16);
    } else if (i < 14336) {               // wB1: MFMA B-frags of w_1x1
        int j2 = i - 6144;
        int jj = j2 & 3;
        int ln = (j2 >> 2) & 63;
        int nt = (j2 >> 8) & 7;
        int kb = j2 >> 11;
        int n = nt * 16 + (ln & 15);
        int k = kb * 32 + (ln >> 4) * 8 + 2 * jj;
        wB1[j2] = bfbits(w1[n * 128 + k]) | (bfbits(w1[n * 128 + k + 1]) << 16);
    } else if (i < 22528) {               // wB: MFMA B-frags of w_e1
        int j2 = i - 14336;
        int jj = j2 & 3;
        int ln = (j2 >> 2) & 63;
        int nt = (j2 >> 8) & 3;
        int kb = j2 >> 10;
        int n  = nt * 16 + (ln & 15);
        int k  = kb * 32 + (ln >> 4) * 8 + 2 * jj;
        wB[j2] = bfbits(we1[n * 256 + k]) | (bfbits(we1[n * 256 + k + 1]) << 16);
    } else if (i < 25600) {               // wB2: MFMA B-frags of w_e2 (96x64)
        int j2 = i - 22528;
        int jj = j2 & 3;
        int ln = (j2 >> 2) & 63;
        int rest = j2 >> 8;               // 0..11
        int kb = rest / 6, nt = rest % 6;
        int n = nt * 16 + (ln & 15);
        int k = kb * 32 + (ln >> 4) * 8 + 2 * jj;
        wB2[j2] = bfbits(we2[n * 64 + k]) | (bfbits(we2[n * 64 + k + 1]) << 16);
    }
}

// ---- kX: x (fp32) -> xq (quad-interleaved bf16 A-fragments) ----
__global__ __launch_bounds__(256, 8) void kX_cvt(
    const float* __restrict__ x, u32* __restrict__ xq)
{
    int qid = blockIdx.x * 256 + threadIdx.x;   // 2,097,152 total (32*16*4096)
    int px  = qid & 4095;
    int c8g = qid >> 12;                        // b2*16 + c8
    const float* xp = x + (c8g * 8) * 4096 + px;
    uint4 o;
    o.x = bfbits(xp[0])        | (bfbits(xp[4096])     << 16);
    o.y = bfbits(xp[2 * 4096]) | (bfbits(xp[3 * 4096]) << 16);
    o.z = bfbits(xp[4 * 4096]) | (bfbits(xp[5 * 4096]) << 16);
    o.w = bfbits(xp[6 * 4096]) | (bfbits(xp[7 * 4096]) << 16);
    *(uint4*)(xq + (c8g * 4096 + px) * 4) = o;
}

// ---- kA: key_embed via MFMA -> k2dh2 (pair-interleaved), + gap ----
__global__ __launch_bounds__(256, 4) void kA_key(
    const u32* __restrict__ xq, const u32* __restrict__ wkF,
    const float* __restrict__ g, const float* __restrict__ bb,
    const float* __restrict__ m, const float* __restrict__ vr,
    u32* __restrict__ k2dh2, float* __restrict__ gap)
{
    int tid  = threadIdx.x;
    int lane = tid & 63;
    int q    = __builtin_amdgcn_readfirstlane(tid >> 6);   // 0..3
    int blk  = blockIdx.x;
    int tile = blk & 15;
    int grp  = (blk >> 4) & 3;
    int b2   = blk >> 6;
    int px0  = tile * 256;
    int bi = b2 >> 3, ni = b2 & 7;
    int lrow = lane & 15, lk = lane >> 4;
    const uint4* wkF4 = (const uint4*)wkF;

    f32x4 acc[4][2];
    #pragma unroll
    for (int mt = 0; mt < 4; ++mt)
        #pragma unroll
        for (int nt = 0; nt < 2; ++nt)
            acc[mt][nt] = (f32x4){0.f, 0.f, 0.f, 0.f};

    int pxA[4];
    #pragma unroll
    for (int mt = 0; mt < 4; ++mt) pxA[mt] = px0 + (4 * q + mt) * 16 + lrow;

    #pragma unroll
    for (int dk = 0; dk < 3; ++dk) {
        int nf = ni + dk - 1;
        if (nf >= 0 && nf < 8) {
            const u32* src = xq + (((bi * 8 + nf) * 16 + grp * 4 + lk) * 4096) * 4;
            ABcast a[4];
            #pragma unroll
            for (int mt = 0; mt < 4; ++mt)
                a[mt].u = *(const uint4*)(src + pxA[mt] * 4);
            #pragma unroll
            for (int nt = 0; nt < 2; ++nt) {
                ABcast bfr;
                bfr.u = wkF4[((grp * 3 + dk) * 2 + nt) * 64 + lane];
                #pragma unroll
                for (int mt = 0; mt < 4; ++mt)
                    acc[mt][nt] = __builtin_amdgcn_mfma_f32_16x16x32_bf16(
                        a[mt].v, bfr.v, acc[mt][nt], 0, 0, 0);
            }
        }
    }

    __shared__ float ssum[32][4];
    #pragma unroll
    for (int nt = 0; nt < 2; ++nt) {
        int ch = grp * 32 + nt * 16 + lrow;
        float s = g[ch] * rsqrtf(vr[ch] + EPSV);
        float t = bb[ch] - m[ch] * s;
        float lsum = 0.f;
        #pragma unroll
        for (int mt = 0; mt < 4; ++mt) {
            float r0 = fmaxf(fmaf(acc[mt][nt].x, s, t), 0.f);
            float r1 = fmaxf(fmaf(acc[mt][nt].y, s, t), 0.f);
            float r2 = fmaxf(fmaf(acc[mt][nt].z, s, t), 0.f);
            float r3 = fmaxf(fmaf(acc[mt][nt].w, s, t), 0.f);
            lsum += r0 + r1 + r2 + r3;
            float p0 = __shfl_xor(r0, 1, 64);
            float p1 = __shfl_xor(r1, 1, 64);
            float p2 = __shfl_xor(r2, 1, 64);
            float p3 = __shfl_xor(r3, 1, 64);
            if (!(lane & 1)) {
                int c2out = grp * 16 + nt * 8 + (lrow >> 1);
                uint4 pk;
                pk.x = bfbits(r0) | (bfbits(p0) << 16);
                pk.y = bfbits(r1) | (bfbits(p1) << 16);
                pk.z = bfbits(r2) | (bfbits(p2) << 16);
                pk.w = bfbits(r3) | (bfbits(p3) << 16);
                *(uint4*)(k2dh2 + (b2 * 64 + c2out) * 4096 +
                          px0 + (4 * q + mt) * 16 + lk * 4) = pk;
            }
        }
        lsum += __shfl_xor(lsum, 16, 64);
        lsum += __shfl_xor(lsum, 32, 64);
        if (lane < 16) ssum[nt * 16 + lrow][q] = lsum;
    }
    __syncthreads();
    if (tid < 32) {
        float* sr = ssum[tid];
        atomicAdd(&gap[bi * 128 + grp * 32 + tid], sr[0] + sr[1] + sr[2] + sr[3]);
    }
}

// ---- kB: v = BN(x @ w_1x1) via MFMA -> bf16 vh (standard layout) ----
__global__ __launch_bounds__(256, 3) void kB_val(
    const u32* __restrict__ xq, const u32* __restrict__ wB1,
    const float* __restrict__ g, const float* __restrict__ bb,
    const float* __restrict__ m, const float* __restrict__ vr,
    u16* __restrict__ vh)
{
    int tid  = threadIdx.x;
    int lane = tid & 63;
    int q    = __builtin_amdgcn_readfirstlane(tid >> 6);   // 0..3
    int tile = blockIdx.x & 31;
    int b2   = blockIdx.x >> 5;
    int px0  = tile * 128;
    int lrow = lane & 15, lk = lane >> 4;

    const uint4* wB14 = (const uint4*)wB1;

    f32x4 acc[2][8];
    #pragma unroll
    for (int mt = 0; mt < 2; ++mt)
        #pragma unroll
        for (int nt = 0; nt < 8; ++nt)
            acc[mt][nt] = (f32x4){0.f, 0.f, 0.f, 0.f};

    int pxA0 = px0 + (2 * q) * 16 + lrow;
    int pxA1 = pxA0 + 16;

    #pragma unroll
    for (int kblk = 0; kblk < 4; ++kblk) {
        const u32* src = xq + ((b2 * 16 + kblk * 4 + lk) * 4096) * 4;
        ABcast a0, a1;
        a0.u = *(const uint4*)(src + pxA0 * 4);
        a1.u = *(const uint4*)(src + pxA1 * 4);
        #pragma unroll
        for (int nt = 0; nt < 8; ++nt) {
            ABcast bfr;
            bfr.u = wB14[(kblk * 8 + nt) * 64 + lane];
            acc[0][nt] = __builtin_amdgcn_mfma_f32_16x16x32_bf16(a0.v, bfr.v, acc[0][nt], 0, 0, 0);
            acc[1][nt] = __builtin_amdgcn_mfma_f32_16x16x32_bf16(a1.v, bfr.v, acc[1][nt], 0, 0, 0);
        }
    }

    #pragma unroll
    for (int nt = 0; nt < 8; ++nt) {
        int ch = nt * 16 + lrow;
        float s = g[ch] * rsqrtf(vr[ch] + EPSV);
        float t = bb[ch] - m[ch] * s;
        #pragma unroll
        for (int mt = 0; mt < 2; ++mt) {
            float r0 = fmaf(acc[mt][nt].x, s, t);
            float r1 = fmaf(acc[mt][nt].y, s, t);
            float r2 = fmaf(acc[mt][nt].z, s, t);
            float r3 = fmaf(acc[mt][nt].w, s, t);
            uint2 pk;
            pk.x = bfbits(r0) | (bfbits(r1) << 16);
            pk.y = bfbits(r2) | (bfbits(r3) << 16);
            *(uint2*)(vh + (b2 * 128 + ch) * 4096 +
                      px0 + (2 * q + mt) * 16 + lk * 4) = pk;
        }
    }
}

// ---- kC: stage1 e via MFMA (x from xq quads, k2d from pair layout);
//          stage2 wd via MFMA; GN partials ----
__global__ __launch_bounds__(256, 3) void kC_wd(
    const u32* __restrict__ xq, const u32* __restrict__ k2dh2,
    const u32* __restrict__ wB,
    const float* __restrict__ eg, const float* __restrict__ eb,
    const float* __restrict__ em, const float* __restrict__ ev,
    const u32* __restrict__ wB2, const float* __restrict__ be2,
    u16* __restrict__ wdh, float* __restrict__ gnsum, float* __restrict__ gnsq)
{
    int tid  = threadIdx.x;
    int lane = tid & 63;
    int q    = __builtin_amdgcn_readfirstlane(tid >> 6);   // 0..3
    int tile = blockIdx.x & 31;
    int b2   = blockIdx.x >> 5;
    int px0  = tile * 128;
    int lrow = lane & 15;
    int lk   = lane >> 4;

    const u32* kb = k2dh2 + b2 * 64 * 4096;
    const uint4* wB4 = (const uint4*)wB;

    f32x4 acc[2][4];
    #pragma unroll
    for (int mt = 0; mt < 2; ++mt)
        #pragma unroll
        for (int nt = 0; nt < 4; ++nt)
            acc[mt][nt] = (f32x4){0.f, 0.f, 0.f, 0.f};

    int pxA0 = px0 + (2 * q) * 16 + lrow;
    int pxA1 = pxA0 + 16;

    // kblk 0..3: x via quad loads
    #pragma unroll
    for (int kblk = 0; kblk < 4; ++kblk) {
        const u32* src = xq + ((b2 * 16 + kblk * 4 + lk) * 4096) * 4;
        ABcast a0, a1;
        a0.u = *(const uint4*)(src + pxA0 * 4);
        a1.u = *(const uint4*)(src + pxA1 * 4);
        #pragma unroll
        for (int nt = 0; nt < 4; ++nt) {
            ABcast bfr;
            bfr.u = wB4[(kblk * 4 + nt) * 64 + lane];
            acc[0][nt] = __builtin_amdgcn_mfma_f32_16x16x32_bf16(a0.v, bfr.v, acc[0][nt], 0, 0, 0);
            acc[1][nt] = __builtin_amdgcn_mfma_f32_16x16x32_bf16(a1.v, bfr.v, acc[1][nt], 0, 0, 0);
        }
    }
    // kblk 4..7: k2d via pair-layout dword loads
    #pragma unroll
    for (int kblk = 4; kblk < 8; ++kblk) {
        int c2b = (((kblk & 3) * 16) + lk * 4) * 4096;
        ABcast a0, a1;
        a0.u.x = kb[c2b         + pxA0];
        a0.u.y = kb[c2b + 4096  + pxA0];
        a0.u.z = kb[c2b + 8192  + pxA0];
        a0.u.w = kb[c2b + 12288 + pxA0];
        a1.u.x = kb[c2b         + pxA1];
        a1.u.y = kb[c2b + 4096  + pxA1];
        a1.u.z = kb[c2b + 8192  + pxA1];
        a1.u.w = kb[c2b + 12288 + pxA1];
        #pragma unroll
        for (int nt = 0; nt < 4; ++nt) {
            ABcast bfr;
            bfr.u = wB4[(kblk * 4 + nt) * 64 + lane];
            acc[0][nt] = __builtin_amdgcn_mfma_f32_16x16x32_bf16(a0.v, bfr.v, acc[0][nt], 0, 0, 0);
            acc[1][nt] = __builtin_amdgcn_mfma_f32_16x16x32_bf16(a1.v, bfr.v, acc[1][nt], 0, 0, 0);
        }
    }

    // stage1 epilogue: BN+ReLU, pack channel pairs, write e_s2[c2][px]
    __shared__ __align__(16) u32 e_s2[32][132];
    #pragma unroll
    for (int nt = 0; nt < 4; ++nt) {
        int ch = nt * 16 + lrow;
        float s = eg[ch] * rsqrtf(ev[ch] + EPSV);
        float t = eb[ch] - em[ch] * s;
        #pragma unroll
        for (int mt = 0; mt < 2; ++mt) {
            float r0 = fmaxf(fmaf(acc[mt][nt].x, s, t), 0.f);
            float r1 = fmaxf(fmaf(acc[mt][nt].y, s, t), 0.f);
            float r2 = fmaxf(fmaf(acc[mt][nt].z, s, t), 0.f);
            float r3 = fmaxf(fmaf(acc[mt][nt].w, s, t), 0.f);
            float p0 = __shfl_xor(r0, 1, 64);
            float p1 = __shfl_xor(r1, 1, 64);
            float p2 = __shfl_xor(r2, 1, 64);
            float p3 = __shfl_xor(r3, 1, 64);
            if (!(lane & 1)) {
                uint4 pk;
                pk.x = bfbits(r0) | (bfbits(p0) << 16);
                pk.y = bfbits(r1) | (bfbits(p1) << 16);
                pk.z = bfbits(r2) | (bfbits(p2) << 16);
                pk.w = bfbits(r3) | (bfbits(p3) << 16);
                *(uint4*)&e_s2[nt * 8 + (lrow >> 1)][(2 * q + mt) * 16 + lk * 4] = pk;
            }
        }
    }
    __syncthreads();

    // stage2: wd = e @ we2^T + bias via MFMA
    const uint4* wB24 = (const uint4*)wB2;
    f32x4 acc2[2][6];
    #pragma unroll
    for (int mt = 0; mt < 2; ++mt)
        #pragma unroll
        for (int nt = 0; nt < 6; ++nt)
            acc2[mt][nt] = (f32x4){0.f, 0.f, 0.f, 0.f};

    #pragma unroll
    for (int kb2 = 0; kb2 < 2; ++kb2) {
        int c2r = kb2 * 16 + lk * 4;
        ABcast a0, a1;
        int pl0 = (2 * q) * 16 + lrow;
        int pl1 = pl0 + 16;
        a0.u.x = e_s2[c2r + 0][pl0];
        a0.u.y = e_s2[c2r + 1][pl0];
        a0.u.z = e_s2[c2r + 2][pl0];
        a0.u.w = e_s2[c2r + 3][pl0];
        a1.u.x = e_s2[c2r + 0][pl1];
        a1.u.y = e_s2[c2r + 1][pl1];
        a1.u.z = e_s2[c2r + 2][pl1];
        a1.u.w = e_s2[c2r + 3][pl1];
        #pragma unroll
        for (int nt = 0; nt < 6; ++nt) {
            ABcast bfr;
            bfr.u = wB24[(kb2 * 6 + nt) * 64 + lane];
            acc2[0][nt] = __builtin_amdgcn_mfma_f32_16x16x32_bf16(a0.v, bfr.v, acc2[0][nt], 0, 0, 0);
            acc2[1][nt] = __builtin_amdgcn_mfma_f32_16x16x32_bf16(a1.v, bfr.v, acc2[1][nt], 0, 0, 0);
        }
    }

    __shared__ float s_sum[96][4], s_sq[96][4];
    #pragma unroll
    for (int nt = 0; nt < 6; ++nt) {
        int ch = nt * 16 + lrow;
        float bias = be2[ch];
        float lsum = 0.f, lsq = 0.f;
        #pragma unroll
        for (int mt = 0; mt < 2; ++mt) {
            float v0 = acc2[mt][nt].x + bias;
            float v1 = acc2[mt][nt].y + bias;
            float v2 = acc2[mt][nt].z + bias;
            float v3 = acc2[mt][nt].w + bias;
            uint2 pk;
            pk.x = bfbits(v0) | (bfbits(v1) << 16);
            pk.y = bfbits(v2) | (bfbits(v3) << 16);
            *(uint2*)(wdh + (b2 * 96 + ch) * 4096 +
                      px0 + (2 * q + mt) * 16 + lk * 4) = pk;
            lsum += v0 + v1 + v2 + v3;
            lsq  += v0 * v0 + v1 * v1 + v2 * v2 + v3 * v3;
        }
        lsum += __shfl_xor(lsum, 16, 64);
        lsum += __shfl_xor(lsum, 32, 64);
        lsq  += __shfl_xor(lsq, 16, 64);
        lsq  += __shfl_xor(lsq, 32, 64);
        if (lane < 16) { s_sum[ch][q] = lsum; s_sq[ch][q] = lsq; }
    }
    __syncthreads();
    if (tid < 32) {
        float ss = 0.f, sq = 0.f;
        #pragma unroll
        for (int j = 0; j < 3; ++j) {
            int ch = tid * 3 + j;
            ss += s_sum[ch][0] + s_sum[ch][1] + s_sum[ch][2] + s_sum[ch][3];
            sq += s_sq[ch][0] + s_sq[ch][1] + s_sq[ch][2] + s_sq[ch][3];
        }
        atomicAdd(&gnsum[b2 * 32 + tid], ss);
        atomicAdd(&gnsq [b2 * 32 + tid], sq);
    }
}

// ---- kC2: finalize GroupNorm stats ----
__global__ __launch_bounds__(256) void kC2_gn(
    const float* __restrict__ gnsum, const float* __restrict__ gnsq,
    float* __restrict__ gnmean, float* __restrict__ gnrstd)
{
    int idx = blockIdx.x * 256 + threadIdx.x;
    const float inv = 1.f / 12288.f;
    float mu  = gnsum[idx] * inv;
    float var = fmaf(gnsq[idx], inv, -mu * mu);
    gnmean[idx] = mu;
    gnrstd[idx] = rsqrtf(fmaxf(var, 0.f) + EPSV);
}

// ---- kD: agg = SiLU(BN2(sum_k GN(wd)*unfold(v))) -> bf16 aggh, + gap ----
__global__ __launch_bounds__(256, 8) void kD_agg(
    const u16* __restrict__ wdh, const u16* __restrict__ vh,
    const float* __restrict__ gnmean, const float* __restrict__ gnrstd,
    const float* __restrict__ gng, const float* __restrict__ gnb,
    const float* __restrict__ g, const float* __restrict__ bb,
    const float* __restrict__ m, const float* __restrict__ vr,
    u16* __restrict__ aggh, float* __restrict__ gap)
{
    int blk   = blockIdx.x;
    int strip = blk & 7;
    int c1    = (blk >> 3) & 31;
    int bi    = blk >> 8;
    int px0   = strip * 512 + threadIdx.x * 2;

    float sch[4], tch[4], gl[4];
    #pragma unroll
    for (int ch = 0; ch < 4; ++ch) {
        int c = c1 * 4 + ch;
        float s = g[c] * rsqrtf(vr[c] + EPSV);
        sch[ch] = s; tch[ch] = bb[c] - m[c] * s; gl[ch] = 0.f;
    }
    float gg[3], gb[3];
    #pragma unroll
    for (int k = 0; k < 3; ++k) { gg[k] = gng[c1 * 3 + k]; gb[k] = gnb[c1 * 3 + k]; }

    float2 vreg[4][3];
    #pragma unroll
    for (int ch = 0; ch < 4; ++ch) {
        vreg[ch][0] = make_float2(0.f, 0.f);
        u32 v1u = *(const u32*)(vh + ((bi * 8 + 0) * 128 + c1 * 4 + ch) * 4096 + px0);
        u32 v2u = *(const u32*)(vh + ((bi * 8 + 1) * 128 + c1 * 4 + ch) * 4096 + px0);
        vreg[ch][1] = make_float2(bflo(v1u), bfhi(v1u));
        vreg[ch][2] = make_float2(bflo(v2u), bfhi(v2u));
    }

    for (int ni = 0; ni < 8; ++ni) {
        int b2 = bi * 8 + ni;
        float mu = gnmean[b2 * 32 + c1], rs = gnrstd[b2 * 32 + c1];
        float2 wn[3];
        #pragma unroll
        for (int k = 0; k < 3; ++k) {
            int nf = ni + k - 1;
            if (nf >= 0 && nf < 8) {
                u32 wvu = *(const u32*)(wdh + ((b2 * 96 + c1 * 3 + k) * 4096 + px0));
                wn[k].x = fmaf((bflo(wvu) - mu) * rs, gg[k], gb[k]);
                wn[k].y = fmaf((bfhi(wvu) - mu) * rs, gg[k], gb[k]);
            } else {
                wn[k] = make_float2(0.f, 0.f);
            }
        }
        #pragma unroll
        for (int ch = 0; ch < 4; ++ch) {
            float a0 = 0.f, a1 = 0.f;
            #pragma unroll
            for (int k = 0; k < 3; ++k) {
                a0 = fmaf(wn[k].x, vreg[ch][k].x, a0);
                a1 = fmaf(wn[k].y, vreg[ch][k].y, a1);
            }
            float y0 = fmaf(a0, sch[ch], tch[ch]);
            float y1 = fmaf(a1, sch[ch], tch[ch]);
            float r0 = y0 / (1.f + __expf(-y0));
            float r1 = y1 / (1.f + __expf(-y1));
            *(u32*)(aggh + (b2 * 128 + c1 * 4 + ch) * 4096 + px0) =
                bfbits(r0) | (bfbits(r1) << 16);
            gl[ch] += r0 + r1;
        }
        if (ni < 7) {
            #pragma unroll
            for (int ch = 0; ch < 4; ++ch) {
                vreg[ch][0] = vreg[ch][1];
                vreg[ch][1] = vreg[ch][2];
                if (ni + 2 < 8) {
                    u32 vu = *(const u32*)(vh + ((bi * 8 + ni + 2) * 128 + c1 * 4 + ch) * 4096 + px0);
                    vreg[ch][2] = make_float2(bflo(vu), bfhi(vu));
                }
            }
        }
    }

    __shared__ float sm[4][4];
    int lane = threadIdx.x & 63, wid = threadIdx.x >> 6;
    #pragma unroll
    for (int ch = 0; ch < 4; ++ch) {
        float s = gl[ch];
        #pragma unroll
        for (int off = 32; off; off >>= 1) s += __shfl_down(s, off, 64);
        if (lane == 0) sm[ch][wid] = s;
    }
    __syncthreads();
    if (threadIdx.x < 4) {
        float* sr = sm[threadIdx.x];
        atomicAdd(&gap[bi * 128 + c1 * 4 + threadIdx.x], sr[0] + sr[1] + sr[2] + sr[3]);
    }
}

// ---- kE1: a = ReLU(BNvec(gap/32768 @ w1^T + b1)) ----
__global__ __launch_bounds__(256) void kE1_a(
    const float* __restrict__ gap,
    const float* __restrict__ w1, const float* __restrict__ b1,
    const float* __restrict__ g, const float* __restrict__ bb,
    const float* __restrict__ m, const float* __restrict__ vr,
    float* __restrict__ a_buf)
{
    int idx = blockIdx.x * 256 + threadIdx.x;
    int bi = idx >> 7, oc = idx & 127;
    float acc = b1[oc];
    const float* gp = gap + bi * 128;
    const float* wp = w1 + oc * 128;
    for (int c = 0; c < 128; c += 4) {
        const float4 w4 = *(const float4*)(wp + c);
        acc = fmaf(gp[c + 0] * (1.f / 32768.f), w4.x, acc);
        acc = fmaf(gp[c + 1] * (1.f / 32768.f), w4.y, acc);
        acc = fmaf(gp[c + 2] * (1.f / 32768.f), w4.z, acc);
        acc = fmaf(gp[c + 3] * (1.f / 32768.f), w4.w, acc);
    }
    float s = g[oc] * rsqrtf(vr[oc] + EPSV);
    a_buf[bi * 128 + oc] = fmaxf(fmaf(acc, s, bb[oc] - m[oc] * s), 0.f);
}

// ---- kE2: attn = softmax over radix-2 pairs ----
__global__ __launch_bounds__(256) void kE2_attn(
    const float* __restrict__ a_buf,
    const float* __restrict__ w2, const float* __restrict__ b2v,
    float* __restrict__ attn)
{
    int idx = blockIdx.x * 256 + threadIdx.x;
    int bi = idx >> 7, cc = idx & 127;
    float l0 = b2v[cc * 2], l1 = b2v[cc * 2 + 1];
    const float* ap  = a_buf + bi * 128;
    const float* w0p = w2 + (cc * 2) * 128;
    const float* w1p = w2 + (cc * 2 + 1) * 128;
    for (int j = 0; j < 128; j += 4) {
        const float4 wa4 = *(const float4*)(w0p + j);
        const float4 wb4 = *(const float4*)(w1p + j);
        l0 = fmaf(ap[j + 0], wa4.x, l0); l1 = fmaf(ap[j + 0], wb4.x, l1);
        l0 = fmaf(ap[j + 1], wa4.y, l0); l1 = fmaf(ap[j + 1], wb4.y, l1);
        l0 = fmaf(ap[j + 2], wa4.z, l0); l1 = fmaf(ap[j + 2], wb4.z, l1);
        l0 = fmaf(ap[j + 3], wa4.w, l0); l1 = fmaf(ap[j + 3], wb4.w, l1);
    }
    float mx = fmaxf(l0, l1);
    float e0 = __expf(l0 - mx), e1 = __expf(l1 - mx);
    float inv = 1.f / (e0 + e1);
    attn[bi * 256 + cc * 2]     = e0 * inv;
    attn[bi * 256 + cc * 2 + 1] = e1 * inv;
}

// ---- kF: out = attn0*agg + attn1*k2d; block = (b2, c2-pair, strip) ----
__global__ __launch_bounds__(256, 8) void kF_out(
    float* __restrict__ out, const u16* __restrict__ aggh,
    const u32* __restrict__ k2dh2, const float* __restrict__ attn)
{
    int blk   = blockIdx.x;
    int strip = blk & 3;
    int c2    = (blk >> 2) & 63;
    int b2    = blk >> 8;
    int bi    = b2 >> 3;
    int px0   = strip * 1024 + threadIdx.x * 4;

    float a0e = attn[bi * 256 + 4 * c2];
    float a1e = attn[bi * 256 + 4 * c2 + 1];
    float a0o = attn[bi * 256 + 4 * c2 + 2];
    float a1o = attn[bi * 256 + 4 * c2 + 3];

    uint4 kk = *(const uint4*)(k2dh2 + (b2 * 64 + c2) * 4096 + px0);
    uint2 g0 = *(const uint2*)(aggh + (b2 * 128 + 2 * c2) * 4096 + px0);
    uint2 g1 = *(const uint2*)(aggh + (b2 * 128 + 2 * c2 + 1) * 4096 + px0);

    float4 re, ro;
    re.x = fmaf(a0e, bflo(g0.x), a1e * bflo(kk.x));
    re.y = fmaf(a0e, bfhi(g0.x), a1e * bflo(kk.y));
    re.z = fmaf(a0e, bflo(g0.y), a1e * bflo(kk.z));
    re.w = fmaf(a0e, bfhi(g0.y), a1e * bflo(kk.w));
    ro.x = fmaf(a0o, bflo(g1.x), a1o * bfhi(kk.x));
    ro.y = fmaf(a0o, bfhi(g1.x), a1o * bfhi(kk.y));
    ro.z = fmaf(a0o, bflo(g1.y), a1o * bfhi(kk.z));
    ro.w = fmaf(a0o, bfhi(g1.y), a1o * bfhi(kk.w));
    *(float4*)(out + (b2 * 128 + 2 * c2) * 4096 + px0) = re;
    *(float4*)(out + (b2 * 128 + 2 * c2 + 1) * 4096 + px0) = ro;
}

extern "C" void kernel_launch(void* const* d_in, const int* in_sizes, int n_in,
                              void* d_out, int out_size, void* d_ws, size_t ws_size,
                              hipStream_t stream)
{
    const float* x      = (const float*)d_in[0];
    const float* w_key  = (const float*)d_in[1];
    const float* bnk_g  = (const float*)d_in[2];
    const float* bnk_b  = (const float*)d_in[3];
    const float* bnk_m  = (const float*)d_in[4];
    const float* bnk_v  = (const float*)d_in[5];
    const float* w_e1   = (const float*)d_in[6];
    const float* bne_g  = (const float*)d_in[7];
    const float* bne_b  = (const float*)d_in[8];
    const float* bne_m  = (const float*)d_in[9];
    const float* bne_v  = (const float*)d_in[10];
    const float* w_e2   = (const float*)d_in[11];
    const float* b_e2   = (const float*)d_in[12];
    const float* gn_g   = (const float*)d_in[13];
    const float* gn_b   = (const float*)d_in[14];
    const float* w_1x1  = (const float*)d_in[15];
    const float* bn1_g  = (const float*)d_in[16];
    const float* bn1_b  = (const float*)d_in[17];
    const float* bn1_m  = (const float*)d_in[18];
    const float* bn1_v  = (const float*)d_in[19];
    const float* bn2_g  = (const float*)d_in[20];
    const float* bn2_b  = (const float*)d_in[21];
    const float* bn2_m  = (const float*)d_in[22];
    const float* bn2_v  = (const float*)d_in[23];
    const float* w_se1  = (const float*)d_in[24];
    const float* b_se1  = (const float*)d_in[25];
    const float* bnse_g = (const float*)d_in[26];
    const float* bnse_b = (const float*)d_in[27];
    const float* bnse_m = (const float*)d_in[28];
    const float* bnse_v = (const float*)d_in[29];
    const float* w_se2  = (const float*)d_in[30];
    const float* b_se2  = (const float*)d_in[31];

    float* ws    = (float*)d_ws;
    u32*  xq    = (u32*)ws;
    u32*  k2dh2 = (u32*)(ws + 8388608);
    u16*  vh    = (u16*)(ws + 16777216);
    u16*  aggh  = (u16*)(ws + 25165824);
    u16*  wdh   = (u16*)(ws + 33554432);
    u32*  wkF   = (u32*)(ws + 39845888);
    u32*  wB1   = wkF + 6144;
    u32*  wB    = wB1 + 8192;
    u32*  wB2   = wB + 8192;
    float* st   = ws + 46137344;
    float* gnsum  = st;
    float* gnsq   = st + 1024;
    float* gap    = st + 2048;
    float* gnmean = st + 2560;
    float* gnrstd = st + 3584;
    float* attn   = st + 4608;
    float* a_buf  = st;            // aliases gnsum (dead after kC2)

    hipMemsetAsync(gnsum, 0, 2560 * sizeof(float), stream);

    kW_pack<<<100, 256, 0, stream>>>(w_key, w_1x1, w_e1, w_e2, wkF, wB1, wB, wB2);
    kX_cvt<<<8192, 256, 0, stream>>>(x, xq);
    kA_key<<<2048, 256, 0, stream>>>(xq, wkF, bnk_g, bnk_b, bnk_m, bnk_v, k2dh2, gap);
    kB_val<<<1024, 256, 0, stream>>>(xq, wB1, bn1_g, bn1_b, bn1_m, bn1_v, vh);
    kC_wd<<<1024, 256, 0, stream>>>(xq, k2dh2, wB, bne_g, bne_b, bne_m, bne_v,
                                    wB2, b_e2, wdh, gnsum, gnsq);
    kC2_gn<<<4, 256, 0, stream>>>(gnsum, gnsq, gnmean, gnrstd);
    kD_agg<<<1024, 256, 0, stream>>>(wdh, vh, gnmean, gnrstd, gn_g, gn_b,
                                     bn2_g, bn2_b, bn2_m, bn2_v, aggh, gap);
    kE1_a<<<2, 256, 0, stream>>>(gap, w_se1, b_se1, bnse_g, bnse_b, bnse_m, bnse_v, a_buf);
    kE2_attn<<<2, 256, 0, stream>>>(a_buf, w_se2, b_se2, attn);
    kF_out<<<8192, 256, 0, stream>>>((float*)d_out, aggh, k2dh2, attn);
}

// Round 17
// 150.931 us; speedup vs baseline: 4.5405x; 1.0083x over previous
//
#include <hip/hip_runtime.h>

#define EPSV 1e-5f
typedef unsigned short u16;
typedef unsigned int u32;

// Problem constants: B=4, N=8, B2=32, C=128, H=W=64, HW=4096, KS=3
// Workspace (float offsets):
//   [0,        8388608)  xq    (u32 quad-interleaved bf16 x: [b2][c8][px][4dw])
//   [8388608, 16777216)  k2dh2 (u32 pair-interleaved bf16 k2d)
//   [16777216,25165824)  vh    (u16 bf16, standard layout)
//   [25165824,33554432)  aggh  (u16 bf16, standard layout)
//   [33554432,39845888)  wdh   (u16 bf16, standard layout)
//   [39845888,39871488)  packed weights: wkF[6144] wB1[8192] wB[8192] wB2[3072]
//   stats @46137344: gnsum[1024] gnsq[1024] gap[512] gnmean[1024] gnrstd[1024] attn[1024]

typedef __attribute__((ext_vector_type(8))) __bf16 bf16x8;
typedef __attribute__((ext_vector_type(4))) float f32x4;
union ABcast { uint4 u; bf16x8 v; };

__device__ __forceinline__ u32 bfbits(float f) {   // RNE f32->bf16 bits
    u32 u = __float_as_uint(f);
    u += 0x7fff + ((u >> 16) & 1);
    return u >> 16;
}
__device__ __forceinline__ float bflo(u32 p) { return __uint_as_float(p << 16); }
__device__ __forceinline__ float bfhi(u32 p) { return __uint_as_float(p & 0xffff0000u); }

// ---- kW: pack weights (MFMA fragments) + zero the stats accumulators ----
__global__ __launch_bounds__(256) void kW_pack(
    const float* __restrict__ wk, const float* __restrict__ w1,
    const float* __restrict__ we1, const float* __restrict__ we2,
    u32* __restrict__ wkF, u32* __restrict__ wB1,
    u32* __restrict__ wB, u32* __restrict__ wB2,
    float* __restrict__ stats_zero)
{
    int i = blockIdx.x * 256 + threadIdx.x;
    if (i < 2560) stats_zero[i] = 0.f;    // gnsum[1024] gnsq[1024] gap[512]
    if (i < 6144) {                       // wkF: MFMA B-frags of w_key per (grp,dk)
        int jj = i & 3;
        int ln = (i >> 2) & 63;
        int nt = (i >> 8) & 1;
        int rest = i >> 9;                // grp*3+dk
        int grp = rest / 3, dk = rest % 3;
        int n = nt * 16 + (ln & 15);
        int k = (ln >> 4) * 8 + 2 * jj;
        int o = grp * 32 + n;
        wkF[i] = bfbits(wk[o * 96 + k * 3 + dk]) |
                 (bfbits(wk[o * 96 + (k + 1) * 3 + dk]) << 16);
    } else if (i < 14336) {               // wB1: MFMA B-frags of w_1x1
        int j2 = i - 6144;
        int jj = j2 & 3;
        int ln = (j2 >> 2) & 63;
        int nt = (j2 >> 8) & 7;
        int kb = j2 >> 11;
        int n = nt * 16 + (ln & 15);
        int k = kb * 32 + (ln >> 4) * 8 + 2 * jj;
        wB1[j2] = bfbits(w1[n * 128 + k]) | (bfbits(w1[n * 128 + k + 1]) << 16);
    } else if (i < 22528) {               // wB: MFMA B-frags of w_e1
        int j2 = i - 14336;
        int jj = j2 & 3;
        int ln = (j2 >> 2) & 63;
        int nt = (j2 >> 8) & 3;
        int kb = j2 >> 10;
        int n  = nt * 16 + (ln & 15);
        int k  = kb * 32 + (ln >> 4) * 8 + 2 * jj;
        wB[j2] = bfbits(we1[n * 256 + k]) | (bfbits(we1[n * 256 + k + 1]) << 16);
    } else if (i < 25600) {               // wB2: MFMA B-frags of w_e2 (96x64)
        int j2 = i - 22528;
        int jj = j2 & 3;
        int ln = (j2 >> 2) & 63;
        int rest = j2 >> 8;               // 0..11
        int kb = rest / 6, nt = rest % 6;
        int n = nt * 16 + (ln & 15);
        int k = kb * 32 + (ln >> 4) * 8 + 2 * jj;
        wB2[j2] = bfbits(we2[n * 64 + k]) | (bfbits(we2[n * 64 + k + 1]) << 16);
    }
}

// ---- kX: x (fp32) -> xq (quad-interleaved bf16 A-fragments) ----
__global__ __launch_bounds__(256, 8) void kX_cvt(
    const float* __restrict__ x, u32* __restrict__ xq)
{
    int qid = blockIdx.x * 256 + threadIdx.x;   // 2,097,152 total (32*16*4096)
    int px  = qid & 4095;
    int c8g = qid >> 12;                        // b2*16 + c8
    const float* xp = x + (c8g * 8) * 4096 + px;
    uint4 o;
    o.x = bfbits(xp[0])        | (bfbits(xp[4096])     << 16);
    o.y = bfbits(xp[2 * 4096]) | (bfbits(xp[3 * 4096]) << 16);
    o.z = bfbits(xp[4 * 4096]) | (bfbits(xp[5 * 4096]) << 16);
    o.w = bfbits(xp[6 * 4096]) | (bfbits(xp[7 * 4096]) << 16);
    *(uint4*)(xq + (c8g * 4096 + px) * 4) = o;
}

// ---- kA: key_embed via MFMA -> k2dh2 (pair-interleaved), + gap ----
__global__ __launch_bounds__(256, 4) void kA_key(
    const u32* __restrict__ xq, const u32* __restrict__ wkF,
    const float* __restrict__ g, const float* __restrict__ bb,
    const float* __restrict__ m, const float* __restrict__ vr,
    u32* __restrict__ k2dh2, float* __restrict__ gap)
{
    int tid  = threadIdx.x;
    int lane = tid & 63;
    int q    = __builtin_amdgcn_readfirstlane(tid >> 6);   // 0..3
    int blk  = blockIdx.x;
    int tile = blk & 15;
    int grp  = (blk >> 4) & 3;
    int b2   = blk >> 6;
    int px0  = tile * 256;
    int bi = b2 >> 3, ni = b2 & 7;
    int lrow = lane & 15, lk = lane >> 4;
    const uint4* wkF4 = (const uint4*)wkF;

    f32x4 acc[4][2];
    #pragma unroll
    for (int mt = 0; mt < 4; ++mt)
        #pragma unroll
        for (int nt = 0; nt < 2; ++nt)
            acc[mt][nt] = (f32x4){0.f, 0.f, 0.f, 0.f};

    int pxA[4];
    #pragma unroll
    for (int mt = 0; mt < 4; ++mt) pxA[mt] = px0 + (4 * q + mt) * 16 + lrow;

    #pragma unroll
    for (int dk = 0; dk < 3; ++dk) {
        int nf = ni + dk - 1;
        if (nf >= 0 && nf < 8) {
            const u32* src = xq + (((bi * 8 + nf) * 16 + grp * 4 + lk) * 4096) * 4;
            ABcast a[4];
            #pragma unroll
            for (int mt = 0; mt < 4; ++mt)
                a[mt].u = *(const uint4*)(src + pxA[mt] * 4);
            #pragma unroll
            for (int nt = 0; nt < 2; ++nt) {
                ABcast bfr;
                bfr.u = wkF4[((grp * 3 + dk) * 2 + nt) * 64 + lane];
                #pragma unroll
                for (int mt = 0; mt < 4; ++mt)
                    acc[mt][nt] = __builtin_amdgcn_mfma_f32_16x16x32_bf16(
                        a[mt].v, bfr.v, acc[mt][nt], 0, 0, 0);
            }
        }
    }

    __shared__ float ssum[32][4];
    #pragma unroll
    for (int nt = 0; nt < 2; ++nt) {
        int ch = grp * 32 + nt * 16 + lrow;
        float s = g[ch] * rsqrtf(vr[ch] + EPSV);
        float t = bb[ch] - m[ch] * s;
        float lsum = 0.f;
        #pragma unroll
        for (int mt = 0; mt < 4; ++mt) {
            float r0 = fmaxf(fmaf(acc[mt][nt].x, s, t), 0.f);
            float r1 = fmaxf(fmaf(acc[mt][nt].y, s, t), 0.f);
            float r2 = fmaxf(fmaf(acc[mt][nt].z, s, t), 0.f);
            float r3 = fmaxf(fmaf(acc[mt][nt].w, s, t), 0.f);
            lsum += r0 + r1 + r2 + r3;
            float p0 = __shfl_xor(r0, 1, 64);
            float p1 = __shfl_xor(r1, 1, 64);
            float p2 = __shfl_xor(r2, 1, 64);
            float p3 = __shfl_xor(r3, 1, 64);
            if (!(lane & 1)) {
                int c2out = grp * 16 + nt * 8 + (lrow >> 1);
                uint4 pk;
                pk.x = bfbits(r0) | (bfbits(p0) << 16);
                pk.y = bfbits(r1) | (bfbits(p1) << 16);
                pk.z = bfbits(r2) | (bfbits(p2) << 16);
                pk.w = bfbits(r3) | (bfbits(p3) << 16);
                *(uint4*)(k2dh2 + (b2 * 64 + c2out) * 4096 +
                          px0 + (4 * q + mt) * 16 + lk * 4) = pk;
            }
        }
        lsum += __shfl_xor(lsum, 16, 64);
        lsum += __shfl_xor(lsum, 32, 64);
        if (lane < 16) ssum[nt * 16 + lrow][q] = lsum;
    }
    __syncthreads();
    if (tid < 32) {
        float* sr = ssum[tid];
        atomicAdd(&gap[bi * 128 + grp * 32 + tid], sr[0] + sr[1] + sr[2] + sr[3]);
    }
}

// ---- kB: v = BN(x @ w_1x1) via MFMA -> bf16 vh (standard layout) ----
__global__ __launch_bounds__(256, 3) void kB_val(
    const u32* __restrict__ xq, const u32* __restrict__ wB1,
    const float* __restrict__ g, const float* __restrict__ bb,
    const float* __restrict__ m, const float* __restrict__ vr,
    u16* __restrict__ vh)
{
    int tid  = threadIdx.x;
    int lane = tid & 63;
    int q    = __builtin_amdgcn_readfirstlane(tid >> 6);   // 0..3
    int tile = blockIdx.x & 31;
    int b2   = blockIdx.x >> 5;
    int px0  = tile * 128;
    int lrow = lane & 15, lk = lane >> 4;

    const uint4* wB14 = (const uint4*)wB1;

    f32x4 acc[2][8];
    #pragma unroll
    for (int mt = 0; mt < 2; ++mt)
        #pragma unroll
        for (int nt = 0; nt < 8; ++nt)
            acc[mt][nt] = (f32x4){0.f, 0.f, 0.f, 0.f};

    int pxA0 = px0 + (2 * q) * 16 + lrow;
    int pxA1 = pxA0 + 16;

    #pragma unroll
    for (int kblk = 0; kblk < 4; ++kblk) {
        const u32* src = xq + ((b2 * 16 + kblk * 4 + lk) * 4096) * 4;
        ABcast a0, a1;
        a0.u = *(const uint4*)(src + pxA0 * 4);
        a1.u = *(const uint4*)(src + pxA1 * 4);
        #pragma unroll
        for (int nt = 0; nt < 8; ++nt) {
            ABcast bfr;
            bfr.u = wB14[(kblk * 8 + nt) * 64 + lane];
            acc[0][nt] = __builtin_amdgcn_mfma_f32_16x16x32_bf16(a0.v, bfr.v, acc[0][nt], 0, 0, 0);
            acc[1][nt] = __builtin_amdgcn_mfma_f32_16x16x32_bf16(a1.v, bfr.v, acc[1][nt], 0, 0, 0);
        }
    }

    #pragma unroll
    for (int nt = 0; nt < 8; ++nt) {
        int ch = nt * 16 + lrow;
        float s = g[ch] * rsqrtf(vr[ch] + EPSV);
        float t = bb[ch] - m[ch] * s;
        #pragma unroll
        for (int mt = 0; mt < 2; ++mt) {
            float r0 = fmaf(acc[mt][nt].x, s, t);
            float r1 = fmaf(acc[mt][nt].y, s, t);
            float r2 = fmaf(acc[mt][nt].z, s, t);
            float r3 = fmaf(acc[mt][nt].w, s, t);
            uint2 pk;
            pk.x = bfbits(r0) | (bfbits(r1) << 16);
            pk.y = bfbits(r2) | (bfbits(r3) << 16);
            *(uint2*)(vh + (b2 * 128 + ch) * 4096 +
                      px0 + (2 * q + mt) * 16 + lk * 4) = pk;
        }
    }
}

// ---- kC: stage1 e via MFMA; stage2 wd via MFMA; GN partials ----
__global__ __launch_bounds__(256, 3) void kC_wd(
    const u32* __restrict__ xq, const u32* __restrict__ k2dh2,
    const u32* __restrict__ wB,
    const float* __restrict__ eg, const float* __restrict__ eb,
    const float* __restrict__ em, const float* __restrict__ ev,
    const u32* __restrict__ wB2, const float* __restrict__ be2,
    u16* __restrict__ wdh, float* __restrict__ gnsum, float* __restrict__ gnsq)
{
    int tid  = threadIdx.x;
    int lane = tid & 63;
    int q    = __builtin_amdgcn_readfirstlane(tid >> 6);   // 0..3
    int tile = blockIdx.x & 31;
    int b2   = blockIdx.x >> 5;
    int px0  = tile * 128;
    int lrow = lane & 15;
    int lk   = lane >> 4;

    const u32* kb = k2dh2 + b2 * 64 * 4096;
    const uint4* wB4 = (const uint4*)wB;

    f32x4 acc[2][4];
    #pragma unroll
    for (int mt = 0; mt < 2; ++mt)
        #pragma unroll
        for (int nt = 0; nt < 4; ++nt)
            acc[mt][nt] = (f32x4){0.f, 0.f, 0.f, 0.f};

    int pxA0 = px0 + (2 * q) * 16 + lrow;
    int pxA1 = pxA0 + 16;

    #pragma unroll
    for (int kblk = 0; kblk < 4; ++kblk) {
        const u32* src = xq + ((b2 * 16 + kblk * 4 + lk) * 4096) * 4;
        ABcast a0, a1;
        a0.u = *(const uint4*)(src + pxA0 * 4);
        a1.u = *(const uint4*)(src + pxA1 * 4);
        #pragma unroll
        for (int nt = 0; nt < 4; ++nt) {
            ABcast bfr;
            bfr.u = wB4[(kblk * 4 + nt) * 64 + lane];
            acc[0][nt] = __builtin_amdgcn_mfma_f32_16x16x32_bf16(a0.v, bfr.v, acc[0][nt], 0, 0, 0);
            acc[1][nt] = __builtin_amdgcn_mfma_f32_16x16x32_bf16(a1.v, bfr.v, acc[1][nt], 0, 0, 0);
        }
    }
    #pragma unroll
    for (int kblk = 4; kblk < 8; ++kblk) {
        int c2b = (((kblk & 3) * 16) + lk * 4) * 4096;
        ABcast a0, a1;
        a0.u.x = kb[c2b         + pxA0];
        a0.u.y = kb[c2b + 4096  + pxA0];
        a0.u.z = kb[c2b + 8192  + pxA0];
        a0.u.w = kb[c2b + 12288 + pxA0];
        a1.u.x = kb[c2b         + pxA1];
        a1.u.y = kb[c2b + 4096  + pxA1];
        a1.u.z = kb[c2b + 8192  + pxA1];
        a1.u.w = kb[c2b + 12288 + pxA1];
        #pragma unroll
        for (int nt = 0; nt < 4; ++nt) {
            ABcast bfr;
            bfr.u = wB4[(kblk * 4 + nt) * 64 + lane];
            acc[0][nt] = __builtin_amdgcn_mfma_f32_16x16x32_bf16(a0.v, bfr.v, acc[0][nt], 0, 0, 0);
            acc[1][nt] = __builtin_amdgcn_mfma_f32_16x16x32_bf16(a1.v, bfr.v, acc[1][nt], 0, 0, 0);
        }
    }

    __shared__ __align__(16) u32 e_s2[32][132];
    #pragma unroll
    for (int nt = 0; nt < 4; ++nt) {
        int ch = nt * 16 + lrow;
        float s = eg[ch] * rsqrtf(ev[ch] + EPSV);
        float t = eb[ch] - em[ch] * s;
        #pragma unroll
        for (int mt = 0; mt < 2; ++mt) {
            float r0 = fmaxf(fmaf(acc[mt][nt].x, s, t), 0.f);
            float r1 = fmaxf(fmaf(acc[mt][nt].y, s, t), 0.f);
            float r2 = fmaxf(fmaf(acc[mt][nt].z, s, t), 0.f);
            float r3 = fmaxf(fmaf(acc[mt][nt].w, s, t), 0.f);
            float p0 = __shfl_xor(r0, 1, 64);
            float p1 = __shfl_xor(r1, 1, 64);
            float p2 = __shfl_xor(r2, 1, 64);
            float p3 = __shfl_xor(r3, 1, 64);
            if (!(lane & 1)) {
                uint4 pk;
                pk.x = bfbits(r0) | (bfbits(p0) << 16);
                pk.y = bfbits(r1) | (bfbits(p1) << 16);
                pk.z = bfbits(r2) | (bfbits(p2) << 16);
                pk.w = bfbits(r3) | (bfbits(p3) << 16);
                *(uint4*)&e_s2[nt * 8 + (lrow >> 1)][(2 * q + mt) * 16 + lk * 4] = pk;
            }
        }
    }
    __syncthreads();

    const uint4* wB24 = (const uint4*)wB2;
    f32x4 acc2[2][6];
    #pragma unroll
    for (int mt = 0; mt < 2; ++mt)
        #pragma unroll
        for (int nt = 0; nt < 6; ++nt)
            acc2[mt][nt] = (f32x4){0.f, 0.f, 0.f, 0.f};

    #pragma unroll
    for (int kb2 = 0; kb2 < 2; ++kb2) {
        int c2r = kb2 * 16 + lk * 4;
        ABcast a0, a1;
        int pl0 = (2 * q) * 16 + lrow;
        int pl1 = pl0 + 16;
        a0.u.x = e_s2[c2r + 0][pl0];
        a0.u.y = e_s2[c2r + 1][pl0];
        a0.u.z = e_s2[c2r + 2][pl0];
        a0.u.w = e_s2[c2r + 3][pl0];
        a1.u.x = e_s2[c2r + 0][pl1];
        a1.u.y = e_s2[c2r + 1][pl1];
        a1.u.z = e_s2[c2r + 2][pl1];
        a1.u.w = e_s2[c2r + 3][pl1];
        #pragma unroll
        for (int nt = 0; nt < 6; ++nt) {
            ABcast bfr;
            bfr.u = wB24[(kb2 * 6 + nt) * 64 + lane];
            acc2[0][nt] = __builtin_amdgcn_mfma_f32_16x16x32_bf16(a0.v, bfr.v, acc2[0][nt], 0, 0, 0);
            acc2[1][nt] = __builtin_amdgcn_mfma_f32_16x16x32_bf16(a1.v, bfr.v, acc2[1][nt], 0, 0, 0);
        }
    }

    __shared__ float s_sum[96][4], s_sq[96][4];
    #pragma unroll
    for (int nt = 0; nt < 6; ++nt) {
        int ch = nt * 16 + lrow;
        float bias = be2[ch];
        float lsum = 0.f, lsq = 0.f;
        #pragma unroll
        for (int mt = 0; mt < 2; ++mt) {
            float v0 = acc2[mt][nt].x + bias;
            float v1 = acc2[mt][nt].y + bias;
            float v2 = acc2[mt][nt].z + bias;
            float v3 = acc2[mt][nt].w + bias;
            uint2 pk;
            pk.x = bfbits(v0) | (bfbits(v1) << 16);
            pk.y = bfbits(v2) | (bfbits(v3) << 16);
            *(uint2*)(wdh + (b2 * 96 + ch) * 4096 +
                      px0 + (2 * q + mt) * 16 + lk * 4) = pk;
            lsum += v0 + v1 + v2 + v3;
            lsq  += v0 * v0 + v1 * v1 + v2 * v2 + v3 * v3;
        }
        lsum += __shfl_xor(lsum, 16, 64);
        lsum += __shfl_xor(lsum, 32, 64);
        lsq  += __shfl_xor(lsq, 16, 64);
        lsq  += __shfl_xor(lsq, 32, 64);
        if (lane < 16) { s_sum[ch][q] = lsum; s_sq[ch][q] = lsq; }
    }
    __syncthreads();
    if (tid < 32) {
        float ss = 0.f, sq = 0.f;
        #pragma unroll
        for (int j = 0; j < 3; ++j) {
            int ch = tid * 3 + j;
            ss += s_sum[ch][0] + s_sum[ch][1] + s_sum[ch][2] + s_sum[ch][3];
            sq += s_sq[ch][0] + s_sq[ch][1] + s_sq[ch][2] + s_sq[ch][3];
        }
        atomicAdd(&gnsum[b2 * 32 + tid], ss);
        atomicAdd(&gnsq [b2 * 32 + tid], sq);
    }
}

// ---- kC2: finalize GroupNorm stats ----
__global__ __launch_bounds__(256) void kC2_gn(
    const float* __restrict__ gnsum, const float* __restrict__ gnsq,
    float* __restrict__ gnmean, float* __restrict__ gnrstd)
{
    int idx = blockIdx.x * 256 + threadIdx.x;
    const float inv = 1.f / 12288.f;
    float mu  = gnsum[idx] * inv;
    float var = fmaf(gnsq[idx], inv, -mu * mu);
    gnmean[idx] = mu;
    gnrstd[idx] = rsqrtf(fmaxf(var, 0.f) + EPSV);
}

// ---- kD: agg = SiLU(BN2(sum_k GN(wd)*unfold(v))) -> bf16 aggh, + gap ----
__global__ __launch_bounds__(256, 8) void kD_agg(
    const u16* __restrict__ wdh, const u16* __restrict__ vh,
    const float* __restrict__ gnmean, const float* __restrict__ gnrstd,
    const float* __restrict__ gng, const float* __restrict__ gnb,
    const float* __restrict__ g, const float* __restrict__ bb,
    const float* __restrict__ m, const float* __restrict__ vr,
    u16* __restrict__ aggh, float* __restrict__ gap)
{
    int blk   = blockIdx.x;
    int strip = blk & 7;
    int c1    = (blk >> 3) & 31;
    int bi    = blk >> 8;
    int px0   = strip * 512 + threadIdx.x * 2;

    float sch[4], tch[4], gl[4];
    #pragma unroll
    for (int ch = 0; ch < 4; ++ch) {
        int c = c1 * 4 + ch;
        float s = g[c] * rsqrtf(vr[c] + EPSV);
        sch[ch] = s; tch[ch] = bb[c] - m[c] * s; gl[ch] = 0.f;
    }
    float gg[3], gb[3];
    #pragma unroll
    for (int k = 0; k < 3; ++k) { gg[k] = gng[c1 * 3 + k]; gb[k] = gnb[c1 * 3 + k]; }

    float2 vreg[4][3];
    #pragma unroll
    for (int ch = 0; ch < 4; ++ch) {
        vreg[ch][0] = make_float2(0.f, 0.f);
        u32 v1u = *(const u32*)(vh + ((bi * 8 + 0) * 128 + c1 * 4 + ch) * 4096 + px0);
        u32 v2u = *(const u32*)(vh + ((bi * 8 + 1) * 128 + c1 * 4 + ch) * 4096 + px0);
        vreg[ch][1] = make_float2(bflo(v1u), bfhi(v1u));
        vreg[ch][2] = make_float2(bflo(v2u), bfhi(v2u));
    }

    for (int ni = 0; ni < 8; ++ni) {
        int b2 = bi * 8 + ni;
        float mu = gnmean[b2 * 32 + c1], rs = gnrstd[b2 * 32 + c1];
        float2 wn[3];
        #pragma unroll
        for (int k = 0; k < 3; ++k) {
            int nf = ni + k - 1;
            if (nf >= 0 && nf < 8) {
                u32 wvu = *(const u32*)(wdh + ((b2 * 96 + c1 * 3 + k) * 4096 + px0));
                wn[k].x = fmaf((bflo(wvu) - mu) * rs, gg[k], gb[k]);
                wn[k].y = fmaf((bfhi(wvu) - mu) * rs, gg[k], gb[k]);
            } else {
                wn[k] = make_float2(0.f, 0.f);
            }
        }
        #pragma unroll
        for (int ch = 0; ch < 4; ++ch) {
            float a0 = 0.f, a1 = 0.f;
            #pragma unroll
            for (int k = 0; k < 3; ++k) {
                a0 = fmaf(wn[k].x, vreg[ch][k].x, a0);
                a1 = fmaf(wn[k].y, vreg[ch][k].y, a1);
            }
            float y0 = fmaf(a0, sch[ch], tch[ch]);
            float y1 = fmaf(a1, sch[ch], tch[ch]);
            float r0 = y0 / (1.f + __expf(-y0));
            float r1 = y1 / (1.f + __expf(-y1));
            *(u32*)(aggh + (b2 * 128 + c1 * 4 + ch) * 4096 + px0) =
                bfbits(r0) | (bfbits(r1) << 16);
            gl[ch] += r0 + r1;
        }
        if (ni < 7) {
            #pragma unroll
            for (int ch = 0; ch < 4; ++ch) {
                vreg[ch][0] = vreg[ch][1];
                vreg[ch][1] = vreg[ch][2];
                if (ni + 2 < 8) {
                    u32 vu = *(const u32*)(vh + ((bi * 8 + ni + 2) * 128 + c1 * 4 + ch) * 4096 + px0);
                    vreg[ch][2] = make_float2(bflo(vu), bfhi(vu));
                }
            }
        }
    }

    __shared__ float sm[4][4];
    int lane = threadIdx.x & 63, wid = threadIdx.x >> 6;
    #pragma unroll
    for (int ch = 0; ch < 4; ++ch) {
        float s = gl[ch];
        #pragma unroll
        for (int off = 32; off; off >>= 1) s += __shfl_down(s, off, 64);
        if (lane == 0) sm[ch][wid] = s;
    }
    __syncthreads();
    if (threadIdx.x < 4) {
        float* sr = sm[threadIdx.x];
        atomicAdd(&gap[bi * 128 + c1 * 4 + threadIdx.x], sr[0] + sr[1] + sr[2] + sr[3]);
    }
}

// ---- kE1: a = ReLU(BNvec(gap/32768 @ w1^T + b1)) ----
__global__ __launch_bounds__(256) void kE1_a(
    const float* __restrict__ gap,
    const float* __restrict__ w1, const float* __restrict__ b1,
    const float* __restrict__ g, const float* __restrict__ bb,
    const float* __restrict__ m, const float* __restrict__ vr,
    float* __restrict__ a_buf)
{
    int idx = blockIdx.x * 256 + threadIdx.x;
    int bi = idx >> 7, oc = idx & 127;
    float acc = b1[oc];
    const float* gp = gap + bi * 128;
    const float* wp = w1 + oc * 128;
    for (int c = 0; c < 128; c += 4) {
        const float4 w4 = *(const float4*)(wp + c);
        acc = fmaf(gp[c + 0] * (1.f / 32768.f), w4.x, acc);
        acc = fmaf(gp[c + 1] * (1.f / 32768.f), w4.y, acc);
        acc = fmaf(gp[c + 2] * (1.f / 32768.f), w4.z, acc);
        acc = fmaf(gp[c + 3] * (1.f / 32768.f), w4.w, acc);
    }
    float s = g[oc] * rsqrtf(vr[oc] + EPSV);
    a_buf[bi * 128 + oc] = fmaxf(fmaf(acc, s, bb[oc] - m[oc] * s), 0.f);
}

// ---- kE2: attn = softmax over radix-2 pairs ----
__global__ __launch_bounds__(256) void kE2_attn(
    const float* __restrict__ a_buf,
    const float* __restrict__ w2, const float* __restrict__ b2v,
    float* __restrict__ attn)
{
    int idx = blockIdx.x * 256 + threadIdx.x;
    int bi = idx >> 7, cc = idx & 127;
    float l0 = b2v[cc * 2], l1 = b2v[cc * 2 + 1];
    const float* ap  = a_buf + bi * 128;
    const float* w0p = w2 + (cc * 2) * 128;
    const float* w1p = w2 + (cc * 2 + 1) * 128;
    for (int j = 0; j < 128; j += 4) {
        const float4 wa4 = *(const float4*)(w0p + j);
        const float4 wb4 = *(const float4*)(w1p + j);
        l0 = fmaf(ap[j + 0], wa4.x, l0); l1 = fmaf(ap[j + 0], wb4.x, l1);
        l0 = fmaf(ap[j + 1], wa4.y, l0); l1 = fmaf(ap[j + 1], wb4.y, l1);
        l0 = fmaf(ap[j + 2], wa4.z, l0); l1 = fmaf(ap[j + 2], wb4.z, l1);
        l0 = fmaf(ap[j + 3], wa4.w, l0); l1 = fmaf(ap[j + 3], wb4.w, l1);
    }
    float mx = fmaxf(l0, l1);
    float e0 = __expf(l0 - mx), e1 = __expf(l1 - mx);
    float inv = 1.f / (e0 + e1);
    attn[bi * 256 + cc * 2]     = e0 * inv;
    attn[bi * 256 + cc * 2 + 1] = e1 * inv;
}

// ---- kF: out = attn0*agg + attn1*k2d; block = (b2, c2-pair, strip) ----
__global__ __launch_bounds__(256, 8) void kF_out(
    float* __restrict__ out, const u16* __restrict__ aggh,
    const u32* __restrict__ k2dh2, const float* __restrict__ attn)
{
    int blk   = blockIdx.x;
    int strip = blk & 3;
    int c2    = (blk >> 2) & 63;
    int b2    = blk >> 8;
    int bi    = b2 >> 3;
    int px0   = strip * 1024 + threadIdx.x * 4;

    float a0e = attn[bi * 256 + 4 * c2];
    float a1e = attn[bi * 256 + 4 * c2 + 1];
    float a0o = attn[bi * 256 + 4 * c2 + 2];
    float a1o = attn[bi * 256 + 4 * c2 + 3];

    uint4 kk = *(const uint4*)(k2dh2 + (b2 * 64 + c2) * 4096 + px0);
    uint2 g0 = *(const uint2*)(aggh + (b2 * 128 + 2 * c2) * 4096 + px0);
    uint2 g1 = *(const uint2*)(aggh + (b2 * 128 + 2 * c2 + 1) * 4096 + px0);

    float4 re, ro;
    re.x = fmaf(a0e, bflo(g0.x), a1e * bflo(kk.x));
    re.y = fmaf(a0e, bfhi(g0.x), a1e * bflo(kk.y));
    re.z = fmaf(a0e, bflo(g0.y), a1e * bflo(kk.z));
    re.w = fmaf(a0e, bfhi(g0.y), a1e * bflo(kk.w));
    ro.x = fmaf(a0o, bflo(g1.x), a1o * bfhi(kk.x));
    ro.y = fmaf(a0o, bfhi(g1.x), a1o * bfhi(kk.y));
    ro.z = fmaf(a0o, bflo(g1.y), a1o * bfhi(kk.z));
    ro.w = fmaf(a0o, bfhi(g1.y), a1o * bfhi(kk.w));
    *(float4*)(out + (b2 * 128 + 2 * c2) * 4096 + px0) = re;
    *(float4*)(out + (b2 * 128 + 2 * c2 + 1) * 4096 + px0) = ro;
}

extern "C" void kernel_launch(void* const* d_in, const int* in_sizes, int n_in,
                              void* d_out, int out_size, void* d_ws, size_t ws_size,
                              hipStream_t stream)
{
    const float* x      = (const float*)d_in[0];
    const float* w_key  = (const float*)d_in[1];
    const float* bnk_g  = (const float*)d_in[2];
    const float* bnk_b  = (const float*)d_in[3];
    const float* bnk_m  = (const float*)d_in[4];
    const float* bnk_v  = (const float*)d_in[5];
    const float* w_e1   = (const float*)d_in[6];
    const float* bne_g  = (const float*)d_in[7];
    const float* bne_b  = (const float*)d_in[8];
    const float* bne_m  = (const float*)d_in[9];
    const float* bne_v  = (const float*)d_in[10];
    const float* w_e2   = (const float*)d_in[11];
    const float* b_e2   = (const float*)d_in[12];
    const float* gn_g   = (const float*)d_in[13];
    const float* gn_b   = (const float*)d_in[14];
    const float* w_1x1  = (const float*)d_in[15];
    const float* bn1_g  = (const float*)d_in[16];
    const float* bn1_b  = (const float*)d_in[17];
    const float* bn1_m  = (const float*)d_in[18];
    const float* bn1_v  = (const float*)d_in[19];
    const float* bn2_g  = (const float*)d_in[20];
    const float* bn2_b  = (const float*)d_in[21];
    const float* bn2_m  = (const float*)d_in[22];
    const float* bn2_v  = (const float*)d_in[23];
    const float* w_se1  = (const float*)d_in[24];
    const float* b_se1  = (const float*)d_in[25];
    const float* bnse_g = (const float*)d_in[26];
    const float* bnse_b = (const float*)d_in[27];
    const float* bnse_m = (const float*)d_in[28];
    const float* bnse_v = (const float*)d_in[29];
    const float* w_se2  = (const float*)d_in[30];
    const float* b_se2  = (const float*)d_in[31];

    float* ws    = (float*)d_ws;
    u32*  xq    = (u32*)ws;
    u32*  k2dh2 = (u32*)(ws + 8388608);
    u16*  vh    = (u16*)(ws + 16777216);
    u16*  aggh  = (u16*)(ws + 25165824);
    u16*  wdh   = (u16*)(ws + 33554432);
    u32*  wkF   = (u32*)(ws + 39845888);
    u32*  wB1   = wkF + 6144;
    u32*  wB    = wB1 + 8192;
    u32*  wB2   = wB + 8192;
    float* st   = ws + 46137344;
    float* gnsum  = st;
    float* gnsq   = st + 1024;
    float* gap    = st + 2048;
    float* gnmean = st + 2560;
    float* gnrstd = st + 3584;
    float* attn   = st + 4608;
    float* a_buf  = st;            // aliases gnsum (dead after kC2)

    // stats zeroing folded into kW_pack (no fillBuffer dispatch)
    kW_pack<<<100, 256, 0, stream>>>(w_key, w_1x1, w_e1, w_e2, wkF, wB1, wB, wB2, gnsum);
    kX_cvt<<<8192, 256, 0, stream>>>(x, xq);
    kA_key<<<2048, 256, 0, stream>>>(xq, wkF, bnk_g, bnk_b, bnk_m, bnk_v, k2dh2, gap);
    kB_val<<<1024, 256, 0, stream>>>(xq, wB1, bn1_g, bn1_b, bn1_m, bn1_v, vh);
    kC_wd<<<1024, 256, 0, stream>>>(xq, k2dh2, wB, bne_g, bne_b, bne_m, bne_v,
                                    wB2, b_e2, wdh, gnsum, gnsq);
    kC2_gn<<<4, 256, 0, stream>>>(gnsum, gnsq, gnmean, gnrstd);
    kD_agg<<<1024, 256, 0, stream>>>(wdh, vh, gnmean, gnrstd, gn_g, gn_b,
                                     bn2_g, bn2_b, bn2_m, bn2_v, aggh, gap);
    kE1_a<<<2, 256, 0, stream>>>(gap, w_se1, b_se1, bnse_g, bnse_b, bnse_m, bnse_v, a_buf);
    kE2_attn<<<2, 256, 0, stream>>>(a_buf, w_se2, b_se2, attn);
    kF_out<<<8192, 256, 0, stream>>>((float*)d_out, aggh, k2dh2, attn);
}

// Round 18
// 137.361 us; speedup vs baseline: 4.9890x; 1.0988x over previous
//
#include <hip/hip_runtime.h>

#define EPSV 1e-5f
typedef unsigned short u16;
typedef unsigned int u32;

// Problem constants: B=4, N=8, B2=32, C=128, H=W=64, HW=4096, KS=3
// Workspace (float offsets):
//   [0,        8388608)  xq    (u32 quad-interleaved bf16 x: [b2][c8][px][4dw])
//   [8388608, 16777216)  k2dq  (u32 quad-interleaved bf16 k2d, same layout as xq)
//   [16777216,25165824)  vh    (u16 bf16, standard layout)
//   [25165824,33554432)  aggh  (u16 bf16, standard layout)
//   [33554432,39845888)  wdh   (u16 bf16, standard layout)
//   [39845888,39871488)  packed weights: wkF[6144] wB1[8192] wB[8192] wB2[3072]
//   stats @46137344: gnsum[1024] gnsq[1024] gap[512] ... attn @ +4608
typedef __attribute__((ext_vector_type(8))) __bf16 bf16x8;
typedef __attribute__((ext_vector_type(4))) float f32x4;
union ABcast { uint4 u; bf16x8 v; };

__device__ __forceinline__ u32 bfbits(float f) {   // RNE f32->bf16 bits
    u32 u = __float_as_uint(f);
    u += 0x7fff + ((u >> 16) & 1);
    return u >> 16;
}
__device__ __forceinline__ float bflo(u32 p) { return __uint_as_float(p << 16); }
__device__ __forceinline__ float bfhi(u32 p) { return __uint_as_float(p & 0xffff0000u); }

// ---- kXW: x -> xq (quad bf16), + weight packing (blocks 0..99), + stats zero ----
__global__ __launch_bounds__(256, 8) void kXW_cvt(
    const float* __restrict__ x, u32* __restrict__ xq,
    const float* __restrict__ wk, const float* __restrict__ w1,
    const float* __restrict__ we1, const float* __restrict__ we2,
    u32* __restrict__ wkF, u32* __restrict__ wB1,
    u32* __restrict__ wB, u32* __restrict__ wB2,
    float* __restrict__ stats_zero)
{
    int qid = blockIdx.x * 256 + threadIdx.x;   // 2,097,152 total (32*16*4096)
    int px  = qid & 4095;
    int c8g = qid >> 12;                        // b2*16 + c8
    const float* xp = x + (c8g * 8) * 4096 + px;
    uint4 o;
    o.x = bfbits(xp[0])        | (bfbits(xp[4096])     << 16);
    o.y = bfbits(xp[2 * 4096]) | (bfbits(xp[3 * 4096]) << 16);
    o.z = bfbits(xp[4 * 4096]) | (bfbits(xp[5 * 4096]) << 16);
    o.w = bfbits(xp[6 * 4096]) | (bfbits(xp[7 * 4096]) << 16);
    *(uint4*)(xq + (c8g * 4096 + px) * 4) = o;

    int i = qid;                                // weight packing: blocks 0..99
    if (i < 2560) stats_zero[i] = 0.f;          // gnsum, gnsq, gap
    if (i < 6144) {                             // wkF: B-frags of w_key per (grp,dk)
        int jj = i & 3;
        int ln = (i >> 2) & 63;
        int nt = (i >> 8) & 1;
        int rest = i >> 9;
        int grp = rest / 3, dk = rest % 3;
        int n = nt * 16 + (ln & 15);
        int k = (ln >> 4) * 8 + 2 * jj;
        int oo = grp * 32 + n;
        wkF[i] = bfbits(wk[oo * 96 + k * 3 + dk]) |
                 (bfbits(wk[oo * 96 + (k + 1) * 3 + dk]) << 16);
    } else if (i < 14336) {                     // wB1: B-frags of w_1x1
        int j2 = i - 6144;
        int jj = j2 & 3;
        int ln = (j2 >> 2) & 63;
        int nt = (j2 >> 8) & 7;
        int kb = j2 >> 11;
        int n = nt * 16 + (ln & 15);
        int k = kb * 32 + (ln >> 4) * 8 + 2 * jj;
        wB1[j2] = bfbits(w1[n * 128 + k]) | (bfbits(w1[n * 128 + k + 1]) << 16);
    } else if (i < 22528) {                     // wB: B-frags of w_e1
        int j2 = i - 14336;
        int jj = j2 & 3;
        int ln = (j2 >> 2) & 63;
        int nt = (j2 >> 8) & 3;
        int kb = j2 >> 10;
        int n  = nt * 16 + (ln & 15);
        int k  = kb * 32 + (ln >> 4) * 8 + 2 * jj;
        wB[j2] = bfbits(we1[n * 256 + k]) | (bfbits(we1[n * 256 + k + 1]) << 16);
    } else if (i < 25600) {                     // wB2: B-frags of w_e2 (96x64)
        int j2 = i - 22528;
        int jj = j2 & 3;
        int ln = (j2 >> 2) & 63;
        int rest = j2 >> 8;
        int kb = rest / 6, nt = rest % 6;
        int n = nt * 16 + (ln & 15);
        int k = kb * 32 + (ln >> 4) * 8 + 2 * jj;
        wB2[j2] = bfbits(we2[n * 64 + k]) | (bfbits(we2[n * 64 + k + 1]) << 16);
    }
}

// ---- kA: key_embed via MFMA -> k2dq (quad layout via LDS repack), + gap ----
__global__ __launch_bounds__(256, 4) void kA_key(
    const u32* __restrict__ xq, const u32* __restrict__ wkF,
    const float* __restrict__ g, const float* __restrict__ bb,
    const float* __restrict__ m, const float* __restrict__ vr,
    u32* __restrict__ k2dq, float* __restrict__ gap)
{
    int tid  = threadIdx.x;
    int lane = tid & 63;
    int q    = __builtin_amdgcn_readfirstlane(tid >> 6);   // 0..3
    int blk  = blockIdx.x;
    int tile = blk & 15;
    int grp  = (blk >> 4) & 3;
    int b2   = blk >> 6;
    int px0  = tile * 256;
    int bi = b2 >> 3, ni = b2 & 7;
    int lrow = lane & 15, lk = lane >> 4;
    const uint4* wkF4 = (const uint4*)wkF;

    f32x4 acc[4][2];
    #pragma unroll
    for (int mt = 0; mt < 4; ++mt)
        #pragma unroll
        for (int nt = 0; nt < 2; ++nt)
            acc[mt][nt] = (f32x4){0.f, 0.f, 0.f, 0.f};

    int pxA[4];
    #pragma unroll
    for (int mt = 0; mt < 4; ++mt) pxA[mt] = px0 + (4 * q + mt) * 16 + lrow;

    #pragma unroll
    for (int dk = 0; dk < 3; ++dk) {
        int nf = ni + dk - 1;
        if (nf >= 0 && nf < 8) {
            const u32* src = xq + (((bi * 8 + nf) * 16 + grp * 4 + lk) * 4096) * 4;
            ABcast a[4];
            #pragma unroll
            for (int mt = 0; mt < 4; ++mt)
                a[mt].u = *(const uint4*)(src + pxA[mt] * 4);
            #pragma unroll
            for (int nt = 0; nt < 2; ++nt) {
                ABcast bfr;
                bfr.u = wkF4[((grp * 3 + dk) * 2 + nt) * 64 + lane];
                #pragma unroll
                for (int mt = 0; mt < 4; ++mt)
                    acc[mt][nt] = __builtin_amdgcn_mfma_f32_16x16x32_bf16(
                        a[mt].v, bfr.v, acc[mt][nt], 0, 0, 0);
            }
        }
    }

    __shared__ u16  karr[32][260];   // ch-within-grp x px, padded
    __shared__ float ssum[32][4];
    #pragma unroll
    for (int nt = 0; nt < 2; ++nt) {
        int ch = grp * 32 + nt * 16 + lrow;
        float s = g[ch] * rsqrtf(vr[ch] + EPSV);
        float t = bb[ch] - m[ch] * s;
        float lsum = 0.f;
        #pragma unroll
        for (int mt = 0; mt < 4; ++mt) {
            float r0 = fmaxf(fmaf(acc[mt][nt].x, s, t), 0.f);
            float r1 = fmaxf(fmaf(acc[mt][nt].y, s, t), 0.f);
            float r2 = fmaxf(fmaf(acc[mt][nt].z, s, t), 0.f);
            float r3 = fmaxf(fmaf(acc[mt][nt].w, s, t), 0.f);
            lsum += r0 + r1 + r2 + r3;
            int pxl = (4 * q + mt) * 16 + lk * 4;
            u16* kr = &karr[nt * 16 + lrow][pxl];
            kr[0] = (u16)bfbits(r0);
            kr[1] = (u16)bfbits(r1);
            kr[2] = (u16)bfbits(r2);
            kr[3] = (u16)bfbits(r3);
        }
        lsum += __shfl_xor(lsum, 16, 64);
        lsum += __shfl_xor(lsum, 32, 64);
        if (lane < 16) ssum[nt * 16 + lrow][q] = lsum;
    }
    __syncthreads();
    if (tid < 32) {
        float* sr = ssum[tid];
        atomicAdd(&gap[bi * 128 + grp * 32 + tid], sr[0] + sr[1] + sr[2] + sr[3]);
    }
    // quad-pack: thread = 1 px, 4 c8 groups
    #pragma unroll
    for (int c8g = 0; c8g < 4; ++c8g) {
        uint4 pk;
        pk.x = (u32)karr[c8g * 8 + 0][tid] | ((u32)karr[c8g * 8 + 1][tid] << 16);
        pk.y = (u32)karr[c8g * 8 + 2][tid] | ((u32)karr[c8g * 8 + 3][tid] << 16);
        pk.z = (u32)karr[c8g * 8 + 4][tid] | ((u32)karr[c8g * 8 + 5][tid] << 16);
        pk.w = (u32)karr[c8g * 8 + 6][tid] | ((u32)karr[c8g * 8 + 7][tid] << 16);
        *(uint4*)(k2dq + ((b2 * 16 + grp * 4 + c8g) * 4096 + px0 + tid) * 4) = pk;
    }
}

// ---- kB: v = BN(x @ w_1x1) via MFMA -> bf16 vh (standard layout) ----
__global__ __launch_bounds__(256, 3) void kB_val(
    const u32* __restrict__ xq, const u32* __restrict__ wB1,
    const float* __restrict__ g, const float* __restrict__ bb,
    const float* __restrict__ m, const float* __restrict__ vr,
    u16* __restrict__ vh)
{
    int tid  = threadIdx.x;
    int lane = tid & 63;
    int q    = __builtin_amdgcn_readfirstlane(tid >> 6);   // 0..3
    int tile = blockIdx.x & 31;
    int b2   = blockIdx.x >> 5;
    int px0  = tile * 128;
    int lrow = lane & 15, lk = lane >> 4;

    const uint4* wB14 = (const uint4*)wB1;

    f32x4 acc[2][8];
    #pragma unroll
    for (int mt = 0; mt < 2; ++mt)
        #pragma unroll
        for (int nt = 0; nt < 8; ++nt)
            acc[mt][nt] = (f32x4){0.f, 0.f, 0.f, 0.f};

    int pxA0 = px0 + (2 * q) * 16 + lrow;
    int pxA1 = pxA0 + 16;

    #pragma unroll
    for (int kblk = 0; kblk < 4; ++kblk) {
        const u32* src = xq + ((b2 * 16 + kblk * 4 + lk) * 4096) * 4;
        ABcast a0, a1;
        a0.u = *(const uint4*)(src + pxA0 * 4);
        a1.u = *(const uint4*)(src + pxA1 * 4);
        #pragma unroll
        for (int nt = 0; nt < 8; ++nt) {
            ABcast bfr;
            bfr.u = wB14[(kblk * 8 + nt) * 64 + lane];
            acc[0][nt] = __builtin_amdgcn_mfma_f32_16x16x32_bf16(a0.v, bfr.v, acc[0][nt], 0, 0, 0);
            acc[1][nt] = __builtin_amdgcn_mfma_f32_16x16x32_bf16(a1.v, bfr.v, acc[1][nt], 0, 0, 0);
        }
    }

    #pragma unroll
    for (int nt = 0; nt < 8; ++nt) {
        int ch = nt * 16 + lrow;
        float s = g[ch] * rsqrtf(vr[ch] + EPSV);
        float t = bb[ch] - m[ch] * s;
        #pragma unroll
        for (int mt = 0; mt < 2; ++mt) {
            float r0 = fmaf(acc[mt][nt].x, s, t);
            float r1 = fmaf(acc[mt][nt].y, s, t);
            float r2 = fmaf(acc[mt][nt].z, s, t);
            float r3 = fmaf(acc[mt][nt].w, s, t);
            uint2 pk;
            pk.x = bfbits(r0) | (bfbits(r1) << 16);
            pk.y = bfbits(r2) | (bfbits(r3) << 16);
            *(uint2*)(vh + (b2 * 128 + ch) * 4096 +
                      px0 + (2 * q + mt) * 16 + lk * 4) = pk;
        }
    }
}

// ---- kC: stage1 e via MFMA (x and k2d both quad); stage2 wd via MFMA; GN partials ----
__global__ __launch_bounds__(256, 3) void kC_wd(
    const u32* __restrict__ xq, const u32* __restrict__ k2dq,
    const u32* __restrict__ wB,
    const float* __restrict__ eg, const float* __restrict__ eb,
    const float* __restrict__ em, const float* __restrict__ ev,
    const u32* __restrict__ wB2, const float* __restrict__ be2,
    u16* __restrict__ wdh, float* __restrict__ gnsum, float* __restrict__ gnsq)
{
    int tid  = threadIdx.x;
    int lane = tid & 63;
    int q    = __builtin_amdgcn_readfirstlane(tid >> 6);   // 0..3
    int tile = blockIdx.x & 31;
    int b2   = blockIdx.x >> 5;
    int px0  = tile * 128;
    int lrow = lane & 15;
    int lk   = lane >> 4;

    const uint4* wB4 = (const uint4*)wB;

    f32x4 acc[2][4];
    #pragma unroll
    for (int mt = 0; mt < 2; ++mt)
        #pragma unroll
        for (int nt = 0; nt < 4; ++nt)
            acc[mt][nt] = (f32x4){0.f, 0.f, 0.f, 0.f};

    int pxA0 = px0 + (2 * q) * 16 + lrow;
    int pxA1 = pxA0 + 16;

    #pragma unroll
    for (int kblk = 0; kblk < 8; ++kblk) {
        const u32* base = (kblk < 4) ? xq : k2dq;
        const u32* src = base + ((b2 * 16 + (kblk & 3) * 4 + lk) * 4096) * 4;
        ABcast a0, a1;
        a0.u = *(const uint4*)(src + pxA0 * 4);
        a1.u = *(const uint4*)(src + pxA1 * 4);
        #pragma unroll
        for (int nt = 0; nt < 4; ++nt) {
            ABcast bfr;
            bfr.u = wB4[(kblk * 4 + nt) * 64 + lane];
            acc[0][nt] = __builtin_amdgcn_mfma_f32_16x16x32_bf16(a0.v, bfr.v, acc[0][nt], 0, 0, 0);
            acc[1][nt] = __builtin_amdgcn_mfma_f32_16x16x32_bf16(a1.v, bfr.v, acc[1][nt], 0, 0, 0);
        }
    }

    __shared__ __align__(16) u32 e_s2[32][132];
    #pragma unroll
    for (int nt = 0; nt < 4; ++nt) {
        int ch = nt * 16 + lrow;
        float s = eg[ch] * rsqrtf(ev[ch] + EPSV);
        float t = eb[ch] - em[ch] * s;
        #pragma unroll
        for (int mt = 0; mt < 2; ++mt) {
            float r0 = fmaxf(fmaf(acc[mt][nt].x, s, t), 0.f);
            float r1 = fmaxf(fmaf(acc[mt][nt].y, s, t), 0.f);
            float r2 = fmaxf(fmaf(acc[mt][nt].z, s, t), 0.f);
            float r3 = fmaxf(fmaf(acc[mt][nt].w, s, t), 0.f);
            float p0 = __shfl_xor(r0, 1, 64);
            float p1 = __shfl_xor(r1, 1, 64);
            float p2 = __shfl_xor(r2, 1, 64);
            float p3 = __shfl_xor(r3, 1, 64);
            if (!(lane & 1)) {
                uint4 pk;
                pk.x = bfbits(r0) | (bfbits(p0) << 16);
                pk.y = bfbits(r1) | (bfbits(p1) << 16);
                pk.z = bfbits(r2) | (bfbits(p2) << 16);
                pk.w = bfbits(r3) | (bfbits(p3) << 16);
                *(uint4*)&e_s2[nt * 8 + (lrow >> 1)][(2 * q + mt) * 16 + lk * 4] = pk;
            }
        }
    }
    __syncthreads();

    const uint4* wB24 = (const uint4*)wB2;
    f32x4 acc2[2][6];
    #pragma unroll
    for (int mt = 0; mt < 2; ++mt)
        #pragma unroll
        for (int nt = 0; nt < 6; ++nt)
            acc2[mt][nt] = (f32x4){0.f, 0.f, 0.f, 0.f};

    #pragma unroll
    for (int kb2 = 0; kb2 < 2; ++kb2) {
        int c2r = kb2 * 16 + lk * 4;
        ABcast a0, a1;
        int pl0 = (2 * q) * 16 + lrow;
        int pl1 = pl0 + 16;
        a0.u.x = e_s2[c2r + 0][pl0];
        a0.u.y = e_s2[c2r + 1][pl0];
        a0.u.z = e_s2[c2r + 2][pl0];
        a0.u.w = e_s2[c2r + 3][pl0];
        a1.u.x = e_s2[c2r + 0][pl1];
        a1.u.y = e_s2[c2r + 1][pl1];
        a1.u.z = e_s2[c2r + 2][pl1];
        a1.u.w = e_s2[c2r + 3][pl1];
        #pragma unroll
        for (int nt = 0; nt < 6; ++nt) {
            ABcast bfr;
            bfr.u = wB24[(kb2 * 6 + nt) * 64 + lane];
            acc2[0][nt] = __builtin_amdgcn_mfma_f32_16x16x32_bf16(a0.v, bfr.v, acc2[0][nt], 0, 0, 0);
            acc2[1][nt] = __builtin_amdgcn_mfma_f32_16x16x32_bf16(a1.v, bfr.v, acc2[1][nt], 0, 0, 0);
        }
    }

    __shared__ float s_sum[96][4], s_sq[96][4];
    #pragma unroll
    for (int nt = 0; nt < 6; ++nt) {
        int ch = nt * 16 + lrow;
        float bias = be2[ch];
        float lsum = 0.f, lsq = 0.f;
        #pragma unroll
        for (int mt = 0; mt < 2; ++mt) {
            float v0 = acc2[mt][nt].x + bias;
            float v1 = acc2[mt][nt].y + bias;
            float v2 = acc2[mt][nt].z + bias;
            float v3 = acc2[mt][nt].w + bias;
            uint2 pk;
            pk.x = bfbits(v0) | (bfbits(v1) << 16);
            pk.y = bfbits(v2) | (bfbits(v3) << 16);
            *(uint2*)(wdh + (b2 * 96 + ch) * 4096 +
                      px0 + (2 * q + mt) * 16 + lk * 4) = pk;
            lsum += v0 + v1 + v2 + v3;
            lsq  += v0 * v0 + v1 * v1 + v2 * v2 + v3 * v3;
        }
        lsum += __shfl_xor(lsum, 16, 64);
        lsum += __shfl_xor(lsum, 32, 64);
        lsq  += __shfl_xor(lsq, 16, 64);
        lsq  += __shfl_xor(lsq, 32, 64);
        if (lane < 16) { s_sum[ch][q] = lsum; s_sq[ch][q] = lsq; }
    }
    __syncthreads();
    if (tid < 32) {
        float ss = 0.f, sq = 0.f;
        #pragma unroll
        for (int j = 0; j < 3; ++j) {
            int ch = tid * 3 + j;
            ss += s_sum[ch][0] + s_sum[ch][1] + s_sum[ch][2] + s_sum[ch][3];
            sq += s_sq[ch][0] + s_sq[ch][1] + s_sq[ch][2] + s_sq[ch][3];
        }
        atomicAdd(&gnsum[b2 * 32 + tid], ss);
        atomicAdd(&gnsq [b2 * 32 + tid], sq);
    }
}

// ---- kD: agg = SiLU(BN2(sum_k GN(wd)*unfold(v))) -> bf16 aggh, + gap ----
// GN stats computed inline from gnsum/gnsq (kC2 folded in).
__global__ __launch_bounds__(256, 8) void kD_agg(
    const u16* __restrict__ wdh, const u16* __restrict__ vh,
    const float* __restrict__ gnsum, const float* __restrict__ gnsq,
    const float* __restrict__ gng, const float* __restrict__ gnb,
    const float* __restrict__ g, const float* __restrict__ bb,
    const float* __restrict__ m, const float* __restrict__ vr,
    u16* __restrict__ aggh, float* __restrict__ gap)
{
    int blk   = blockIdx.x;
    int strip = blk & 7;
    int c1    = (blk >> 3) & 31;
    int bi    = blk >> 8;
    int px0   = strip * 512 + threadIdx.x * 2;
    const float inv = 1.f / 12288.f;

    float sch[4], tch[4], gl[4];
    #pragma unroll
    for (int ch = 0; ch < 4; ++ch) {
        int c = c1 * 4 + ch;
        float s = g[c] * rsqrtf(vr[c] + EPSV);
        sch[ch] = s; tch[ch] = bb[c] - m[c] * s; gl[ch] = 0.f;
    }
    float gg[3], gb[3];
    #pragma unroll
    for (int k = 0; k < 3; ++k) { gg[k] = gng[c1 * 3 + k]; gb[k] = gnb[c1 * 3 + k]; }

    float2 vreg[4][3];
    #pragma unroll
    for (int ch = 0; ch < 4; ++ch) {
        vreg[ch][0] = make_float2(0.f, 0.f);
        u32 v1u = *(const u32*)(vh + ((bi * 8 + 0) * 128 + c1 * 4 + ch) * 4096 + px0);
        u32 v2u = *(const u32*)(vh + ((bi * 8 + 1) * 128 + c1 * 4 + ch) * 4096 + px0);
        vreg[ch][1] = make_float2(bflo(v1u), bfhi(v1u));
        vreg[ch][2] = make_float2(bflo(v2u), bfhi(v2u));
    }

    for (int ni = 0; ni < 8; ++ni) {
        int b2 = bi * 8 + ni;
        float mu = gnsum[b2 * 32 + c1] * inv;
        float var = fmaf(gnsq[b2 * 32 + c1], inv, -mu * mu);
        float rs = rsqrtf(fmaxf(var, 0.f) + EPSV);
        float2 wn[3];
        #pragma unroll
        for (int k = 0; k < 3; ++k) {
            int nf = ni + k - 1;
            if (nf >= 0 && nf < 8) {
                u32 wvu = *(const u32*)(wdh + ((b2 * 96 + c1 * 3 + k) * 4096 + px0));
                wn[k].x = fmaf((bflo(wvu) - mu) * rs, gg[k], gb[k]);
                wn[k].y = fmaf((bfhi(wvu) - mu) * rs, gg[k], gb[k]);
            } else {
                wn[k] = make_float2(0.f, 0.f);
            }
        }
        #pragma unroll
        for (int ch = 0; ch < 4; ++ch) {
            float a0 = 0.f, a1 = 0.f;
            #pragma unroll
            for (int k = 0; k < 3; ++k) {
                a0 = fmaf(wn[k].x, vreg[ch][k].x, a0);
                a1 = fmaf(wn[k].y, vreg[ch][k].y, a1);
            }
            float y0 = fmaf(a0, sch[ch], tch[ch]);
            float y1 = fmaf(a1, sch[ch], tch[ch]);
            float r0 = y0 / (1.f + __expf(-y0));
            float r1 = y1 / (1.f + __expf(-y1));
            *(u32*)(aggh + (b2 * 128 + c1 * 4 + ch) * 4096 + px0) =
                bfbits(r0) | (bfbits(r1) << 16);
            gl[ch] += r0 + r1;
        }
        if (ni < 7) {
            #pragma unroll
            for (int ch = 0; ch < 4; ++ch) {
                vreg[ch][0] = vreg[ch][1];
                vreg[ch][1] = vreg[ch][2];
                if (ni + 2 < 8) {
                    u32 vu = *(const u32*)(vh + ((bi * 8 + ni + 2) * 128 + c1 * 4 + ch) * 4096 + px0);
                    vreg[ch][2] = make_float2(bflo(vu), bfhi(vu));
                }
            }
        }
    }

    __shared__ float sm[4][4];
    int lane = threadIdx.x & 63, wid = threadIdx.x >> 6;
    #pragma unroll
    for (int ch = 0; ch < 4; ++ch) {
        float s = gl[ch];
        #pragma unroll
        for (int off = 32; off; off >>= 1) s += __shfl_down(s, off, 64);
        if (lane == 0) sm[ch][wid] = s;
    }
    __syncthreads();
    if (threadIdx.x < 4) {
        float* sr = sm[threadIdx.x];
        atomicAdd(&gap[bi * 128 + c1 * 4 + threadIdx.x], sr[0] + sr[1] + sr[2] + sr[3]);
    }
}

// ---- kE: SE head, merged (grid 4 = bi, 128 threads) ----
__global__ __launch_bounds__(128) void kE_attn(
    const float* __restrict__ gap,
    const float* __restrict__ w1, const float* __restrict__ b1,
    const float* __restrict__ g, const float* __restrict__ bb,
    const float* __restrict__ m, const float* __restrict__ vr,
    const float* __restrict__ w2, const float* __restrict__ b2v,
    float* __restrict__ attn)
{
    __shared__ float a_s[128];
    int bi = blockIdx.x;
    int oc = threadIdx.x;
    float acc = b1[oc];
    const float* gp = gap + bi * 128;
    const float* wp = w1 + oc * 128;
    for (int c = 0; c < 128; c += 4) {
        const float4 w4 = *(const float4*)(wp + c);
        acc = fmaf(gp[c + 0] * (1.f / 32768.f), w4.x, acc);
        acc = fmaf(gp[c + 1] * (1.f / 32768.f), w4.y, acc);
        acc = fmaf(gp[c + 2] * (1.f / 32768.f), w4.z, acc);
        acc = fmaf(gp[c + 3] * (1.f / 32768.f), w4.w, acc);
    }
    float s = g[oc] * rsqrtf(vr[oc] + EPSV);
    a_s[oc] = fmaxf(fmaf(acc, s, bb[oc] - m[oc] * s), 0.f);
    __syncthreads();

    int cc = threadIdx.x;
    float l0 = b2v[cc * 2], l1 = b2v[cc * 2 + 1];
    const float* w0p = w2 + (cc * 2) * 128;
    const float* w1p = w2 + (cc * 2 + 1) * 128;
    for (int j = 0; j < 128; j += 4) {
        const float4 wa4 = *(const float4*)(w0p + j);
        const float4 wb4 = *(const float4*)(w1p + j);
        l0 = fmaf(a_s[j + 0], wa4.x, l0); l1 = fmaf(a_s[j + 0], wb4.x, l1);
        l0 = fmaf(a_s[j + 1], wa4.y, l0); l1 = fmaf(a_s[j + 1], wb4.y, l1);
        l0 = fmaf(a_s[j + 2], wa4.z, l0); l1 = fmaf(a_s[j + 2], wb4.z, l1);
        l0 = fmaf(a_s[j + 3], wa4.w, l0); l1 = fmaf(a_s[j + 3], wb4.w, l1);
    }
    float mx = fmaxf(l0, l1);
    float e0 = __expf(l0 - mx), e1 = __expf(l1 - mx);
    float inv = 1.f / (e0 + e1);
    attn[bi * 256 + cc * 2]     = e0 * inv;
    attn[bi * 256 + cc * 2 + 1] = e1 * inv;
}

// ---- kF: out = attn0*agg + attn1*k2d; block = (b2, c8, strip); thread = 4 px ----
__global__ __launch_bounds__(256, 8) void kF_out(
    float* __restrict__ out, const u16* __restrict__ aggh,
    const u32* __restrict__ k2dq, const float* __restrict__ attn)
{
    int blk   = blockIdx.x;
    int strip = blk & 3;
    int c8    = (blk >> 2) & 15;
    int b2    = blk >> 6;
    int bi    = b2 >> 3;
    int p     = strip * 1024 + threadIdx.x * 4;

    // 4 px quads of 8 channels
    const u32* kp = k2dq + ((b2 * 16 + c8) * 4096 + p) * 4;
    uint4 kq[4];
    #pragma unroll
    for (int i = 0; i < 4; ++i) kq[i] = *(const uint4*)(kp + i * 4);

    #pragma unroll
    for (int j = 0; j < 8; ++j) {
        int ch = c8 * 8 + j;
        float a0 = attn[bi * 256 + ch * 2];
        float a1 = attn[bi * 256 + ch * 2 + 1];
        uint2 ag = *(const uint2*)(aggh + (b2 * 128 + ch) * 4096 + p);
        float av[4] = { bflo(ag.x), bfhi(ag.x), bflo(ag.y), bfhi(ag.y) };
        float4 r;
        u32 kd0 = (&kq[0].x)[j >> 1];
        u32 kd1 = (&kq[1].x)[j >> 1];
        u32 kd2 = (&kq[2].x)[j >> 1];
        u32 kd3 = (&kq[3].x)[j >> 1];
        float kv0 = (j & 1) ? bfhi(kd0) : bflo(kd0);
        float kv1 = (j & 1) ? bfhi(kd1) : bflo(kd1);
        float kv2 = (j & 1) ? bfhi(kd2) : bflo(kd2);
        float kv3 = (j & 1) ? bfhi(kd3) : bflo(kd3);
        r.x = fmaf(a0, av[0], a1 * kv0);
        r.y = fmaf(a0, av[1], a1 * kv1);
        r.z = fmaf(a0, av[2], a1 * kv2);
        r.w = fmaf(a0, av[3], a1 * kv3);
        *(float4*)(out + (b2 * 128 + ch) * 4096 + p) = r;
    }
}

extern "C" void kernel_launch(void* const* d_in, const int* in_sizes, int n_in,
                              void* d_out, int out_size, void* d_ws, size_t ws_size,
                              hipStream_t stream)
{
    const float* x      = (const float*)d_in[0];
    const float* w_key  = (const float*)d_in[1];
    const float* bnk_g  = (const float*)d_in[2];
    const float* bnk_b  = (const float*)d_in[3];
    const float* bnk_m  = (const float*)d_in[4];
    const float* bnk_v  = (const float*)d_in[5];
    const float* w_e1   = (const float*)d_in[6];
    const float* bne_g  = (const float*)d_in[7];
    const float* bne_b  = (const float*)d_in[8];
    const float* bne_m  = (const float*)d_in[9];
    const float* bne_v  = (const float*)d_in[10];
    const float* w_e2   = (const float*)d_in[11];
    const float* b_e2   = (const float*)d_in[12];
    const float* gn_g   = (const float*)d_in[13];
    const float* gn_b   = (const float*)d_in[14];
    const float* w_1x1  = (const float*)d_in[15];
    const float* bn1_g  = (const float*)d_in[16];
    const float* bn1_b  = (const float*)d_in[17];
    const float* bn1_m  = (const float*)d_in[18];
    const float* bn1_v  = (const float*)d_in[19];
    const float* bn2_g  = (const float*)d_in[20];
    const float* bn2_b  = (const float*)d_in[21];
    const float* bn2_m  = (const float*)d_in[22];
    const float* bn2_v  = (const float*)d_in[23];
    const float* w_se1  = (const float*)d_in[24];
    const float* b_se1  = (const float*)d_in[25];
    const float* bnse_g = (const float*)d_in[26];
    const float* bnse_b = (const float*)d_in[27];
    const float* bnse_m = (const float*)d_in[28];
    const float* bnse_v = (const float*)d_in[29];
    const float* w_se2  = (const float*)d_in[30];
    const float* b_se2  = (const float*)d_in[31];

    float* ws    = (float*)d_ws;
    u32*  xq    = (u32*)ws;
    u32*  k2dq  = (u32*)(ws + 8388608);
    u16*  vh    = (u16*)(ws + 16777216);
    u16*  aggh  = (u16*)(ws + 25165824);
    u16*  wdh   = (u16*)(ws + 33554432);
    u32*  wkF   = (u32*)(ws + 39845888);
    u32*  wB1   = wkF + 6144;
    u32*  wB    = wB1 + 8192;
    u32*  wB2   = wB + 8192;
    float* st   = ws + 46137344;
    float* gnsum  = st;
    float* gnsq   = st + 1024;
    float* gap    = st + 2048;
    float* attn   = st + 4608;

    kXW_cvt<<<8192, 256, 0, stream>>>(x, xq, w_key, w_1x1, w_e1, w_e2,
                                      wkF, wB1, wB, wB2, gnsum);
    kA_key<<<2048, 256, 0, stream>>>(xq, wkF, bnk_g, bnk_b, bnk_m, bnk_v, k2dq, gap);
    kB_val<<<1024, 256, 0, stream>>>(xq, wB1, bn1_g, bn1_b, bn1_m, bn1_v, vh);
    kC_wd<<<1024, 256, 0, stream>>>(xq, k2dq, wB, bne_g, bne_b, bne_m, bne_v,
                                    wB2, b_e2, wdh, gnsum, gnsq);
    kD_agg<<<1024, 256, 0, stream>>>(wdh, vh, gnsum, gnsq, gn_g, gn_b,
                                     bn2_g, bn2_b, bn2_m, bn2_v, aggh, gap);
    kE_attn<<<4, 128, 0, stream>>>(gap, w_se1, b_se1, bnse_g, bnse_b, bnse_m, bnse_v,
                                   w_se2, b_se2, attn);
    kF_out<<<2048, 256, 0, stream>>>((float*)d_out, aggh, k2dq, attn);
}